// Round 1
// baseline (1693.138 us; speedup 1.0000x reference)
//
#include <hip/hip_runtime.h>
#include <math.h>

#define DIMK 512
#define NH 8
#define NKV 2
#define DH 64
#define SEGL 1024
#define NSEG 8
#define NTOK 8192   // concatenated sequence length (NA + NX)
#define BATCH 2

// ---------------------------------------------------------------------------
// Projection GEMM (64x64 tile) + optional per-head RMSNorm + RoPE.
// X: (BATCH*4096, 512) row-major. W: (512, Hout*64). OUT: (BATCH, Hout, 8192, 64).
// pos = pos_offset + row_in_batch  (a -> 0..4095, x -> 4096..8191)
// ---------------------------------------------------------------------------
__global__ __launch_bounds__(256, 2) void proj_kernel(
    const float* __restrict__ X, const float* __restrict__ W,
    const float* __restrict__ gamma, float* __restrict__ OUT,
    int Hout, int pos_offset, int doRope)
{
  __shared__ float As[16][65];
  __shared__ float Bs[16][65];
  __shared__ float T[64][65];
  const int h = blockIdx.y;
  const int rowTile = blockIdx.x;
  const int tid = threadIdx.x;
  const int tx = tid & 15, ty = tid >> 4;
  const int C = Hout * 64;
  const float* Xb = X + (size_t)rowTile * 64 * DIMK;
  const float* Wh = W + h * 64;

  float acc[4][4] = {};
  for (int k0 = 0; k0 < DIMK; k0 += 16) {
    #pragma unroll
    for (int i = 0; i < 4; i++) {
      int idx = i * 256 + tid;
      int m = idx >> 4, kk = idx & 15;
      As[kk][m] = Xb[(size_t)m * DIMK + k0 + kk];
    }
    #pragma unroll
    for (int i = 0; i < 4; i++) {
      int idx = i * 256 + tid;
      int kk = idx >> 6, nn = idx & 63;
      Bs[kk][nn] = Wh[(size_t)(k0 + kk) * C + nn];
    }
    __syncthreads();
    #pragma unroll
    for (int kk = 0; kk < 16; kk++) {
      float av[4], bv[4];
      #pragma unroll
      for (int i = 0; i < 4; i++) av[i] = As[kk][ty * 4 + i];
      #pragma unroll
      for (int j = 0; j < 4; j++) bv[j] = Bs[kk][tx * 4 + j];
      #pragma unroll
      for (int i = 0; i < 4; i++)
        #pragma unroll
        for (int j = 0; j < 4; j++) acc[i][j] += av[i] * bv[j];
    }
    __syncthreads();
  }

  #pragma unroll
  for (int i = 0; i < 4; i++)
    #pragma unroll
    for (int j = 0; j < 4; j++) T[ty * 4 + i][tx * 4 + j] = acc[i][j];
  __syncthreads();

  if (tid < 64) {
    const int r = tid;
    const size_t grow = (size_t)rowTile * 64 + r;   // 0 .. BATCH*4096-1
    const int b = (int)(grow >> 12);                // /4096
    const int rr = (int)(grow & 4095);
    const int pos = pos_offset + rr;

    float v[64];
    #pragma unroll
    for (int d = 0; d < 64; d++) v[d] = T[r][d];

    if (gamma != nullptr) {
      float ss = 0.f;
      #pragma unroll
      for (int d = 0; d < 64; d++) ss += v[d] * v[d];
      float nrm = fmaxf(sqrtf(ss), 1e-12f);
      float s = 8.0f / nrm;   // sqrt(DH)=8
      #pragma unroll
      for (int d = 0; d < 64; d++) v[d] = v[d] * s * gamma[h * 64 + d];
    }

    float o[64];
    if (doRope) {
      const float LOG1E4 = 9.210340371976184f; // ln(10000)
      #pragma unroll
      for (int j = 0; j < 32; j++) {
        float inv = expf(-((float)j / 32.0f) * LOG1E4);
        float ang = (float)pos * inv;
        float cs, sn;
        sincosf(ang, &sn, &cs);
        o[j]      = v[j] * cs      - v[j + 32] * sn;
        o[j + 32] = v[j + 32] * cs + v[j] * sn;
      }
    } else {
      #pragma unroll
      for (int d = 0; d < 64; d++) o[d] = v[d];
    }

    float* dst = OUT + (((size_t)b * Hout + h) * NTOK + pos) * 64;
    #pragma unroll
    for (int d = 0; d < 64; d++) dst[d] = o[d];
  }
}

// ---------------------------------------------------------------------------
// Per-segment memory summaries:  ST[e][d] = sum_n v[n,e]*sk[n,d],  z[d] = sum_n sk[n,d]
// sk = elu(k)+1. One block per (b, kv, seg) -> 32 blocks.
// ---------------------------------------------------------------------------
__global__ __launch_bounds__(256, 2) void seg_summary_kernel(
    const float* __restrict__ K, const float* __restrict__ V,
    float* __restrict__ S, float* __restrict__ Z)
{
  __shared__ float SK[64][65];
  __shared__ float SV[64][65];
  const int blk = blockIdx.x;          // (b*NKV+kv)*NSEG + seg
  const int seg = blk & 7;
  const int bkv = blk >> 3;
  const float* Kp = K + ((size_t)bkv * NTOK + seg * SEGL) * 64;
  const float* Vp = V + ((size_t)bkv * NTOK + seg * SEGL) * 64;
  const int tid = threadIdx.x;
  const int e = tid >> 2;
  const int d0 = (tid & 3) * 16;

  float acc[16] = {};
  float zacc[16] = {};
  for (int n0 = 0; n0 < SEGL; n0 += 64) {
    #pragma unroll
    for (int i = 0; i < 16; i++) {
      int idx = i * 256 + tid;
      int r = idx >> 6, c = idx & 63;
      float kvv = Kp[(size_t)(n0 + r) * 64 + c];
      SK[r][c] = kvv > 0.f ? kvv + 1.f : expf(kvv);
      SV[r][c] = Vp[(size_t)(n0 + r) * 64 + c];
    }
    __syncthreads();
    for (int n = 0; n < 64; n++) {
      float vv = SV[n][e];
      #pragma unroll
      for (int i = 0; i < 16; i++) acc[i] += vv * SK[n][d0 + i];
      if (e == 0) {
        #pragma unroll
        for (int i = 0; i < 16; i++) zacc[i] += SK[n][d0 + i];
      }
    }
    __syncthreads();
  }
  float* Sp = S + (size_t)blk * 4096;
  #pragma unroll
  for (int i = 0; i < 16; i++) Sp[e * 64 + d0 + i] = acc[i];
  if (e == 0) {
    float* Zp = Z + (size_t)blk * 64;
    #pragma unroll
    for (int i = 0; i < 16; i++) Zp[d0 + i] = zacc[i];
  }
}

// Exclusive prefix over segments. One block per (b,kv) -> 4 blocks.
__global__ void prefix_kernel(const float* __restrict__ S, const float* __restrict__ Z,
                              float* __restrict__ P, float* __restrict__ PZ)
{
  const int bkv = blockIdx.x;
  const int tid = threadIdx.x;
  for (int i = tid; i < 4096; i += 256) {
    float run = 0.f;
    for (int s = 0; s < NSEG; s++) {
      P[((size_t)bkv * NSEG + s) * 4096 + i] = run;
      run += S[((size_t)bkv * NSEG + s) * 4096 + i];
    }
  }
  if (tid < 64) {
    float run = 0.f;
    for (int s = 0; s < NSEG; s++) {
      PZ[((size_t)bkv * NSEG + s) * 64 + tid] = run;
      run += Z[((size_t)bkv * NSEG + s) * 64 + tid];
    }
  }
}

// ---------------------------------------------------------------------------
// Attention: per block = (b,h,seg, quarter of 256 rows), 4 waves, lane = 1 row.
// Local causal softmax (online, chunked) + linear-memory read + gated mix.
// ---------------------------------------------------------------------------
__global__ __launch_bounds__(256, 2) void attn_kernel(
    const float* __restrict__ Q, const float* __restrict__ K,
    const float* __restrict__ V, const float* __restrict__ P,
    const float* __restrict__ PZ, const float* __restrict__ beta,
    float* __restrict__ OUT)
{
  __shared__ float Ks[64][64];
  __shared__ float Vs[64][64];
  const int bhs = blockIdx.x;            // (b*NH+h)*NSEG + seg
  const int qt  = blockIdx.y;            // quarter
  const int seg = bhs & 7;
  const int bh  = bhs >> 3;
  const int h = bh & 7;
  const int b = bh >> 3;
  const int kv = h & 1;                  // jnp.tile -> h % KVH
  const int bkv = b * NKV + kv;
  const int tid = threadIdx.x;
  const int w = tid >> 6, l = tid & 63;
  const int row = qt * 256 + w * 64 + l; // row in segment
  const int n = seg * SEGL + row;        // global position

  const float* qp = Q + ((size_t)bh * NTOK + n) * 64;
  float q[64];
  #pragma unroll
  for (int d = 0; d < 64; d++) q[d] = qp[d];

  float out[64];
  #pragma unroll
  for (int d = 0; d < 64; d++) out[d] = 0.f;
  float runmax = -1e30f, runsum = 0.f;

  const float* Kbase = K + ((size_t)bkv * NTOK + seg * SEGL) * 64;
  const float* Vbase = V + ((size_t)bkv * NTOK + seg * SEGL) * 64;
  const int maxkt = qt * 4 + 3;
  const int mykt  = qt * 4 + w;

  for (int kt = 0; kt <= maxkt; kt++) {
    #pragma unroll
    for (int i = 0; i < 4; i++) {
      int idx = i * 1024 + tid * 4;
      int r = idx >> 6, c = idx & 63;
      *(float4*)&Ks[r][c] = *(const float4*)(Kbase + (size_t)(kt * 64 + r) * 64 + c);
      *(float4*)&Vs[r][c] = *(const float4*)(Vbase + (size_t)(kt * 64 + r) * 64 + c);
    }
    __syncthreads();
    if (kt <= mykt) {
      const int kbase = kt * 64;
      for (int m0 = 0; m0 < 64; m0 += 16) {
        float sc[16];
        #pragma unroll
        for (int mm = 0; mm < 16; mm++) {
          const int m = m0 + mm;
          float s = 0.f;
          #pragma unroll
          for (int d = 0; d < 64; d++) s += q[d] * Ks[m][d];
          sc[mm] = (kbase + m <= row) ? s * 0.125f : -1e30f;
        }
        float tmax = sc[0];
        #pragma unroll
        for (int mm = 1; mm < 16; mm++) tmax = fmaxf(tmax, sc[mm]);
        const float nmax = fmaxf(runmax, tmax);
        const float corr = expf(runmax - nmax);
        runsum *= corr;
        #pragma unroll
        for (int d = 0; d < 64; d++) out[d] *= corr;
        #pragma unroll
        for (int mm = 0; mm < 16; mm++) {
          float wgt = expf(sc[mm] - nmax);
          runsum += wgt;
          #pragma unroll
          for (int d = 0; d < 64; d++) out[d] += wgt * Vs[m0 + mm][d];
        }
        runmax = nmax;
      }
    }
    __syncthreads();
  }

  const float invsum = 1.f / runsum;
  float sq[64];
  #pragma unroll
  for (int d = 0; d < 64; d++) { float xv = q[d]; sq[d] = xv > 0.f ? xv + 1.f : expf(xv); }

  const float* STp = P + ((size_t)bkv * NSEG + seg) * 4096;
  const float* zp  = PZ + ((size_t)bkv * NSEG + seg) * 64;
  float den = 1e-12f;
  #pragma unroll
  for (int d = 0; d < 64; d++) den += sq[d] * zp[d];
  const float invden = 1.f / den;
  const float g = 1.f / (1.f + expf(-beta[h]));
  const float g1 = 1.f - g;

  size_t obase;
  if (n < 4096) {   // out_a: second half of d_out
    obase = (size_t)BATCH * 4096 * 512 + (((size_t)b * 4096 + n) * NH + h) * 64;
  } else {          // out_x: first half
    obase = (((size_t)b * 4096 + (n - 4096)) * NH + h) * 64;
  }
  #pragma unroll
  for (int e = 0; e < 64; e++) {
    float num = 0.f;
    #pragma unroll
    for (int d = 0; d < 64; d++) num += sq[d] * STp[e * 64 + d];
    OUT[obase + e] = g * num * invden + g1 * out[e] * invsum;
  }
}

// ---------------------------------------------------------------------------
extern "C" void kernel_launch(void* const* d_in, const int* in_sizes, int n_in,
                              void* d_out, int out_size, void* d_ws, size_t ws_size,
                              hipStream_t stream) {
  const float* x    = (const float*)d_in[0];
  const float* a    = (const float*)d_in[1];
  const float* Wq_x = (const float*)d_in[2];
  const float* Wk_x = (const float*)d_in[3];
  const float* Wv_x = (const float*)d_in[4];
  const float* Wq_a = (const float*)d_in[5];
  const float* Wk_a = (const float*)d_in[6];
  const float* Wv_a = (const float*)d_in[7];
  const float* gq_x = (const float*)d_in[8];
  const float* gk_x = (const float*)d_in[9];
  const float* gq_a = (const float*)d_in[10];
  const float* gk_a = (const float*)d_in[11];
  const float* beta = (const float*)d_in[12];

  float* ws = (float*)d_ws;
  float* Qb = ws;                       // BATCH*NH*NTOK*64  = 8388608
  float* Kb = Qb + (size_t)8388608;     // BATCH*NKV*NTOK*64 = 2097152
  float* Vb = Kb + (size_t)2097152;     // 2097152
  float* S  = Vb + (size_t)2097152;     // 32*4096 = 131072
  float* Z  = S  + (size_t)131072;      // 32*64   = 2048
  float* P  = Z  + (size_t)2048;        // 131072
  float* PZ = P  + (size_t)131072;      // 2048

  // a occupies positions 0..4095, x occupies 4096..8191
  proj_kernel<<<dim3(128, 8), 256, 0, stream>>>(a, Wq_a, gq_a, Qb, 8, 0, 1);
  proj_kernel<<<dim3(128, 2), 256, 0, stream>>>(a, Wk_a, gk_a, Kb, 2, 0, 1);
  proj_kernel<<<dim3(128, 2), 256, 0, stream>>>(a, Wv_a, nullptr, Vb, 2, 0, 0);
  proj_kernel<<<dim3(128, 8), 256, 0, stream>>>(x, Wq_x, gq_x, Qb, 8, 4096, 1);
  proj_kernel<<<dim3(128, 2), 256, 0, stream>>>(x, Wk_x, gk_x, Kb, 2, 4096, 1);
  proj_kernel<<<dim3(128, 2), 256, 0, stream>>>(x, Wv_x, nullptr, Vb, 2, 4096, 0);

  seg_summary_kernel<<<32, 256, 0, stream>>>(Kb, Vb, S, Z);
  prefix_kernel<<<4, 256, 0, stream>>>(S, Z, P, PZ);

  attn_kernel<<<dim3(128, 4), 256, 0, stream>>>(Qb, Kb, Vb, P, PZ, beta, (float*)d_out);
}

// Round 2
// 807.358 us; speedup vs baseline: 2.0971x; 2.0971x over previous
//
#include <hip/hip_runtime.h>
#include <math.h>

#define NH 8
#define NKV 2
#define SEGL 1024
#define NSEG 8
#define NTOK 8192
#define BATCH 2
#define DIMK 512

typedef short short8v __attribute__((ext_vector_type(8)));
typedef float f32x4 __attribute__((ext_vector_type(4)));

__device__ __forceinline__ unsigned short f2bf(float f) {
  union { float f; unsigned u; } c; c.f = f;
  unsigned u = c.u;
  return (unsigned short)((u + 0x7FFFu + ((u >> 16) & 1u)) >> 16);
}
__device__ __forceinline__ float bf2f(unsigned short h) {
  union { unsigned u; float f; } c; c.u = ((unsigned)h) << 16;
  return c.f;
}

// ---------------------------------------------------------------------------
// Projection GEMM (64x64 tile) + RMSNorm + RoPE (mode 0) or V + transpose (mode 1).
// X: (BATCH*4096, 512) f32. W: (512, Hout*64) f32. OUT: bf16 (B,Hout,8192,64).
// mode 1 also writes OUTT: bf16 (B,Hout,64,8192)  (Vt[e][n]).
// ---------------------------------------------------------------------------
__global__ __launch_bounds__(256, 2) void proj_kernel(
    const float* __restrict__ X, const float* __restrict__ W,
    const float* __restrict__ gamma, unsigned short* __restrict__ OUT,
    unsigned short* __restrict__ OUTT,
    int Hout, int pos_offset, int mode)
{
  __shared__ float As[16][65];
  __shared__ float Bs[16][65];
  __shared__ float T[64][65];
  const int h = blockIdx.y;
  const int rowTile = blockIdx.x;
  const int tid = threadIdx.x;
  const int tx = tid & 15, ty = tid >> 4;
  const int C = Hout * 64;
  const float* Xb = X + (size_t)rowTile * 64 * DIMK;
  const float* Wh = W + h * 64;

  float acc[4][4] = {};
  for (int k0 = 0; k0 < DIMK; k0 += 16) {
    #pragma unroll
    for (int i = 0; i < 4; i++) {
      int idx = i * 256 + tid;
      int m = idx >> 4, kk = idx & 15;
      As[kk][m] = Xb[(size_t)m * DIMK + k0 + kk];
    }
    #pragma unroll
    for (int i = 0; i < 4; i++) {
      int idx = i * 256 + tid;
      int kk = idx >> 6, nn = idx & 63;
      Bs[kk][nn] = Wh[(size_t)(k0 + kk) * C + nn];
    }
    __syncthreads();
    #pragma unroll
    for (int kk = 0; kk < 16; kk++) {
      float av[4], bv[4];
      #pragma unroll
      for (int i = 0; i < 4; i++) av[i] = As[kk][ty * 4 + i];
      #pragma unroll
      for (int j = 0; j < 4; j++) bv[j] = Bs[kk][tx * 4 + j];
      #pragma unroll
      for (int i = 0; i < 4; i++)
        #pragma unroll
        for (int j = 0; j < 4; j++) acc[i][j] += av[i] * bv[j];
    }
    __syncthreads();
  }

  #pragma unroll
  for (int i = 0; i < 4; i++)
    #pragma unroll
    for (int j = 0; j < 4; j++) T[ty * 4 + i][tx * 4 + j] = acc[i][j];
  __syncthreads();

  if (tid < 64) {
    const int r = tid;
    const size_t grow = (size_t)rowTile * 64 + r;
    const int b = (int)(grow >> 12);
    const int rr = (int)(grow & 4095);
    const int pos = pos_offset + rr;

    float v[64];
    #pragma unroll
    for (int d = 0; d < 64; d++) v[d] = T[r][d];

    float o[64];
    if (mode == 0) {
      float ss = 0.f;
      #pragma unroll
      for (int d = 0; d < 64; d++) ss += v[d] * v[d];
      float nrm = fmaxf(sqrtf(ss), 1e-12f);
      float s = 8.0f / nrm;
      #pragma unroll
      for (int d = 0; d < 64; d++) v[d] = v[d] * s * gamma[h * 64 + d];
      const float LOG1E4 = 9.210340371976184f;
      #pragma unroll
      for (int j = 0; j < 32; j++) {
        float inv = expf(-((float)j / 32.0f) * LOG1E4);
        float ang = (float)pos * inv;
        float cs, sn;
        sincosf(ang, &sn, &cs);
        o[j]      = v[j] * cs      - v[j + 32] * sn;
        o[j + 32] = v[j + 32] * cs + v[j] * sn;
      }
    } else {
      #pragma unroll
      for (int d = 0; d < 64; d++) o[d] = v[d];
    }

    unsigned short* dst = OUT + (((size_t)b * Hout + h) * NTOK + pos) * 64;
    #pragma unroll
    for (int d = 0; d < 64; d++) dst[d] = f2bf(o[d]);
  }

  if (mode == 1 && tid < 64) {
    const int e = tid;
    const size_t grow0 = (size_t)rowTile * 64;
    const int b0 = (int)(grow0 >> 12);
    const int pos0 = pos_offset + (int)(grow0 & 4095);
    unsigned short* dstT = OUTT + (((size_t)b0 * NKV + h) * 64 + e) * NTOK + pos0;
    #pragma unroll
    for (int nn = 0; nn < 64; nn++) dstT[nn] = f2bf(T[nn][e]);
  }
}

// ---------------------------------------------------------------------------
// Per-segment summaries from bf16 K (row-major) and bf16 V (row-major):
// ST[e][d] = sum_n v[n,e]*sk[n,d] ; z[d] = sum_n sk[n,d] ; sk = elu(k)+1
// ---------------------------------------------------------------------------
__global__ __launch_bounds__(256, 2) void seg_summary_kernel(
    const unsigned short* __restrict__ K, const unsigned short* __restrict__ V,
    float* __restrict__ S, float* __restrict__ Z)
{
  __shared__ float SK[64][65];
  __shared__ float SV[64][65];
  const int blk = blockIdx.x;
  const int seg = blk & 7;
  const int bkv = blk >> 3;
  const unsigned short* Kp = K + ((size_t)bkv * NTOK + seg * SEGL) * 64;
  const unsigned short* Vp = V + ((size_t)bkv * NTOK + seg * SEGL) * 64;
  const int tid = threadIdx.x;
  const int e = tid >> 2;
  const int d0 = (tid & 3) * 16;

  float acc[16] = {};
  float zacc[16] = {};
  for (int n0 = 0; n0 < SEGL; n0 += 64) {
    #pragma unroll
    for (int i = 0; i < 16; i++) {
      int idx = i * 256 + tid;
      int r = idx >> 6, c = idx & 63;
      float kvv = bf2f(Kp[(size_t)(n0 + r) * 64 + c]);
      SK[r][c] = kvv > 0.f ? kvv + 1.f : __expf(kvv);
      SV[r][c] = bf2f(Vp[(size_t)(n0 + r) * 64 + c]);
    }
    __syncthreads();
    for (int n = 0; n < 64; n++) {
      float vv = SV[n][e];
      #pragma unroll
      for (int i = 0; i < 16; i++) acc[i] += vv * SK[n][d0 + i];
      if (e == 0) {
        #pragma unroll
        for (int i = 0; i < 16; i++) zacc[i] += SK[n][d0 + i];
      }
    }
    __syncthreads();
  }
  float* Sp = S + (size_t)blk * 4096;
  #pragma unroll
  for (int i = 0; i < 16; i++) Sp[e * 64 + d0 + i] = acc[i];
  if (e == 0) {
    float* Zp = Z + (size_t)blk * 64;
    #pragma unroll
    for (int i = 0; i < 16; i++) Zp[d0 + i] = zacc[i];
  }
}

// Exclusive prefix over segments -> bf16 PT (for MFMA B-frags) + f32 PZ.
__global__ void prefix_kernel(const float* __restrict__ S, const float* __restrict__ Z,
                              unsigned short* __restrict__ PT, float* __restrict__ PZ)
{
  const int bkv = blockIdx.x;
  const int tid = threadIdx.x;
  for (int i = tid; i < 4096; i += 256) {
    float run = 0.f;
    for (int s = 0; s < NSEG; s++) {
      PT[((size_t)bkv * NSEG + s) * 4096 + i] = f2bf(run);
      run += S[((size_t)bkv * NSEG + s) * 4096 + i];
    }
  }
  if (tid < 64) {
    float run = 0.f;
    for (int s = 0; s < NSEG; s++) {
      PZ[((size_t)bkv * NSEG + s) * 64 + tid] = run;
      run += Z[((size_t)bkv * NSEG + s) * 64 + tid];
    }
  }
}

// ---------------------------------------------------------------------------
// MFMA flash attention. Block = (b,h,seg,qtile of 64 rows). 4 waves x 16 rows.
// ---------------------------------------------------------------------------
__global__ __launch_bounds__(256, 2) void attn_mfma_kernel(
    const unsigned short* __restrict__ Qb, const unsigned short* __restrict__ Kb,
    const unsigned short* __restrict__ Vt, const unsigned short* __restrict__ PT,
    const float* __restrict__ PZ, const float* __restrict__ beta,
    float* __restrict__ OUT)
{
  __shared__ unsigned short P_lds[4][2][16][72];
  const int tid = threadIdx.x;
  const int w = tid >> 6;
  const int l = tid & 63;
  const int lc = l & 15;
  const int lg = l >> 4;

  const int qt  = blockIdx.x & 15;
  const int seg = (blockIdx.x >> 4) & 7;
  const int bh  = blockIdx.x >> 7;
  const int h = bh & (NH - 1), b = bh >> 3;
  const int bkv = b * NKV + (h & (NKV - 1));   // jnp.tile -> h % KVH

  const int q0 = qt * 64;
  const int segbase = seg * SEGL;

  // Q A-fragments (row = lc within wave strip, k = lg*8 + i (+32 per chunk))
  const unsigned short* qptr =
      Qb + (((size_t)bh * NTOK) + segbase + q0 + w * 16 + lc) * 64 + lg * 8;
  const short8v aq0 = *(const short8v*)(qptr);
  const short8v aq1 = *(const short8v*)(qptr + 32);

  f32x4 O[4];
  #pragma unroll
  for (int ct = 0; ct < 4; ct++) { O[ct][0]=0.f; O[ct][1]=0.f; O[ct][2]=0.f; O[ct][3]=0.f; }
  float rmax[4] = {-1e30f, -1e30f, -1e30f, -1e30f};
  float rsum[4] = {0.f, 0.f, 0.f, 0.f};

  const unsigned short* Kbase = Kb + ((size_t)bkv * NTOK + segbase) * 64;
  const unsigned short* Vbase = Vt + ((size_t)bkv * 64) * NTOK + segbase;
  const int rloc = w * 16 + lg * 4;  // C-frag row base within 64-row tile

  for (int kt = 0; kt <= qt; ++kt) {
    // ---- S = Q K^T ----
    f32x4 s[4];
    #pragma unroll
    for (int ct = 0; ct < 4; ct++) { s[ct][0]=0.f; s[ct][1]=0.f; s[ct][2]=0.f; s[ct][3]=0.f; }
    const unsigned short* kp = Kbase + (size_t)(kt * 64 + lc) * 64 + lg * 8;
    #pragma unroll
    for (int ct = 0; ct < 4; ct++) {
      short8v bk0 = *(const short8v*)(kp + (size_t)ct * 16 * 64);
      short8v bk1 = *(const short8v*)(kp + (size_t)ct * 16 * 64 + 32);
      s[ct] = __builtin_amdgcn_mfma_f32_16x16x32_bf16(aq0, bk0, s[ct], 0, 0, 0);
      s[ct] = __builtin_amdgcn_mfma_f32_16x16x32_bf16(aq1, bk1, s[ct], 0, 0, 0);
    }
    // ---- mask + scale ----
    const bool diag = (kt == qt);
    float sc[4][4];
    #pragma unroll
    for (int ct = 0; ct < 4; ct++) {
      const int cl = ct * 16 + lc;
      #pragma unroll
      for (int i = 0; i < 4; i++) {
        float v = s[ct][i] * 0.125f;
        if (diag && cl > rloc + i) v = -1e30f;
        sc[ct][i] = v;
      }
    }
    // ---- online softmax ----
    float tm[4], ts[4];
    #pragma unroll
    for (int i = 0; i < 4; i++)
      tm[i] = fmaxf(fmaxf(sc[0][i], sc[1][i]), fmaxf(sc[2][i], sc[3][i]));
    #pragma unroll
    for (int off = 1; off < 16; off <<= 1) {
      #pragma unroll
      for (int i = 0; i < 4; i++) tm[i] = fmaxf(tm[i], __shfl_xor(tm[i], off, 64));
    }
    #pragma unroll
    for (int i = 0; i < 4; i++) {
      float nm = fmaxf(rmax[i], tm[i]);
      float corr = __expf(rmax[i] - nm);
      rmax[i] = nm;
      rsum[i] *= corr;
      O[0][i] *= corr; O[1][i] *= corr; O[2][i] *= corr; O[3][i] *= corr;
      ts[i] = 0.f;
    }
    unsigned short pb[4][4];
    #pragma unroll
    for (int ct = 0; ct < 4; ct++)
      #pragma unroll
      for (int i = 0; i < 4; i++) {
        float p = __expf(sc[ct][i] - rmax[i]);
        ts[i] += p;
        pb[ct][i] = f2bf(p);
      }
    #pragma unroll
    for (int off = 1; off < 16; off <<= 1) {
      #pragma unroll
      for (int i = 0; i < 4; i++) ts[i] += __shfl_xor(ts[i], off, 64);
    }
    #pragma unroll
    for (int i = 0; i < 4; i++) rsum[i] += ts[i];

    // ---- P -> LDS (C layout) -> A-frags ----
    const int buf = kt & 1;
    #pragma unroll
    for (int ct = 0; ct < 4; ct++)
      #pragma unroll
      for (int i = 0; i < 4; i++)
        P_lds[w][buf][lg * 4 + i][ct * 16 + lc] = pb[ct][i];
    asm volatile("s_waitcnt lgkmcnt(0)" ::: "memory");
    __builtin_amdgcn_sched_barrier(0);
    const unsigned short* pp = &P_lds[w][buf][lc][lg * 8];
    short8v ap0 = *(const short8v*)(pp);
    short8v ap1 = *(const short8v*)(pp + 32);
    // ---- O += P V ----
    const unsigned short* vp = Vbase + (size_t)lc * NTOK + kt * 64 + lg * 8;
    #pragma unroll
    for (int ct = 0; ct < 4; ct++) {
      short8v bv0 = *(const short8v*)(vp + (size_t)ct * 16 * NTOK);
      short8v bv1 = *(const short8v*)(vp + (size_t)ct * 16 * NTOK + 32);
      O[ct] = __builtin_amdgcn_mfma_f32_16x16x32_bf16(ap0, bv0, O[ct], 0, 0, 0);
      O[ct] = __builtin_amdgcn_mfma_f32_16x16x32_bf16(ap1, bv1, O[ct], 0, 0, 0);
    }
  }

  // ---- memory path: sq = elu(q)+1 ; N = sq @ M ; den = sq . z ----
  float sqf[2][8];
  short8v asq0, asq1;
  #pragma unroll
  for (int i = 0; i < 8; i++) {
    float f0 = bf2f((unsigned short)aq0[i]);
    float e0 = f0 > 0.f ? f0 + 1.f : __expf(f0);
    sqf[0][i] = e0; asq0[i] = (short)f2bf(e0);
    float f1 = bf2f((unsigned short)aq1[i]);
    float e1 = f1 > 0.f ? f1 + 1.f : __expf(f1);
    sqf[1][i] = e1; asq1[i] = (short)f2bf(e1);
  }
  f32x4 N[4];
  #pragma unroll
  for (int ct = 0; ct < 4; ct++) { N[ct][0]=0.f; N[ct][1]=0.f; N[ct][2]=0.f; N[ct][3]=0.f; }
  const unsigned short* stp = PT + ((size_t)bkv * NSEG + seg) * 4096 + lc * 64 + lg * 8;
  #pragma unroll
  for (int ct = 0; ct < 4; ct++) {
    short8v bs0 = *(const short8v*)(stp + ct * 16 * 64);
    short8v bs1 = *(const short8v*)(stp + ct * 16 * 64 + 32);
    N[ct] = __builtin_amdgcn_mfma_f32_16x16x32_bf16(asq0, bs0, N[ct], 0, 0, 0);
    N[ct] = __builtin_amdgcn_mfma_f32_16x16x32_bf16(asq1, bs1, N[ct], 0, 0, 0);
  }
  const float* zp = PZ + ((size_t)bkv * NSEG + seg) * 64 + lg * 8;
  float den = 1e-12f;
  #pragma unroll
  for (int i = 0; i < 8; i++) den += sqf[0][i] * zp[i] + sqf[1][i] * zp[32 + i];
  den += __shfl_xor(den, 16, 64);
  den += __shfl_xor(den, 32, 64);
  float denc[4];
  #pragma unroll
  for (int reg = 0; reg < 4; reg++) denc[reg] = __shfl(den, lg * 4 + reg, 64);

  const float g = 1.f / (1.f + __expf(-beta[h]));
  const float g1 = 1.f - g;
  const int nrow = segbase + q0 + w * 16 + lg * 4;

  #pragma unroll
  for (int reg = 0; reg < 4; reg++) {
    const int n = nrow + reg;
    const float invs = 1.f / rsum[reg];
    const float invd = 1.f / denc[reg];
    size_t obase;
    if (n < 4096) obase = (size_t)BATCH * 4096 * 512 + (((size_t)b * 4096 + n) * NH + h) * 64;
    else          obase = (((size_t)b * 4096 + (n - 4096)) * NH + h) * 64;
    #pragma unroll
    for (int ct = 0; ct < 4; ct++) {
      OUT[obase + ct * 16 + lc] = g * N[ct][reg] * invd + g1 * O[ct][reg] * invs;
    }
  }
}

// ---------------------------------------------------------------------------
extern "C" void kernel_launch(void* const* d_in, const int* in_sizes, int n_in,
                              void* d_out, int out_size, void* d_ws, size_t ws_size,
                              hipStream_t stream) {
  const float* x    = (const float*)d_in[0];
  const float* a    = (const float*)d_in[1];
  const float* Wq_x = (const float*)d_in[2];
  const float* Wk_x = (const float*)d_in[3];
  const float* Wv_x = (const float*)d_in[4];
  const float* Wq_a = (const float*)d_in[5];
  const float* Wk_a = (const float*)d_in[6];
  const float* Wv_a = (const float*)d_in[7];
  const float* gq_x = (const float*)d_in[8];
  const float* gk_x = (const float*)d_in[9];
  const float* gq_a = (const float*)d_in[10];
  const float* gk_a = (const float*)d_in[11];
  const float* beta = (const float*)d_in[12];

  unsigned short* Qb = (unsigned short*)d_ws;          // 8388608 elems bf16
  unsigned short* Kb = Qb + (size_t)8388608;           // 2097152
  unsigned short* Vb = Kb + (size_t)2097152;           // 2097152 (row-major)
  unsigned short* Vt = Vb + (size_t)2097152;           // 2097152 (transposed)
  float* S  = (float*)(Vt + (size_t)2097152);          // 131072 f32
  float* Z  = S + (size_t)131072;                      // 2048
  float* PZ = Z + (size_t)2048;                        // 2048
  unsigned short* PT = (unsigned short*)(PZ + (size_t)2048); // 131072 bf16

  // a -> positions 0..4095, x -> positions 4096..8191
  proj_kernel<<<dim3(128, 8), 256, 0, stream>>>(a, Wq_a, gq_a, Qb, nullptr, 8, 0, 0);
  proj_kernel<<<dim3(128, 2), 256, 0, stream>>>(a, Wk_a, gk_a, Kb, nullptr, 2, 0, 0);
  proj_kernel<<<dim3(128, 2), 256, 0, stream>>>(a, Wv_a, nullptr, Vb, Vt, 2, 0, 1);
  proj_kernel<<<dim3(128, 8), 256, 0, stream>>>(x, Wq_x, gq_x, Qb, nullptr, 8, 4096, 0);
  proj_kernel<<<dim3(128, 2), 256, 0, stream>>>(x, Wk_x, gk_x, Kb, nullptr, 2, 4096, 0);
  proj_kernel<<<dim3(128, 2), 256, 0, stream>>>(x, Wv_x, nullptr, Vb, Vt, 2, 4096, 1);

  seg_summary_kernel<<<32, 256, 0, stream>>>(Kb, Vb, S, Z);
  prefix_kernel<<<4, 256, 0, stream>>>(S, Z, PT, PZ);

  attn_mfma_kernel<<<dim3(2048), 256, 0, stream>>>(Qb, Kb, Vt, PT, PZ, beta, (float*)d_out);
}

// Round 3
// 597.818 us; speedup vs baseline: 2.8322x; 1.3505x over previous
//
#include <hip/hip_runtime.h>
#include <math.h>

#define NH 8
#define NKV 2
#define SEGL 1024
#define NSEG 8
#define NTOK 8192
#define BATCH 2
#define DIMK 512

typedef short short8v __attribute__((ext_vector_type(8)));
typedef float f32x4 __attribute__((ext_vector_type(4)));

__device__ __forceinline__ unsigned short f2bf(float f) {
  union { float f; unsigned u; } c; c.f = f;
  unsigned u = c.u;
  return (unsigned short)((u + 0x7FFFu + ((u >> 16) & 1u)) >> 16);
}
__device__ __forceinline__ float bf2f(unsigned short h) {
  union { unsigned u; float f; } c; c.u = ((unsigned)h) << 16;
  return c.f;
}

// ---------------------------------------------------------------------------
// f32 -> bf16 cast, 8 elems/thread.
// ---------------------------------------------------------------------------
__global__ void cast_bf16_kernel(const float* __restrict__ in,
                                 unsigned short* __restrict__ out, int n8) {
  int i = blockIdx.x * blockDim.x + threadIdx.x;
  if (i >= n8) return;
  const float4* p = (const float4*)in + (size_t)i * 2;
  float4 v0 = p[0], v1 = p[1];
  short8v o;
  o[0] = (short)f2bf(v0.x); o[1] = (short)f2bf(v0.y);
  o[2] = (short)f2bf(v0.z); o[3] = (short)f2bf(v0.w);
  o[4] = (short)f2bf(v1.x); o[5] = (short)f2bf(v1.y);
  o[6] = (short)f2bf(v1.z); o[7] = (short)f2bf(v1.w);
  *((short8v*)out + i) = o;
}

// ---------------------------------------------------------------------------
// W (512 x C) f32 -> Wt (C x 512) bf16, 32x32 LDS tile transpose.
// ---------------------------------------------------------------------------
__global__ void wtrans_kernel(const float* __restrict__ in,
                              unsigned short* __restrict__ out, int C) {
  __shared__ float T[32][33];
  const int c0 = blockIdx.x * 32, k0 = blockIdx.y * 32;
  const int tx = threadIdx.x & 31, ty = threadIdx.x >> 5;  // ty 0..7
  #pragma unroll
  for (int i = 0; i < 4; i++)
    T[ty + i * 8][tx] = in[(size_t)(k0 + ty + i * 8) * C + c0 + tx];
  __syncthreads();
  #pragma unroll
  for (int i = 0; i < 4; i++)
    out[(size_t)(c0 + ty + i * 8) * 512 + k0 + tx] = f2bf(T[tx][ty + i * 8]);
}

// ---------------------------------------------------------------------------
// MFMA projection: C[m][n] = sum_k X[m][k] * Wt[n][k], 64x64 tile (one head).
// mode 0: RMSNorm + RoPE epilogue -> OUT bf16 (B,Hout,NTOK,64)
// mode 1: plain -> OUT row-major + OUTT transposed (B,NKV,64,NTOK)
// ---------------------------------------------------------------------------
__global__ __launch_bounds__(256) void proj_mfma_kernel(
    const unsigned short* __restrict__ Xbf, const unsigned short* __restrict__ Wt,
    const float* __restrict__ gamma, unsigned short* __restrict__ OUT,
    unsigned short* __restrict__ OUTT, int Hout, int pos_offset, int mode)
{
  __shared__ unsigned short Tsh[64][72];
  const int tid = threadIdx.x;
  const int w = tid >> 6, l = tid & 63, lc = l & 15, lg = l >> 4;
  const int h = blockIdx.y;
  const int row0 = blockIdx.x * 64;

  const unsigned short* ap = Xbf + (size_t)(row0 + w * 16 + lc) * 512 + lg * 8;
  const unsigned short* bp = Wt + (size_t)(h * 64 + lc) * 512 + lg * 8;

  f32x4 acc[4];
  #pragma unroll
  for (int ct = 0; ct < 4; ct++) { acc[ct][0]=0.f; acc[ct][1]=0.f; acc[ct][2]=0.f; acc[ct][3]=0.f; }

  #pragma unroll 4
  for (int kc = 0; kc < 16; kc++) {
    short8v av = *(const short8v*)(ap + kc * 32);
    #pragma unroll
    for (int ct = 0; ct < 4; ct++) {
      short8v bv = *(const short8v*)(bp + (size_t)(ct * 16 * 512) + kc * 32);
      acc[ct] = __builtin_amdgcn_mfma_f32_16x16x32_bf16(av, bv, acc[ct], 0, 0, 0);
    }
  }

  float o[4][4];
  if (mode == 0) {
    float srow[4];
    #pragma unroll
    for (int reg = 0; reg < 4; reg++) {
      float ss = acc[0][reg]*acc[0][reg] + acc[1][reg]*acc[1][reg]
               + acc[2][reg]*acc[2][reg] + acc[3][reg]*acc[3][reg];
      ss += __shfl_xor(ss, 1, 64);
      ss += __shfl_xor(ss, 2, 64);
      ss += __shfl_xor(ss, 4, 64);
      ss += __shfl_xor(ss, 8, 64);
      srow[reg] = 8.0f / fmaxf(sqrtf(ss), 1e-12f);
    }
    float gam[4];
    #pragma unroll
    for (int ct = 0; ct < 4; ct++) gam[ct] = gamma[h * 64 + ct * 16 + lc];
    const float LOG1E4 = 9.210340371976184f;
    float invf[2];
    invf[0] = __expf(-((float)lc / 32.f) * LOG1E4);
    invf[1] = __expf(-((float)(16 + lc) / 32.f) * LOG1E4);
    const int posb = pos_offset + (row0 & 4095) + w * 16 + lg * 4;
    #pragma unroll
    for (int reg = 0; reg < 4; reg++) {
      #pragma unroll
      for (int half = 0; half < 2; half++) {
        float ang = (float)(posb + reg) * invf[half];
        float sn, cs;
        sincosf(ang, &sn, &cs);
        float v1 = acc[half][reg] * srow[reg] * gam[half];
        float v2 = acc[half + 2][reg] * srow[reg] * gam[half + 2];
        o[half][reg]     = v1 * cs - v2 * sn;
        o[half + 2][reg] = v2 * cs + v1 * sn;
      }
    }
  } else {
    #pragma unroll
    for (int ct = 0; ct < 4; ct++)
      #pragma unroll
      for (int reg = 0; reg < 4; reg++) o[ct][reg] = acc[ct][reg];
  }

  #pragma unroll
  for (int ct = 0; ct < 4; ct++)
    #pragma unroll
    for (int reg = 0; reg < 4; reg++)
      Tsh[w * 16 + lg * 4 + reg][ct * 16 + lc] = f2bf(o[ct][reg]);
  __syncthreads();

  const int b = row0 >> 12;
  const int pos0 = pos_offset + (row0 & 4095);
  {
    const int r = tid >> 2, part = tid & 3;
    unsigned short* dst = OUT + (((size_t)b * Hout + h) * NTOK + pos0 + r) * 64 + part * 16;
    short8v u0 = *(const short8v*)&Tsh[r][part * 16];
    short8v u1 = *(const short8v*)&Tsh[r][part * 16 + 8];
    *(short8v*)dst = u0;
    *(short8v*)(dst + 8) = u1;
  }
  if (mode == 1) {
    const int e = tid >> 2, part = tid & 3;
    short8v t0, t1;
    #pragma unroll
    for (int i = 0; i < 8; i++) t0[i] = (short)Tsh[part * 16 + i][e];
    #pragma unroll
    for (int i = 0; i < 8; i++) t1[i] = (short)Tsh[part * 16 + 8 + i][e];
    unsigned short* dstT = OUTT + (((size_t)b * NKV + h) * 64 + e) * NTOK + pos0 + part * 16;
    *(short8v*)dstT = t0;
    *(short8v*)(dstT + 8) = t1;
  }
}

// ---------------------------------------------------------------------------
// Per-segment summaries from bf16 K, V (row-major):
// ST[e][d] = sum_n v[n,e]*sk[n,d] ; z[d] = sum_n sk[n,d] ; sk = elu(k)+1
// ---------------------------------------------------------------------------
__global__ __launch_bounds__(256, 2) void seg_summary_kernel(
    const unsigned short* __restrict__ K, const unsigned short* __restrict__ V,
    float* __restrict__ S, float* __restrict__ Z)
{
  __shared__ float SK[64][65];
  __shared__ float SV[64][65];
  const int blk = blockIdx.x;
  const int seg = blk & 7;
  const int bkv = blk >> 3;
  const unsigned short* Kp = K + ((size_t)bkv * NTOK + seg * SEGL) * 64;
  const unsigned short* Vp = V + ((size_t)bkv * NTOK + seg * SEGL) * 64;
  const int tid = threadIdx.x;
  const int e = tid >> 2;
  const int d0 = (tid & 3) * 16;

  float acc[16] = {};
  float zacc[16] = {};
  for (int n0 = 0; n0 < SEGL; n0 += 64) {
    #pragma unroll
    for (int i = 0; i < 16; i++) {
      int idx = i * 256 + tid;
      int r = idx >> 6, c = idx & 63;
      float kvv = bf2f(Kp[(size_t)(n0 + r) * 64 + c]);
      SK[r][c] = kvv > 0.f ? kvv + 1.f : __expf(kvv);
      SV[r][c] = bf2f(Vp[(size_t)(n0 + r) * 64 + c]);
    }
    __syncthreads();
    for (int n = 0; n < 64; n++) {
      float vv = SV[n][e];
      #pragma unroll
      for (int i = 0; i < 16; i++) acc[i] += vv * SK[n][d0 + i];
      if (e == 0) {
        #pragma unroll
        for (int i = 0; i < 16; i++) zacc[i] += SK[n][d0 + i];
      }
    }
    __syncthreads();
  }
  float* Sp = S + (size_t)blk * 4096;
  #pragma unroll
  for (int i = 0; i < 16; i++) Sp[e * 64 + d0 + i] = acc[i];
  if (e == 0) {
    float* Zp = Z + (size_t)blk * 64;
    #pragma unroll
    for (int i = 0; i < 16; i++) Zp[d0 + i] = zacc[i];
  }
}

// Exclusive prefix over segments -> bf16 PT + f32 PZ.
__global__ void prefix_kernel(const float* __restrict__ S, const float* __restrict__ Z,
                              unsigned short* __restrict__ PT, float* __restrict__ PZ)
{
  const int bkv = blockIdx.x;
  const int tid = threadIdx.x;
  for (int i = tid; i < 4096; i += 256) {
    float run = 0.f;
    for (int s = 0; s < NSEG; s++) {
      PT[((size_t)bkv * NSEG + s) * 4096 + i] = f2bf(run);
      run += S[((size_t)bkv * NSEG + s) * 4096 + i];
    }
  }
  if (tid < 64) {
    float run = 0.f;
    for (int s = 0; s < NSEG; s++) {
      PZ[((size_t)bkv * NSEG + s) * 64 + tid] = run;
      run += Z[((size_t)bkv * NSEG + s) * 64 + tid];
    }
  }
}

// ---------------------------------------------------------------------------
// MFMA flash attention. Block = (b,h,seg,qtile of 64 rows). 4 waves x 16 rows.
// ---------------------------------------------------------------------------
__global__ __launch_bounds__(256, 2) void attn_mfma_kernel(
    const unsigned short* __restrict__ Qb, const unsigned short* __restrict__ Kb,
    const unsigned short* __restrict__ Vt, const unsigned short* __restrict__ PT,
    const float* __restrict__ PZ, const float* __restrict__ beta,
    float* __restrict__ OUT)
{
  __shared__ unsigned short P_lds[4][2][16][72];
  const int tid = threadIdx.x;
  const int w = tid >> 6;
  const int l = tid & 63;
  const int lc = l & 15;
  const int lg = l >> 4;

  const int qt  = blockIdx.x & 15;
  const int seg = (blockIdx.x >> 4) & 7;
  const int bh  = blockIdx.x >> 7;
  const int h = bh & (NH - 1), b = bh >> 3;
  const int bkv = b * NKV + (h & (NKV - 1));   // jnp.tile -> h % KVH

  const int q0 = qt * 64;
  const int segbase = seg * SEGL;

  const unsigned short* qptr =
      Qb + (((size_t)bh * NTOK) + segbase + q0 + w * 16 + lc) * 64 + lg * 8;
  const short8v aq0 = *(const short8v*)(qptr);
  const short8v aq1 = *(const short8v*)(qptr + 32);

  f32x4 O[4];
  #pragma unroll
  for (int ct = 0; ct < 4; ct++) { O[ct][0]=0.f; O[ct][1]=0.f; O[ct][2]=0.f; O[ct][3]=0.f; }
  float rmax[4] = {-1e30f, -1e30f, -1e30f, -1e30f};
  float rsum[4] = {0.f, 0.f, 0.f, 0.f};

  const unsigned short* Kbase = Kb + ((size_t)bkv * NTOK + segbase) * 64;
  const unsigned short* Vbase = Vt + ((size_t)bkv * 64) * NTOK + segbase;
  const int rloc = w * 16 + lg * 4;

  for (int kt = 0; kt <= qt; ++kt) {
    f32x4 s[4];
    #pragma unroll
    for (int ct = 0; ct < 4; ct++) { s[ct][0]=0.f; s[ct][1]=0.f; s[ct][2]=0.f; s[ct][3]=0.f; }
    const unsigned short* kp = Kbase + (size_t)(kt * 64 + lc) * 64 + lg * 8;
    #pragma unroll
    for (int ct = 0; ct < 4; ct++) {
      short8v bk0 = *(const short8v*)(kp + (size_t)ct * 16 * 64);
      short8v bk1 = *(const short8v*)(kp + (size_t)ct * 16 * 64 + 32);
      s[ct] = __builtin_amdgcn_mfma_f32_16x16x32_bf16(aq0, bk0, s[ct], 0, 0, 0);
      s[ct] = __builtin_amdgcn_mfma_f32_16x16x32_bf16(aq1, bk1, s[ct], 0, 0, 0);
    }
    const bool diag = (kt == qt);
    float sc[4][4];
    #pragma unroll
    for (int ct = 0; ct < 4; ct++) {
      const int cl = ct * 16 + lc;
      #pragma unroll
      for (int i = 0; i < 4; i++) {
        float v = s[ct][i] * 0.125f;
        if (diag && cl > rloc + i) v = -1e30f;
        sc[ct][i] = v;
      }
    }
    float tm[4], ts[4];
    #pragma unroll
    for (int i = 0; i < 4; i++)
      tm[i] = fmaxf(fmaxf(sc[0][i], sc[1][i]), fmaxf(sc[2][i], sc[3][i]));
    #pragma unroll
    for (int off = 1; off < 16; off <<= 1) {
      #pragma unroll
      for (int i = 0; i < 4; i++) tm[i] = fmaxf(tm[i], __shfl_xor(tm[i], off, 64));
    }
    #pragma unroll
    for (int i = 0; i < 4; i++) {
      float nm = fmaxf(rmax[i], tm[i]);
      float corr = __expf(rmax[i] - nm);
      rmax[i] = nm;
      rsum[i] *= corr;
      O[0][i] *= corr; O[1][i] *= corr; O[2][i] *= corr; O[3][i] *= corr;
      ts[i] = 0.f;
    }
    unsigned short pb[4][4];
    #pragma unroll
    for (int ct = 0; ct < 4; ct++)
      #pragma unroll
      for (int i = 0; i < 4; i++) {
        float p = __expf(sc[ct][i] - rmax[i]);
        ts[i] += p;
        pb[ct][i] = f2bf(p);
      }
    #pragma unroll
    for (int off = 1; off < 16; off <<= 1) {
      #pragma unroll
      for (int i = 0; i < 4; i++) ts[i] += __shfl_xor(ts[i], off, 64);
    }
    #pragma unroll
    for (int i = 0; i < 4; i++) rsum[i] += ts[i];

    const int buf = kt & 1;
    #pragma unroll
    for (int ct = 0; ct < 4; ct++)
      #pragma unroll
      for (int i = 0; i < 4; i++)
        P_lds[w][buf][lg * 4 + i][ct * 16 + lc] = pb[ct][i];
    asm volatile("s_waitcnt lgkmcnt(0)" ::: "memory");
    __builtin_amdgcn_sched_barrier(0);
    const unsigned short* pp = &P_lds[w][buf][lc][lg * 8];
    short8v ap0 = *(const short8v*)(pp);
    short8v ap1 = *(const short8v*)(pp + 32);
    const unsigned short* vp = Vbase + (size_t)lc * NTOK + kt * 64 + lg * 8;
    #pragma unroll
    for (int ct = 0; ct < 4; ct++) {
      short8v bv0 = *(const short8v*)(vp + (size_t)ct * 16 * NTOK);
      short8v bv1 = *(const short8v*)(vp + (size_t)ct * 16 * NTOK + 32);
      O[ct] = __builtin_amdgcn_mfma_f32_16x16x32_bf16(ap0, bv0, O[ct], 0, 0, 0);
      O[ct] = __builtin_amdgcn_mfma_f32_16x16x32_bf16(ap1, bv1, O[ct], 0, 0, 0);
    }
  }

  float sqf[2][8];
  short8v asq0, asq1;
  #pragma unroll
  for (int i = 0; i < 8; i++) {
    float f0 = bf2f((unsigned short)aq0[i]);
    float e0 = f0 > 0.f ? f0 + 1.f : __expf(f0);
    sqf[0][i] = e0; asq0[i] = (short)f2bf(e0);
    float f1 = bf2f((unsigned short)aq1[i]);
    float e1 = f1 > 0.f ? f1 + 1.f : __expf(f1);
    sqf[1][i] = e1; asq1[i] = (short)f2bf(e1);
  }
  f32x4 N[4];
  #pragma unroll
  for (int ct = 0; ct < 4; ct++) { N[ct][0]=0.f; N[ct][1]=0.f; N[ct][2]=0.f; N[ct][3]=0.f; }
  const unsigned short* stp = PT + ((size_t)bkv * NSEG + seg) * 4096 + lc * 64 + lg * 8;
  #pragma unroll
  for (int ct = 0; ct < 4; ct++) {
    short8v bs0 = *(const short8v*)(stp + ct * 16 * 64);
    short8v bs1 = *(const short8v*)(stp + ct * 16 * 64 + 32);
    N[ct] = __builtin_amdgcn_mfma_f32_16x16x32_bf16(asq0, bs0, N[ct], 0, 0, 0);
    N[ct] = __builtin_amdgcn_mfma_f32_16x16x32_bf16(asq1, bs1, N[ct], 0, 0, 0);
  }
  const float* zp = PZ + ((size_t)bkv * NSEG + seg) * 64 + lg * 8;
  float den = 1e-12f;
  #pragma unroll
  for (int i = 0; i < 8; i++) den += sqf[0][i] * zp[i] + sqf[1][i] * zp[32 + i];
  den += __shfl_xor(den, 16, 64);
  den += __shfl_xor(den, 32, 64);
  float denc[4];
  #pragma unroll
  for (int reg = 0; reg < 4; reg++) denc[reg] = __shfl(den, lg * 4 + reg, 64);

  const float g = 1.f / (1.f + __expf(-beta[h]));
  const float g1 = 1.f - g;
  const int nrow = segbase + q0 + w * 16 + lg * 4;

  #pragma unroll
  for (int reg = 0; reg < 4; reg++) {
    const int n = nrow + reg;
    const float invs = 1.f / rsum[reg];
    const float invd = 1.f / denc[reg];
    size_t obase;
    if (n < 4096) obase = (size_t)BATCH * 4096 * 512 + (((size_t)b * 4096 + n) * NH + h) * 64;
    else          obase = (((size_t)b * 4096 + (n - 4096)) * NH + h) * 64;
    #pragma unroll
    for (int ct = 0; ct < 4; ct++) {
      OUT[obase + ct * 16 + lc] = g * N[ct][reg] * invd + g1 * O[ct][reg] * invs;
    }
  }
}

// ---------------------------------------------------------------------------
extern "C" void kernel_launch(void* const* d_in, const int* in_sizes, int n_in,
                              void* d_out, int out_size, void* d_ws, size_t ws_size,
                              hipStream_t stream) {
  const float* x    = (const float*)d_in[0];
  const float* a    = (const float*)d_in[1];
  const float* Wq_x = (const float*)d_in[2];
  const float* Wk_x = (const float*)d_in[3];
  const float* Wv_x = (const float*)d_in[4];
  const float* Wq_a = (const float*)d_in[5];
  const float* Wk_a = (const float*)d_in[6];
  const float* Wv_a = (const float*)d_in[7];
  const float* gq_x = (const float*)d_in[8];
  const float* gk_x = (const float*)d_in[9];
  const float* gq_a = (const float*)d_in[10];
  const float* gk_a = (const float*)d_in[11];
  const float* beta = (const float*)d_in[12];

  unsigned short* Qb = (unsigned short*)d_ws;          // 8388608
  unsigned short* Kb = Qb + (size_t)8388608;           // 2097152
  unsigned short* Vb = Kb + (size_t)2097152;           // 2097152
  unsigned short* Vt = Vb + (size_t)2097152;           // 2097152
  unsigned short* Xa = Vt + (size_t)2097152;           // 4194304
  unsigned short* Xx = Xa + (size_t)4194304;           // 4194304
  unsigned short* WtQa = Xx + (size_t)4194304;         // 262144
  unsigned short* WtKa = WtQa + (size_t)262144;        // 65536
  unsigned short* WtVa = WtKa + (size_t)65536;         // 65536
  unsigned short* WtQx = WtVa + (size_t)65536;         // 262144
  unsigned short* WtKx = WtQx + (size_t)262144;        // 65536
  unsigned short* WtVx = WtKx + (size_t)65536;         // 65536
  float* S  = (float*)(WtVx + (size_t)65536);          // 131072 f32
  float* Z  = S + (size_t)131072;                      // 2048
  float* PZ = Z + (size_t)2048;                        // 2048
  unsigned short* PT = (unsigned short*)(PZ + (size_t)2048); // 131072

  cast_bf16_kernel<<<2048, 256, 0, stream>>>(a, Xa, 524288);
  cast_bf16_kernel<<<2048, 256, 0, stream>>>(x, Xx, 524288);
  wtrans_kernel<<<dim3(16, 16), 256, 0, stream>>>(Wq_a, WtQa, 512);
  wtrans_kernel<<<dim3(4, 16), 256, 0, stream>>>(Wk_a, WtKa, 128);
  wtrans_kernel<<<dim3(4, 16), 256, 0, stream>>>(Wv_a, WtVa, 128);
  wtrans_kernel<<<dim3(16, 16), 256, 0, stream>>>(Wq_x, WtQx, 512);
  wtrans_kernel<<<dim3(4, 16), 256, 0, stream>>>(Wk_x, WtKx, 128);
  wtrans_kernel<<<dim3(4, 16), 256, 0, stream>>>(Wv_x, WtVx, 128);

  // a -> positions 0..4095, x -> positions 4096..8191
  proj_mfma_kernel<<<dim3(128, 8), 256, 0, stream>>>(Xa, WtQa, gq_a, Qb, nullptr, 8, 0, 0);
  proj_mfma_kernel<<<dim3(128, 2), 256, 0, stream>>>(Xa, WtKa, gk_a, Kb, nullptr, 2, 0, 0);
  proj_mfma_kernel<<<dim3(128, 2), 256, 0, stream>>>(Xa, WtVa, nullptr, Vb, Vt, 2, 0, 1);
  proj_mfma_kernel<<<dim3(128, 8), 256, 0, stream>>>(Xx, WtQx, gq_x, Qb, nullptr, 8, 4096, 0);
  proj_mfma_kernel<<<dim3(128, 2), 256, 0, stream>>>(Xx, WtKx, gk_x, Kb, nullptr, 2, 4096, 0);
  proj_mfma_kernel<<<dim3(128, 2), 256, 0, stream>>>(Xx, WtVx, nullptr, Vb, Vt, 2, 4096, 1);

  seg_summary_kernel<<<32, 256, 0, stream>>>(Kb, Vb, S, Z);
  prefix_kernel<<<4, 256, 0, stream>>>(S, Z, PT, PZ);

  attn_mfma_kernel<<<dim3(2048), 256, 0, stream>>>(Qb, Kb, Vt, PT, PZ, beta, (float*)d_out);
}

// Round 5
// 502.022 us; speedup vs baseline: 3.3726x; 1.1908x over previous
//
#include <hip/hip_runtime.h>
#include <math.h>

#define NH 8
#define NKV 2
#define SEGL 1024
#define NSEG 8
#define NTOK 8192
#define BATCH 2
#define DIMK 512

typedef short short8v __attribute__((ext_vector_type(8)));
typedef short short4v __attribute__((ext_vector_type(4)));
typedef float f32x4 __attribute__((ext_vector_type(4)));

__device__ __forceinline__ unsigned short f2bf(float f) {
  union { float f; unsigned u; } c; c.f = f;
  unsigned u = c.u;
  return (unsigned short)((u + 0x7FFFu + ((u >> 16) & 1u)) >> 16);
}
__device__ __forceinline__ float bf2f(unsigned short h) {
  union { unsigned u; float f; } c; c.u = ((unsigned)h) << 16;
  return c.f;
}

// ---------------------------------------------------------------------------
// f32 -> bf16 cast; y selects input (0 = a, 1 = x).
// ---------------------------------------------------------------------------
__global__ void cast_bf16_kernel(const float* __restrict__ a, const float* __restrict__ x,
                                 unsigned short* __restrict__ outa,
                                 unsigned short* __restrict__ outx) {
  const float* in = blockIdx.y ? x : a;
  unsigned short* out = blockIdx.y ? outx : outa;
  int i = blockIdx.x * blockDim.x + threadIdx.x;
  const float4* p = (const float4*)in + (size_t)i * 2;
  float4 v0 = p[0], v1 = p[1];
  short8v o;
  o[0] = (short)f2bf(v0.x); o[1] = (short)f2bf(v0.y);
  o[2] = (short)f2bf(v0.z); o[3] = (short)f2bf(v0.w);
  o[4] = (short)f2bf(v1.x); o[5] = (short)f2bf(v1.y);
  o[6] = (short)f2bf(v1.z); o[7] = (short)f2bf(v1.w);
  *((short8v*)out + i) = o;
}

// ---------------------------------------------------------------------------
// W (512 x C) f32 -> Wt (C x 512) bf16; z selects which of the 6 weights.
// ---------------------------------------------------------------------------
__global__ void wtrans_kernel(const float* __restrict__ w0, const float* __restrict__ w1,
                              const float* __restrict__ w2, const float* __restrict__ w3,
                              const float* __restrict__ w4, const float* __restrict__ w5,
                              unsigned short* __restrict__ o0, unsigned short* __restrict__ o1,
                              unsigned short* __restrict__ o2, unsigned short* __restrict__ o3,
                              unsigned short* __restrict__ o4, unsigned short* __restrict__ o5) {
  __shared__ float T[32][33];
  const int z = blockIdx.z;
  const float* in; unsigned short* out; int C;
  switch (z) {
    case 0: in = w0; out = o0; C = 512; break;
    case 1: in = w1; out = o1; C = 128; break;
    case 2: in = w2; out = o2; C = 128; break;
    case 3: in = w3; out = o3; C = 512; break;
    case 4: in = w4; out = o4; C = 128; break;
    default: in = w5; out = o5; C = 128; break;
  }
  const int c0 = blockIdx.x * 32, k0 = blockIdx.y * 32;
  if (c0 >= C) return;
  const int tx = threadIdx.x & 31, ty = threadIdx.x >> 5;
  #pragma unroll
  for (int i = 0; i < 4; i++)
    T[ty + i * 8][tx] = in[(size_t)(k0 + ty + i * 8) * C + c0 + tx];
  __syncthreads();
  #pragma unroll
  for (int i = 0; i < 4; i++)
    out[(size_t)(c0 + ty + i * 8) * 512 + k0 + tx] = f2bf(T[tx][ty + i * 8]);
}

// ---------------------------------------------------------------------------
// Merged MFMA projection. grid (128, 12, 2):
//   z: input (0=a pos 0..4095, 1=x pos 4096..8191)
//   y: 0-7 -> Q head y (norm+rope); 8-9 -> K head y-8 (norm+rope, +Kt);
//      10-11 -> V head y-10 (plain, Vt only)
// ---------------------------------------------------------------------------
__global__ __launch_bounds__(256) void proj_all_kernel(
    const unsigned short* __restrict__ Xa, const unsigned short* __restrict__ Xx,
    const unsigned short* __restrict__ WtQa, const unsigned short* __restrict__ WtKa,
    const unsigned short* __restrict__ WtVa, const unsigned short* __restrict__ WtQx,
    const unsigned short* __restrict__ WtKx, const unsigned short* __restrict__ WtVx,
    const float* __restrict__ gq_a, const float* __restrict__ gk_a,
    const float* __restrict__ gq_x, const float* __restrict__ gk_x,
    unsigned short* __restrict__ Qb, unsigned short* __restrict__ Kb,
    unsigned short* __restrict__ Kt, unsigned short* __restrict__ Vt)
{
  __shared__ unsigned short Tsh[64][72];
  const int tid = threadIdx.x;
  const int w = tid >> 6, l = tid & 63, lc = l & 15, lg = l >> 4;
  const int z = blockIdx.z;
  const int y = blockIdx.y;
  const int row0 = blockIdx.x * 64;
  const int pos_offset = z ? 4096 : 0;

  const unsigned short* Xbf = z ? Xx : Xa;
  const unsigned short* Wt;
  const float* gamma = nullptr;
  unsigned short* OUT = nullptr;
  unsigned short* OUTT = nullptr;
  int h, Hout, doNR;
  if (y < 8) {
    h = y; Hout = NH; doNR = 1;
    Wt = z ? WtQx : WtQa; gamma = z ? gq_x : gq_a; OUT = Qb;
  } else if (y < 10) {
    h = y - 8; Hout = NKV; doNR = 1;
    Wt = z ? WtKx : WtKa; gamma = z ? gk_x : gk_a; OUT = Kb; OUTT = Kt;
  } else {
    h = y - 10; Hout = NKV; doNR = 0;
    Wt = z ? WtVx : WtVa; OUTT = Vt;
  }

  const unsigned short* ap = Xbf + (size_t)(row0 + w * 16 + lc) * 512 + lg * 8;
  const unsigned short* bp = Wt + (size_t)(h * 64 + lc) * 512 + lg * 8;

  f32x4 acc[4];
  #pragma unroll
  for (int ct = 0; ct < 4; ct++) { acc[ct][0]=0.f; acc[ct][1]=0.f; acc[ct][2]=0.f; acc[ct][3]=0.f; }

  #pragma unroll 4
  for (int kc = 0; kc < 16; kc++) {
    short8v av = *(const short8v*)(ap + kc * 32);
    #pragma unroll
    for (int ct = 0; ct < 4; ct++) {
      short8v bv = *(const short8v*)(bp + (size_t)(ct * 16 * 512) + kc * 32);
      acc[ct] = __builtin_amdgcn_mfma_f32_16x16x32_bf16(av, bv, acc[ct], 0, 0, 0);
    }
  }

  float o[4][4];
  if (doNR) {
    float srow[4];
    #pragma unroll
    for (int reg = 0; reg < 4; reg++) {
      float ss = acc[0][reg]*acc[0][reg] + acc[1][reg]*acc[1][reg]
               + acc[2][reg]*acc[2][reg] + acc[3][reg]*acc[3][reg];
      ss += __shfl_xor(ss, 1, 64);
      ss += __shfl_xor(ss, 2, 64);
      ss += __shfl_xor(ss, 4, 64);
      ss += __shfl_xor(ss, 8, 64);
      srow[reg] = 8.0f / fmaxf(sqrtf(ss), 1e-12f);
    }
    float gam[4];
    #pragma unroll
    for (int ct = 0; ct < 4; ct++) gam[ct] = gamma[h * 64 + ct * 16 + lc];
    const float LOG1E4 = 9.210340371976184f;
    float invf[2];
    invf[0] = __expf(-((float)lc / 32.f) * LOG1E4);
    invf[1] = __expf(-((float)(16 + lc) / 32.f) * LOG1E4);
    const int posb = pos_offset + (row0 & 4095) + w * 16 + lg * 4;
    #pragma unroll
    for (int reg = 0; reg < 4; reg++) {
      #pragma unroll
      for (int half = 0; half < 2; half++) {
        float ang = (float)(posb + reg) * invf[half];
        float sn, cs;
        sincosf(ang, &sn, &cs);
        float v1 = acc[half][reg] * srow[reg] * gam[half];
        float v2 = acc[half + 2][reg] * srow[reg] * gam[half + 2];
        o[half][reg]     = v1 * cs - v2 * sn;
        o[half + 2][reg] = v2 * cs + v1 * sn;
      }
    }
  } else {
    #pragma unroll
    for (int ct = 0; ct < 4; ct++)
      #pragma unroll
      for (int reg = 0; reg < 4; reg++) o[ct][reg] = acc[ct][reg];
  }

  #pragma unroll
  for (int ct = 0; ct < 4; ct++)
    #pragma unroll
    for (int reg = 0; reg < 4; reg++)
      Tsh[w * 16 + lg * 4 + reg][ct * 16 + lc] = f2bf(o[ct][reg]);
  __syncthreads();

  const int b = row0 >> 12;
  const int pos0 = pos_offset + (row0 & 4095);
  if (OUT) {
    const int r = tid >> 2, part = tid & 3;
    unsigned short* dst = OUT + (((size_t)b * Hout + h) * NTOK + pos0 + r) * 64 + part * 16;
    short8v u0 = *(const short8v*)&Tsh[r][part * 16];
    short8v u1 = *(const short8v*)&Tsh[r][part * 16 + 8];
    *(short8v*)dst = u0;
    *(short8v*)(dst + 8) = u1;
  }
  if (OUTT) {
    const int e = tid >> 2, part = tid & 3;
    short8v t0, t1;
    #pragma unroll
    for (int i = 0; i < 8; i++) t0[i] = (short)Tsh[part * 16 + i][e];
    #pragma unroll
    for (int i = 0; i < 8; i++) t1[i] = (short)Tsh[part * 16 + 8 + i][e];
    unsigned short* dstT = OUTT + (((size_t)b * NKV + h) * 64 + e) * NTOK + pos0 + part * 16;
    *(short8v*)dstT = t0;
    *(short8v*)(dstT + 8) = t1;
  }
}

// ---------------------------------------------------------------------------
// Per-segment summaries via MFMA from Kt, Vt (d/e-major, n contiguous):
// S[e][d] = sum_n Vt[e][n] * (elu(Kt[d][n])+1) ; Z[d] = sum_n (elu(Kt[d][n])+1)
// ---------------------------------------------------------------------------
__global__ __launch_bounds__(256) void seg_summary_kernel(
    const unsigned short* __restrict__ Kt, const unsigned short* __restrict__ Vt,
    float* __restrict__ S, float* __restrict__ Z)
{
  const int blk = blockIdx.x;
  const int seg = blk & 7;
  const int bkv = blk >> 3;
  const int tid = threadIdx.x;
  const int w = tid >> 6, l = tid & 63, lc = l & 15, lg = l >> 4;
  const unsigned short* KtB = Kt + ((size_t)bkv * 64) * NTOK + seg * SEGL;
  const unsigned short* VtB = Vt + ((size_t)bkv * 64) * NTOK + seg * SEGL;

  f32x4 acc[4];
  #pragma unroll
  for (int ct = 0; ct < 4; ct++) { acc[ct][0]=0.f; acc[ct][1]=0.f; acc[ct][2]=0.f; acc[ct][3]=0.f; }
  float zacc[4] = {0.f, 0.f, 0.f, 0.f};

  for (int n0 = 0; n0 < SEGL; n0 += 32) {
    short8v av = *(const short8v*)(VtB + (size_t)(w * 16 + lc) * NTOK + n0 + lg * 8);
    #pragma unroll
    for (int ct = 0; ct < 4; ct++) {
      short8v kv = *(const short8v*)(KtB + (size_t)(ct * 16 + lc) * NTOK + n0 + lg * 8);
      short8v skv;
      float zp = 0.f;
      #pragma unroll
      for (int i = 0; i < 8; i++) {
        float kf = bf2f((unsigned short)kv[i]);
        float sk = kf > 0.f ? kf + 1.f : __expf(kf);
        zp += sk;
        skv[i] = (short)f2bf(sk);
      }
      zacc[ct] += zp;
      acc[ct] = __builtin_amdgcn_mfma_f32_16x16x32_bf16(av, skv, acc[ct], 0, 0, 0);
    }
  }

  float* Sp = S + (size_t)blk * 4096;
  #pragma unroll
  for (int ct = 0; ct < 4; ct++)
    #pragma unroll
    for (int reg = 0; reg < 4; reg++)
      Sp[(size_t)(w * 16 + lg * 4 + reg) * 64 + ct * 16 + lc] = acc[ct][reg];

  if (w == 0) {
    #pragma unroll
    for (int ct = 0; ct < 4; ct++) {
      zacc[ct] += __shfl_xor(zacc[ct], 16, 64);
      zacc[ct] += __shfl_xor(zacc[ct], 32, 64);
    }
    if (lg == 0) {
      float* Zp = Z + (size_t)blk * 64;
      #pragma unroll
      for (int ct = 0; ct < 4; ct++) Zp[ct * 16 + lc] = zacc[ct];
    }
  }
}

// Exclusive prefix over segments -> bf16 PT + f32 PZ.
__global__ void prefix_kernel(const float* __restrict__ S, const float* __restrict__ Z,
                              unsigned short* __restrict__ PT, float* __restrict__ PZ)
{
  const int bkv = blockIdx.x;
  const int tid = threadIdx.x;
  for (int i = tid; i < 4096; i += 256) {
    float run = 0.f;
    for (int s = 0; s < NSEG; s++) {
      PT[((size_t)bkv * NSEG + s) * 4096 + i] = f2bf(run);
      run += S[((size_t)bkv * NSEG + s) * 4096 + i];
    }
  }
  if (tid < 64) {
    float run = 0.f;
    for (int s = 0; s < NSEG; s++) {
      PZ[((size_t)bkv * NSEG + s) * 64 + tid] = run;
      run += Z[((size_t)bkv * NSEG + s) * 64 + tid];
    }
  }
}

// ---------------------------------------------------------------------------
// MFMA flash attention, LDS-free, builtin-only. Block = (b,h,seg,qtile 64 rows).
// Swapped QK^T (S^T: q=lane&15, k=(lane>>4)*4+reg) keeps P in the A-frag slots;
// PV via 16x16x32 with paired ck sub-tiles (k-slot permutation matched in B).
// Fixed softmax max = 8 (RMSNorm bounds |score| <= 8): no online rescale.
// ---------------------------------------------------------------------------
__global__ __launch_bounds__(256, 4) void attn_mfma_kernel(
    const unsigned short* __restrict__ Qb, const unsigned short* __restrict__ Kb,
    const unsigned short* __restrict__ Vt, const unsigned short* __restrict__ PT,
    const float* __restrict__ PZ, const float* __restrict__ beta,
    float* __restrict__ OUT)
{
  const int tid = threadIdx.x;
  const int w = tid >> 6;
  const int l = tid & 63;
  const int lc = l & 15;
  const int lg = l >> 4;

  const int qt  = blockIdx.x & 15;
  const int seg = (blockIdx.x >> 4) & 7;
  const int bh  = blockIdx.x >> 7;
  const int h = bh & (NH - 1), b = bh >> 3;
  const int bkv = b * NKV + (h & (NKV - 1));   // jnp.tile -> h % KVH

  const int q0 = qt * 64;
  const int segbase = seg * SEGL;

  // Q fragments: q-row = w*16+lc, k(d) = lg*8+i (+32)
  const unsigned short* qptr =
      Qb + (((size_t)bh * NTOK) + segbase + q0 + w * 16 + lc) * 64 + lg * 8;
  const short8v aq0 = *(const short8v*)(qptr);
  const short8v aq1 = *(const short8v*)(qptr + 32);

  f32x4 O[4];   // q = lg*4+reg (within wave strip), e = ce*16+lc
  #pragma unroll
  for (int ce = 0; ce < 4; ce++) { O[ce][0]=0.f; O[ce][1]=0.f; O[ce][2]=0.f; O[ce][3]=0.f; }
  float rsumL = 0.f;   // per-lane partial softmax sum for q = lc

  const unsigned short* Kbase = Kb + ((size_t)bkv * NTOK + segbase) * 64;
  const unsigned short* Vbase = Vt + ((size_t)bkv * 64) * NTOK + segbase;

  for (int kt = 0; kt <= qt; ++kt) {
    const bool diag = (kt == qt);
    const int ctmax = diag ? w : 3;

    // ---- S^T = K Q^T, P = exp(s/8 - 8) with causal mask, packed in-lane ----
    short4v pa[4];
    #pragma unroll
    for (int ck = 0; ck < 4; ck++) {
      if (ck > ctmax) {
        pa[ck][0] = 0; pa[ck][1] = 0; pa[ck][2] = 0; pa[ck][3] = 0;
        continue;
      }
      f32x4 s;
      s[0]=0.f; s[1]=0.f; s[2]=0.f; s[3]=0.f;
      const unsigned short* kp = Kbase + (size_t)(kt * 64 + ck * 16 + lc) * 64 + lg * 8;
      short8v ak0 = *(const short8v*)(kp);
      short8v ak1 = *(const short8v*)(kp + 32);
      s = __builtin_amdgcn_mfma_f32_16x16x32_bf16(ak0, aq0, s, 0, 0, 0);
      s = __builtin_amdgcn_mfma_f32_16x16x32_bf16(ak1, aq1, s, 0, 0, 0);
      const bool needmask = diag && (ck == w);
      float p0 = __expf(s[0] * 0.125f - 8.0f);
      float p1 = __expf(s[1] * 0.125f - 8.0f);
      float p2 = __expf(s[2] * 0.125f - 8.0f);
      float p3 = __expf(s[3] * 0.125f - 8.0f);
      if (needmask) {
        if (lg * 4 + 0 > lc) p0 = 0.f;
        if (lg * 4 + 1 > lc) p1 = 0.f;
        if (lg * 4 + 2 > lc) p2 = 0.f;
        if (lg * 4 + 3 > lc) p3 = 0.f;
      }
      rsumL += p0 + p1 + p2 + p3;
      pa[ck][0] = (short)f2bf(p0);
      pa[ck][1] = (short)f2bf(p1);
      pa[ck][2] = (short)f2bf(p2);
      pa[ck][3] = (short)f2bf(p3);
    }

    // ---- O += P V via 16x16x32, pairing ck sub-tiles (cp covers k=cp*32..+31).
    // A slot i<4 -> k=cp*32+lg*4+i ; slot 4+i -> k=cp*32+16+lg*4+i; B matches. ----
    #pragma unroll
    for (int cp = 0; cp < 2; cp++) {
      if (cp * 2 > ctmax) continue;
      short8v a8;
      #pragma unroll
      for (int i = 0; i < 4; i++) { a8[i] = pa[cp * 2][i]; a8[4 + i] = pa[cp * 2 + 1][i]; }
      #pragma unroll
      for (int ce = 0; ce < 4; ce++) {
        const unsigned short* vb = Vbase + (size_t)(ce * 16 + lc) * NTOK
                                   + kt * 64 + cp * 32 + lg * 4;
        short4v b0 = *(const short4v*)(vb);
        short4v b1 = *(const short4v*)(vb + 16);
        short8v b8;
        #pragma unroll
        for (int i = 0; i < 4; i++) { b8[i] = b0[i]; b8[4 + i] = b1[i]; }
        O[ce] = __builtin_amdgcn_mfma_f32_16x16x32_bf16(a8, b8, O[ce], 0, 0, 0);
      }
    }
  }

  // deferred softmax-sum reduction (q = lc)
  rsumL += __shfl_xor(rsumL, 16, 64);
  rsumL += __shfl_xor(rsumL, 32, 64);

  // ---- memory path: sq = elu(q)+1 ; N = sq @ ST ; den = sq . z ----
  float sqf[2][8];
  short8v asq0, asq1;
  #pragma unroll
  for (int i = 0; i < 8; i++) {
    float f0 = bf2f((unsigned short)aq0[i]);
    float e0 = f0 > 0.f ? f0 + 1.f : __expf(f0);
    sqf[0][i] = e0; asq0[i] = (short)f2bf(e0);
    float f1 = bf2f((unsigned short)aq1[i]);
    float e1 = f1 > 0.f ? f1 + 1.f : __expf(f1);
    sqf[1][i] = e1; asq1[i] = (short)f2bf(e1);
  }
  f32x4 N[4];
  #pragma unroll
  for (int ct = 0; ct < 4; ct++) { N[ct][0]=0.f; N[ct][1]=0.f; N[ct][2]=0.f; N[ct][3]=0.f; }
  const unsigned short* stp = PT + ((size_t)bkv * NSEG + seg) * 4096 + lc * 64 + lg * 8;
  #pragma unroll
  for (int ct = 0; ct < 4; ct++) {
    short8v bs0 = *(const short8v*)(stp + ct * 16 * 64);
    short8v bs1 = *(const short8v*)(stp + ct * 16 * 64 + 32);
    N[ct] = __builtin_amdgcn_mfma_f32_16x16x32_bf16(asq0, bs0, N[ct], 0, 0, 0);
    N[ct] = __builtin_amdgcn_mfma_f32_16x16x32_bf16(asq1, bs1, N[ct], 0, 0, 0);
  }
  const float* zp = PZ + ((size_t)bkv * NSEG + seg) * 64 + lg * 8;
  float den = 1e-12f;
  #pragma unroll
  for (int i = 0; i < 8; i++) den += sqf[0][i] * zp[i] + sqf[1][i] * zp[32 + i];
  den += __shfl_xor(den, 16, 64);
  den += __shfl_xor(den, 32, 64);
  float denc[4], rs[4];
  #pragma unroll
  for (int reg = 0; reg < 4; reg++) {
    denc[reg] = __shfl(den, lg * 4 + reg, 64);
    rs[reg]   = __shfl(rsumL, lg * 4 + reg, 64);
  }

  const float g = 1.f / (1.f + __expf(-beta[h]));
  const float g1 = 1.f - g;
  const int nrow = segbase + q0 + w * 16 + lg * 4;

  #pragma unroll
  for (int reg = 0; reg < 4; reg++) {
    const int n = nrow + reg;
    const float invs = 1.f / rs[reg];
    const float invd = 1.f / denc[reg];
    size_t obase;
    if (n < 4096) obase = (size_t)BATCH * 4096 * 512 + (((size_t)b * 4096 + n) * NH + h) * 64;
    else          obase = (((size_t)b * 4096 + (n - 4096)) * NH + h) * 64;
    #pragma unroll
    for (int ce = 0; ce < 4; ce++) {
      OUT[obase + ce * 16 + lc] = g * N[ce][reg] * invd + g1 * O[ce][reg] * invs;
    }
  }
}

// ---------------------------------------------------------------------------
extern "C" void kernel_launch(void* const* d_in, const int* in_sizes, int n_in,
                              void* d_out, int out_size, void* d_ws, size_t ws_size,
                              hipStream_t stream) {
  const float* x    = (const float*)d_in[0];
  const float* a    = (const float*)d_in[1];
  const float* Wq_x = (const float*)d_in[2];
  const float* Wk_x = (const float*)d_in[3];
  const float* Wv_x = (const float*)d_in[4];
  const float* Wq_a = (const float*)d_in[5];
  const float* Wk_a = (const float*)d_in[6];
  const float* Wv_a = (const float*)d_in[7];
  const float* gq_x = (const float*)d_in[8];
  const float* gk_x = (const float*)d_in[9];
  const float* gq_a = (const float*)d_in[10];
  const float* gk_a = (const float*)d_in[11];
  const float* beta = (const float*)d_in[12];

  unsigned short* Qb = (unsigned short*)d_ws;          // 8388608
  unsigned short* Kb = Qb + (size_t)8388608;           // 2097152
  unsigned short* Kt = Kb + (size_t)2097152;           // 2097152
  unsigned short* Vt = Kt + (size_t)2097152;           // 2097152
  unsigned short* Xa = Vt + (size_t)2097152;           // 4194304
  unsigned short* Xx = Xa + (size_t)4194304;           // 4194304
  unsigned short* WtQa = Xx + (size_t)4194304;         // 262144
  unsigned short* WtKa = WtQa + (size_t)262144;        // 65536
  unsigned short* WtVa = WtKa + (size_t)65536;         // 65536
  unsigned short* WtQx = WtVa + (size_t)65536;         // 262144
  unsigned short* WtKx = WtQx + (size_t)262144;        // 65536
  unsigned short* WtVx = WtKx + (size_t)65536;         // 65536
  float* S  = (float*)(WtVx + (size_t)65536);          // 131072 f32
  float* Z  = S + (size_t)131072;                      // 2048
  float* PZ = Z + (size_t)2048;                        // 2048
  unsigned short* PT = (unsigned short*)(PZ + (size_t)2048); // 131072

  cast_bf16_kernel<<<dim3(2048, 2), 256, 0, stream>>>(a, x, Xa, Xx);
  wtrans_kernel<<<dim3(16, 16, 6), 256, 0, stream>>>(
      Wq_a, Wk_a, Wv_a, Wq_x, Wk_x, Wv_x, WtQa, WtKa, WtVa, WtQx, WtKx, WtVx);
  proj_all_kernel<<<dim3(128, 12, 2), 256, 0, stream>>>(
      Xa, Xx, WtQa, WtKa, WtVa, WtQx, WtKx, WtVx,
      gq_a, gk_a, gq_x, gk_x, Qb, Kb, Kt, Vt);
  seg_summary_kernel<<<32, 256, 0, stream>>>(Kt, Vt, S, Z);
  prefix_kernel<<<4, 256, 0, stream>>>(S, Z, PT, PZ);
  attn_mfma_kernel<<<dim3(2048), 256, 0, stream>>>(Qb, Kb, Vt, PT, PZ, beta, (float*)d_out);
}

// Round 6
// 281.342 us; speedup vs baseline: 6.0181x; 1.7844x over previous
//
#include <hip/hip_runtime.h>
#include <math.h>

#define NH 8
#define NKV 2
#define SEGL 1024
#define NSEG 8
#define NTOK 8192
#define BATCH 2
#define DIMK 512

typedef short short8v __attribute__((ext_vector_type(8)));
typedef short short4v __attribute__((ext_vector_type(4)));
typedef float f32x4 __attribute__((ext_vector_type(4)));

__device__ __forceinline__ unsigned short f2bf(float f) {
  union { float f; unsigned u; } c; c.f = f;
  unsigned u = c.u;
  return (unsigned short)((u + 0x7FFFu + ((u >> 16) & 1u)) >> 16);
}
__device__ __forceinline__ float bf2f(unsigned short h) {
  union { unsigned u; float f; } c; c.u = ((unsigned)h) << 16;
  return c.f;
}

// ---------------------------------------------------------------------------
// f32 -> bf16 cast; y selects input (0 = a, 1 = x).
// ---------------------------------------------------------------------------
__global__ void cast_bf16_kernel(const float* __restrict__ a, const float* __restrict__ x,
                                 unsigned short* __restrict__ outa,
                                 unsigned short* __restrict__ outx) {
  const float* in = blockIdx.y ? x : a;
  unsigned short* out = blockIdx.y ? outx : outa;
  int i = blockIdx.x * blockDim.x + threadIdx.x;
  const float4* p = (const float4*)in + (size_t)i * 2;
  float4 v0 = p[0], v1 = p[1];
  short8v o;
  o[0] = (short)f2bf(v0.x); o[1] = (short)f2bf(v0.y);
  o[2] = (short)f2bf(v0.z); o[3] = (short)f2bf(v0.w);
  o[4] = (short)f2bf(v1.x); o[5] = (short)f2bf(v1.y);
  o[6] = (short)f2bf(v1.z); o[7] = (short)f2bf(v1.w);
  *((short8v*)out + i) = o;
}

// ---------------------------------------------------------------------------
// W (512 x C) f32 -> Wt (C x 512) bf16; z selects which of the 6 weights.
// ---------------------------------------------------------------------------
__global__ void wtrans_kernel(const float* __restrict__ w0, const float* __restrict__ w1,
                              const float* __restrict__ w2, const float* __restrict__ w3,
                              const float* __restrict__ w4, const float* __restrict__ w5,
                              unsigned short* __restrict__ o0, unsigned short* __restrict__ o1,
                              unsigned short* __restrict__ o2, unsigned short* __restrict__ o3,
                              unsigned short* __restrict__ o4, unsigned short* __restrict__ o5) {
  __shared__ float T[32][33];
  const int z = blockIdx.z;
  const float* in; unsigned short* out; int C;
  switch (z) {
    case 0: in = w0; out = o0; C = 512; break;
    case 1: in = w1; out = o1; C = 128; break;
    case 2: in = w2; out = o2; C = 128; break;
    case 3: in = w3; out = o3; C = 512; break;
    case 4: in = w4; out = o4; C = 128; break;
    default: in = w5; out = o5; C = 128; break;
  }
  const int c0 = blockIdx.x * 32, k0 = blockIdx.y * 32;
  if (c0 >= C) return;
  const int tx = threadIdx.x & 31, ty = threadIdx.x >> 5;
  #pragma unroll
  for (int i = 0; i < 4; i++)
    T[ty + i * 8][tx] = in[(size_t)(k0 + ty + i * 8) * C + c0 + tx];
  __syncthreads();
  #pragma unroll
  for (int i = 0; i < 4; i++)
    out[(size_t)(c0 + ty + i * 8) * 512 + k0 + tx] = f2bf(T[tx][ty + i * 8]);
}

// ---------------------------------------------------------------------------
// Merged MFMA projection. grid (128, 12, 2):
//   z: input (0=a pos 0..4095, 1=x pos 4096..8191)
//   y: 0-7 -> Q head y (norm+rope); 8-9 -> K head y-8 (norm+rope, +Kt);
//      10-11 -> V head y-10 (plain, Vt only)
// ---------------------------------------------------------------------------
__global__ __launch_bounds__(256) void proj_all_kernel(
    const unsigned short* __restrict__ Xa, const unsigned short* __restrict__ Xx,
    const unsigned short* __restrict__ WtQa, const unsigned short* __restrict__ WtKa,
    const unsigned short* __restrict__ WtVa, const unsigned short* __restrict__ WtQx,
    const unsigned short* __restrict__ WtKx, const unsigned short* __restrict__ WtVx,
    const float* __restrict__ gq_a, const float* __restrict__ gk_a,
    const float* __restrict__ gq_x, const float* __restrict__ gk_x,
    unsigned short* __restrict__ Qb, unsigned short* __restrict__ Kb,
    unsigned short* __restrict__ Kt, unsigned short* __restrict__ Vt)
{
  __shared__ unsigned short Tsh[64][72];
  const int tid = threadIdx.x;
  const int w = tid >> 6, l = tid & 63, lc = l & 15, lg = l >> 4;
  const int z = blockIdx.z;
  const int y = blockIdx.y;
  const int row0 = blockIdx.x * 64;
  const int pos_offset = z ? 4096 : 0;

  const unsigned short* Xbf = z ? Xx : Xa;
  const unsigned short* Wt;
  const float* gamma = nullptr;
  unsigned short* OUT = nullptr;
  unsigned short* OUTT = nullptr;
  int h, Hout, doNR;
  if (y < 8) {
    h = y; Hout = NH; doNR = 1;
    Wt = z ? WtQx : WtQa; gamma = z ? gq_x : gq_a; OUT = Qb;
  } else if (y < 10) {
    h = y - 8; Hout = NKV; doNR = 1;
    Wt = z ? WtKx : WtKa; gamma = z ? gk_x : gk_a; OUT = Kb; OUTT = Kt;
  } else {
    h = y - 10; Hout = NKV; doNR = 0;
    Wt = z ? WtVx : WtVa; OUTT = Vt;
  }

  const unsigned short* ap = Xbf + (size_t)(row0 + w * 16 + lc) * 512 + lg * 8;
  const unsigned short* bp = Wt + (size_t)(h * 64 + lc) * 512 + lg * 8;

  f32x4 acc[4];
  #pragma unroll
  for (int ct = 0; ct < 4; ct++) { acc[ct][0]=0.f; acc[ct][1]=0.f; acc[ct][2]=0.f; acc[ct][3]=0.f; }

  #pragma unroll 4
  for (int kc = 0; kc < 16; kc++) {
    short8v av = *(const short8v*)(ap + kc * 32);
    #pragma unroll
    for (int ct = 0; ct < 4; ct++) {
      short8v bv = *(const short8v*)(bp + (size_t)(ct * 16 * 512) + kc * 32);
      acc[ct] = __builtin_amdgcn_mfma_f32_16x16x32_bf16(av, bv, acc[ct], 0, 0, 0);
    }
  }

  float o[4][4];
  if (doNR) {
    float srow[4];
    #pragma unroll
    for (int reg = 0; reg < 4; reg++) {
      float ss = acc[0][reg]*acc[0][reg] + acc[1][reg]*acc[1][reg]
               + acc[2][reg]*acc[2][reg] + acc[3][reg]*acc[3][reg];
      ss += __shfl_xor(ss, 1, 64);
      ss += __shfl_xor(ss, 2, 64);
      ss += __shfl_xor(ss, 4, 64);
      ss += __shfl_xor(ss, 8, 64);
      srow[reg] = 8.0f / fmaxf(sqrtf(ss), 1e-12f);
    }
    float gam[4];
    #pragma unroll
    for (int ct = 0; ct < 4; ct++) gam[ct] = gamma[h * 64 + ct * 16 + lc];
    const float LOG1E4 = 9.210340371976184f;
    float invf[2];
    invf[0] = __expf(-((float)lc / 32.f) * LOG1E4);
    invf[1] = __expf(-((float)(16 + lc) / 32.f) * LOG1E4);
    const int posb = pos_offset + (row0 & 4095) + w * 16 + lg * 4;
    #pragma unroll
    for (int reg = 0; reg < 4; reg++) {
      #pragma unroll
      for (int half = 0; half < 2; half++) {
        float ang = (float)(posb + reg) * invf[half];
        float sn, cs;
        sincosf(ang, &sn, &cs);
        float v1 = acc[half][reg] * srow[reg] * gam[half];
        float v2 = acc[half + 2][reg] * srow[reg] * gam[half + 2];
        o[half][reg]     = v1 * cs - v2 * sn;
        o[half + 2][reg] = v2 * cs + v1 * sn;
      }
    }
  } else {
    #pragma unroll
    for (int ct = 0; ct < 4; ct++)
      #pragma unroll
      for (int reg = 0; reg < 4; reg++) o[ct][reg] = acc[ct][reg];
  }

  #pragma unroll
  for (int ct = 0; ct < 4; ct++)
    #pragma unroll
    for (int reg = 0; reg < 4; reg++)
      Tsh[w * 16 + lg * 4 + reg][ct * 16 + lc] = f2bf(o[ct][reg]);
  __syncthreads();

  const int b = row0 >> 12;
  const int pos0 = pos_offset + (row0 & 4095);
  if (OUT) {
    const int r = tid >> 2, part = tid & 3;
    unsigned short* dst = OUT + (((size_t)b * Hout + h) * NTOK + pos0 + r) * 64 + part * 16;
    short8v u0 = *(const short8v*)&Tsh[r][part * 16];
    short8v u1 = *(const short8v*)&Tsh[r][part * 16 + 8];
    *(short8v*)dst = u0;
    *(short8v*)(dst + 8) = u1;
  }
  if (OUTT) {
    const int e = tid >> 2, part = tid & 3;
    short8v t0, t1;
    #pragma unroll
    for (int i = 0; i < 8; i++) t0[i] = (short)Tsh[part * 16 + i][e];
    #pragma unroll
    for (int i = 0; i < 8; i++) t1[i] = (short)Tsh[part * 16 + 8 + i][e];
    unsigned short* dstT = OUTT + (((size_t)b * NKV + h) * 64 + e) * NTOK + pos0 + part * 16;
    *(short8v*)dstT = t0;
    *(short8v*)(dstT + 8) = t1;
  }
}

// ---------------------------------------------------------------------------
// Per-segment summaries via MFMA from Kt, Vt (d/e-major, n contiguous):
// S[e][d] = sum_n Vt[e][n] * (elu(Kt[d][n])+1) ; Z[d] = sum_n (elu(Kt[d][n])+1)
// ---------------------------------------------------------------------------
__global__ __launch_bounds__(256) void seg_summary_kernel(
    const unsigned short* __restrict__ Kt, const unsigned short* __restrict__ Vt,
    float* __restrict__ S, float* __restrict__ Z)
{
  const int blk = blockIdx.x;
  const int seg = blk & 7;
  const int bkv = blk >> 3;
  const int tid = threadIdx.x;
  const int w = tid >> 6, l = tid & 63, lc = l & 15, lg = l >> 4;
  const unsigned short* KtB = Kt + ((size_t)bkv * 64) * NTOK + seg * SEGL;
  const unsigned short* VtB = Vt + ((size_t)bkv * 64) * NTOK + seg * SEGL;

  f32x4 acc[4];
  #pragma unroll
  for (int ct = 0; ct < 4; ct++) { acc[ct][0]=0.f; acc[ct][1]=0.f; acc[ct][2]=0.f; acc[ct][3]=0.f; }
  float zacc[4] = {0.f, 0.f, 0.f, 0.f};

  for (int n0 = 0; n0 < SEGL; n0 += 32) {
    short8v av = *(const short8v*)(VtB + (size_t)(w * 16 + lc) * NTOK + n0 + lg * 8);
    #pragma unroll
    for (int ct = 0; ct < 4; ct++) {
      short8v kv = *(const short8v*)(KtB + (size_t)(ct * 16 + lc) * NTOK + n0 + lg * 8);
      short8v skv;
      float zp = 0.f;
      #pragma unroll
      for (int i = 0; i < 8; i++) {
        float kf = bf2f((unsigned short)kv[i]);
        float sk = kf > 0.f ? kf + 1.f : __expf(kf);
        zp += sk;
        skv[i] = (short)f2bf(sk);
      }
      zacc[ct] += zp;
      acc[ct] = __builtin_amdgcn_mfma_f32_16x16x32_bf16(av, skv, acc[ct], 0, 0, 0);
    }
  }

  float* Sp = S + (size_t)blk * 4096;
  #pragma unroll
  for (int ct = 0; ct < 4; ct++)
    #pragma unroll
    for (int reg = 0; reg < 4; reg++)
      Sp[(size_t)(w * 16 + lg * 4 + reg) * 64 + ct * 16 + lc] = acc[ct][reg];

  if (w == 0) {
    #pragma unroll
    for (int ct = 0; ct < 4; ct++) {
      zacc[ct] += __shfl_xor(zacc[ct], 16, 64);
      zacc[ct] += __shfl_xor(zacc[ct], 32, 64);
    }
    if (lg == 0) {
      float* Zp = Z + (size_t)blk * 64;
      #pragma unroll
      for (int ct = 0; ct < 4; ct++) Zp[ct * 16 + lc] = zacc[ct];
    }
  }
}

// Exclusive prefix over segments -> bf16 PT + f32 PZ.
__global__ void prefix_kernel(const float* __restrict__ S, const float* __restrict__ Z,
                              unsigned short* __restrict__ PT, float* __restrict__ PZ)
{
  const int bkv = blockIdx.x;
  const int tid = threadIdx.x;
  for (int i = tid; i < 4096; i += 256) {
    float run = 0.f;
    for (int s = 0; s < NSEG; s++) {
      PT[((size_t)bkv * NSEG + s) * 4096 + i] = f2bf(run);
      run += S[((size_t)bkv * NSEG + s) * 4096 + i];
    }
  }
  if (tid < 64) {
    float run = 0.f;
    for (int s = 0; s < NSEG; s++) {
      PZ[((size_t)bkv * NSEG + s) * 64 + tid] = run;
      run += Z[((size_t)bkv * NSEG + s) * 64 + tid];
    }
  }
}

// ---------------------------------------------------------------------------
// MFMA flash attention v3: causal-balanced pair of q-tiles per block,
// LDS-staged K/V tiles (double-buffered, prefetch), builtin-only MFMA.
// Block = (b,h,seg, j) handles q-tiles qtA=15-j and qtB=j -> uniform 17 steps.
// ---------------------------------------------------------------------------
__global__ __launch_bounds__(256, 4) void attn_mfma_kernel(
    const unsigned short* __restrict__ Qb, const unsigned short* __restrict__ Kb,
    const unsigned short* __restrict__ Vt, const unsigned short* __restrict__ PT,
    const float* __restrict__ PZ, const float* __restrict__ beta,
    float* __restrict__ OUT)
{
  __shared__ unsigned short Ks[2][64][72];
  __shared__ unsigned short Vs[2][64][72];
  const int tid = threadIdx.x;
  const int w = tid >> 6;
  const int l = tid & 63;
  const int lc = l & 15;
  const int lg = l >> 4;

  const int j   = blockIdx.x & 7;
  const int seg = (blockIdx.x >> 3) & 7;
  const int bh  = blockIdx.x >> 6;
  const int h = bh & (NH - 1), b = bh >> 3;
  const int bkv = b * NKV + (h & (NKV - 1));   // jnp.tile -> h % KVH
  const int qtA = 15 - j, qtB = j;
  const int segbase = seg * SEGL;

  const unsigned short* Kbase = Kb + ((size_t)bkv * NTOK + segbase) * 64;
  const unsigned short* Vbase = Vt + ((size_t)bkv * 64) * NTOK + segbase;

  // Q fragments for both tiles: q-row = qt*64 + w*16+lc, k(d) = lg*8+i (+32)
  short8v aq0[2], aq1[2];
  {
    const unsigned short* qp =
        Qb + (((size_t)bh * NTOK) + segbase + qtA * 64 + w * 16 + lc) * 64 + lg * 8;
    aq0[0] = *(const short8v*)(qp);
    aq1[0] = *(const short8v*)(qp + 32);
  }
  {
    const unsigned short* qp =
        Qb + (((size_t)bh * NTOK) + segbase + qtB * 64 + w * 16 + lc) * 64 + lg * 8;
    aq0[1] = *(const short8v*)(qp);
    aq1[1] = *(const short8v*)(qp + 32);
  }

  f32x4 O[2][4];
  #pragma unroll
  for (int tt = 0; tt < 2; tt++)
    #pragma unroll
    for (int ce = 0; ce < 4; ce++) { O[tt][ce][0]=0.f; O[tt][ce][1]=0.f; O[tt][ce][2]=0.f; O[tt][ce][3]=0.f; }
  float rsumL[2] = {0.f, 0.f};

  // ---- prologue: stage tile 0 ----
  short8v kst[2], vst[2];
  #pragma unroll
  for (int i = 0; i < 2; i++) {
    int idx = i * 256 + tid;
    int r = idx >> 3, c = (idx & 7) * 8;
    kst[i] = *(const short8v*)(Kbase + (size_t)r * 64 + c);
    vst[i] = *(const short8v*)(Vbase + (size_t)r * NTOK + c);
  }
  #pragma unroll
  for (int i = 0; i < 2; i++) {
    int idx = i * 256 + tid;
    int r = idx >> 3, c = (idx & 7) * 8;
    *(short8v*)&Ks[0][r][c] = kst[i];
    *(short8v*)&Vs[0][r][c] = vst[i];
  }
  __syncthreads();

  for (int kt = 0; kt <= qtA; ++kt) {
    const int buf = kt & 1;
    const bool more = kt < qtA;
    if (more) {
      const int ktn = kt + 1;
      #pragma unroll
      for (int i = 0; i < 2; i++) {
        int idx = i * 256 + tid;
        int r = idx >> 3, c = (idx & 7) * 8;
        kst[i] = *(const short8v*)(Kbase + (size_t)(ktn * 64 + r) * 64 + c);
        vst[i] = *(const short8v*)(Vbase + (size_t)r * NTOK + ktn * 64 + c);
      }
    }

    #pragma unroll
    for (int tt = 0; tt < 2; tt++) {
      if (tt == 1 && kt > qtB) continue;
      const int qt_ = tt ? qtB : qtA;
      const bool diag = (kt == qt_);
      const int ctmax = diag ? w : 3;

      // ---- S^T = K Q^T, P = exp(s/8 - 8) with causal mask, packed in-lane ----
      short4v pa[4];
      #pragma unroll
      for (int ck = 0; ck < 4; ck++) {
        if (ck > ctmax) {
          pa[ck][0] = 0; pa[ck][1] = 0; pa[ck][2] = 0; pa[ck][3] = 0;
          continue;
        }
        f32x4 s;
        s[0]=0.f; s[1]=0.f; s[2]=0.f; s[3]=0.f;
        short8v ak0 = *(const short8v*)&Ks[buf][ck * 16 + lc][lg * 8];
        short8v ak1 = *(const short8v*)&Ks[buf][ck * 16 + lc][lg * 8 + 32];
        s = __builtin_amdgcn_mfma_f32_16x16x32_bf16(ak0, aq0[tt], s, 0, 0, 0);
        s = __builtin_amdgcn_mfma_f32_16x16x32_bf16(ak1, aq1[tt], s, 0, 0, 0);
        const bool needmask = diag && (ck == w);
        float p0 = __expf(s[0] * 0.125f - 8.0f);
        float p1 = __expf(s[1] * 0.125f - 8.0f);
        float p2 = __expf(s[2] * 0.125f - 8.0f);
        float p3 = __expf(s[3] * 0.125f - 8.0f);
        if (needmask) {
          if (lg * 4 + 0 > lc) p0 = 0.f;
          if (lg * 4 + 1 > lc) p1 = 0.f;
          if (lg * 4 + 2 > lc) p2 = 0.f;
          if (lg * 4 + 3 > lc) p3 = 0.f;
        }
        rsumL[tt] += p0 + p1 + p2 + p3;
        pa[ck][0] = (short)f2bf(p0);
        pa[ck][1] = (short)f2bf(p1);
        pa[ck][2] = (short)f2bf(p2);
        pa[ck][3] = (short)f2bf(p3);
      }

      // ---- O += P V via 16x16x32, pairing ck sub-tiles ----
      #pragma unroll
      for (int cp = 0; cp < 2; cp++) {
        if (cp * 2 > ctmax) continue;
        short8v a8;
        #pragma unroll
        for (int i = 0; i < 4; i++) { a8[i] = pa[cp * 2][i]; a8[4 + i] = pa[cp * 2 + 1][i]; }
        #pragma unroll
        for (int ce = 0; ce < 4; ce++) {
          short4v b0 = *(const short4v*)&Vs[buf][ce * 16 + lc][cp * 32 + lg * 4];
          short4v b1 = *(const short4v*)&Vs[buf][ce * 16 + lc][cp * 32 + 16 + lg * 4];
          short8v b8;
          #pragma unroll
          for (int i = 0; i < 4; i++) { b8[i] = b0[i]; b8[4 + i] = b1[i]; }
          O[tt][ce] = __builtin_amdgcn_mfma_f32_16x16x32_bf16(a8, b8, O[tt][ce], 0, 0, 0);
        }
      }
    }

    __syncthreads();
    if (more) {
      #pragma unroll
      for (int i = 0; i < 2; i++) {
        int idx = i * 256 + tid;
        int r = idx >> 3, c = (idx & 7) * 8;
        *(short8v*)&Ks[buf ^ 1][r][c] = kst[i];
        *(short8v*)&Vs[buf ^ 1][r][c] = vst[i];
      }
      __syncthreads();
    }
  }

  // ---- epilogue per tile: softmax sum + memory path + gated write ----
  const float g = 1.f / (1.f + __expf(-beta[h]));
  const float g1 = 1.f - g;
  const unsigned short* stp = PT + ((size_t)bkv * NSEG + seg) * 4096 + lc * 64 + lg * 8;
  const float* zp = PZ + ((size_t)bkv * NSEG + seg) * 64 + lg * 8;

  #pragma unroll
  for (int tt = 0; tt < 2; tt++) {
    float rsum = rsumL[tt];
    rsum += __shfl_xor(rsum, 16, 64);
    rsum += __shfl_xor(rsum, 32, 64);

    short8v asq0, asq1;
    float den = 1e-12f;
    #pragma unroll
    for (int i = 0; i < 8; i++) {
      float f0 = bf2f((unsigned short)aq0[tt][i]);
      float e0 = f0 > 0.f ? f0 + 1.f : __expf(f0);
      asq0[i] = (short)f2bf(e0);
      den += e0 * zp[i];
      float f1 = bf2f((unsigned short)aq1[tt][i]);
      float e1 = f1 > 0.f ? f1 + 1.f : __expf(f1);
      asq1[i] = (short)f2bf(e1);
      den += e1 * zp[32 + i];
    }
    f32x4 N[4];
    #pragma unroll
    for (int ct = 0; ct < 4; ct++) { N[ct][0]=0.f; N[ct][1]=0.f; N[ct][2]=0.f; N[ct][3]=0.f; }
    #pragma unroll
    for (int ct = 0; ct < 4; ct++) {
      short8v bs0 = *(const short8v*)(stp + ct * 16 * 64);
      short8v bs1 = *(const short8v*)(stp + ct * 16 * 64 + 32);
      N[ct] = __builtin_amdgcn_mfma_f32_16x16x32_bf16(asq0, bs0, N[ct], 0, 0, 0);
      N[ct] = __builtin_amdgcn_mfma_f32_16x16x32_bf16(asq1, bs1, N[ct], 0, 0, 0);
    }
    den += __shfl_xor(den, 16, 64);
    den += __shfl_xor(den, 32, 64);
    float denc[4], rs[4];
    #pragma unroll
    for (int reg = 0; reg < 4; reg++) {
      denc[reg] = __shfl(den, lg * 4 + reg, 64);
      rs[reg]   = __shfl(rsum, lg * 4 + reg, 64);
    }

    const int q0 = (tt ? qtB : qtA) * 64;
    const int nrow = segbase + q0 + w * 16 + lg * 4;
    #pragma unroll
    for (int reg = 0; reg < 4; reg++) {
      const int n = nrow + reg;
      const float invs = 1.f / rs[reg];
      const float invd = 1.f / denc[reg];
      size_t obase;
      if (n < 4096) obase = (size_t)BATCH * 4096 * 512 + (((size_t)b * 4096 + n) * NH + h) * 64;
      else          obase = (((size_t)b * 4096 + (n - 4096)) * NH + h) * 64;
      #pragma unroll
      for (int ce = 0; ce < 4; ce++) {
        OUT[obase + ce * 16 + lc] = g * N[ce][reg] * invd + g1 * O[tt][ce][reg] * invs;
      }
    }
  }
}

// ---------------------------------------------------------------------------
extern "C" void kernel_launch(void* const* d_in, const int* in_sizes, int n_in,
                              void* d_out, int out_size, void* d_ws, size_t ws_size,
                              hipStream_t stream) {
  const float* x    = (const float*)d_in[0];
  const float* a    = (const float*)d_in[1];
  const float* Wq_x = (const float*)d_in[2];
  const float* Wk_x = (const float*)d_in[3];
  const float* Wv_x = (const float*)d_in[4];
  const float* Wq_a = (const float*)d_in[5];
  const float* Wk_a = (const float*)d_in[6];
  const float* Wv_a = (const float*)d_in[7];
  const float* gq_x = (const float*)d_in[8];
  const float* gk_x = (const float*)d_in[9];
  const float* gq_a = (const float*)d_in[10];
  const float* gk_a = (const float*)d_in[11];
  const float* beta = (const float*)d_in[12];

  unsigned short* Qb = (unsigned short*)d_ws;          // 8388608
  unsigned short* Kb = Qb + (size_t)8388608;           // 2097152
  unsigned short* Kt = Kb + (size_t)2097152;           // 2097152
  unsigned short* Vt = Kt + (size_t)2097152;           // 2097152
  unsigned short* Xa = Vt + (size_t)2097152;           // 4194304
  unsigned short* Xx = Xa + (size_t)4194304;           // 4194304
  unsigned short* WtQa = Xx + (size_t)4194304;         // 262144
  unsigned short* WtKa = WtQa + (size_t)262144;        // 65536
  unsigned short* WtVa = WtKa + (size_t)65536;         // 65536
  unsigned short* WtQx = WtVa + (size_t)65536;         // 262144
  unsigned short* WtKx = WtQx + (size_t)262144;        // 65536
  unsigned short* WtVx = WtKx + (size_t)65536;         // 65536
  float* S  = (float*)(WtVx + (size_t)65536);          // 131072 f32
  float* Z  = S + (size_t)131072;                      // 2048
  float* PZ = Z + (size_t)2048;                        // 2048
  unsigned short* PT = (unsigned short*)(PZ + (size_t)2048); // 131072

  cast_bf16_kernel<<<dim3(2048, 2), 256, 0, stream>>>(a, x, Xa, Xx);
  wtrans_kernel<<<dim3(16, 16, 6), 256, 0, stream>>>(
      Wq_a, Wk_a, Wv_a, Wq_x, Wk_x, Wv_x, WtQa, WtKa, WtVa, WtQx, WtKx, WtVx);
  proj_all_kernel<<<dim3(128, 12, 2), 256, 0, stream>>>(
      Xa, Xx, WtQa, WtKa, WtVa, WtQx, WtKx, WtVx,
      gq_a, gk_a, gq_x, gk_x, Qb, Kb, Kt, Vt);
  seg_summary_kernel<<<32, 256, 0, stream>>>(Kt, Vt, S, Z);
  prefix_kernel<<<4, 256, 0, stream>>>(S, Z, PT, PZ);
  attn_mfma_kernel<<<dim3(1024), 256, 0, stream>>>(Qb, Kb, Vt, PT, PZ, beta, (float*)d_out);
}

// Round 7
// 215.604 us; speedup vs baseline: 7.8530x; 1.3049x over previous
//
#include <hip/hip_runtime.h>
#include <math.h>

#define NH 8
#define NKV 2
#define SEGL 1024
#define NSEG 8
#define NTOK 8192
#define BATCH 2
#define DIMK 512

typedef short short8v __attribute__((ext_vector_type(8)));
typedef short short4v __attribute__((ext_vector_type(4)));
typedef float f32x4 __attribute__((ext_vector_type(4)));

__device__ __forceinline__ unsigned short f2bf(float f) {
  union { float f; unsigned u; } c; c.f = f;
  unsigned u = c.u;
  return (unsigned short)((u + 0x7FFFu + ((u >> 16) & 1u)) >> 16);
}
__device__ __forceinline__ float bf2f(unsigned short h) {
  union { unsigned u; float f; } c; c.u = ((unsigned)h) << 16;
  return c.f;
}

// async global->LDS, 16 bytes per lane. LDS dest must be wave-uniform + lane*16.
__device__ __forceinline__ void gload16(const unsigned short* g, unsigned short* l) {
  __builtin_amdgcn_global_load_lds(
      (const __attribute__((address_space(1))) unsigned int*)g,
      (__attribute__((address_space(3))) unsigned int*)l, 16, 0, 0);
}

// ---------------------------------------------------------------------------
// f32 -> bf16 cast; y selects input (0 = a, 1 = x).
// ---------------------------------------------------------------------------
__global__ void cast_bf16_kernel(const float* __restrict__ a, const float* __restrict__ x,
                                 unsigned short* __restrict__ outa,
                                 unsigned short* __restrict__ outx) {
  const float* in = blockIdx.y ? x : a;
  unsigned short* out = blockIdx.y ? outx : outa;
  int i = blockIdx.x * blockDim.x + threadIdx.x;
  const float4* p = (const float4*)in + (size_t)i * 2;
  float4 v0 = p[0], v1 = p[1];
  short8v o;
  o[0] = (short)f2bf(v0.x); o[1] = (short)f2bf(v0.y);
  o[2] = (short)f2bf(v0.z); o[3] = (short)f2bf(v0.w);
  o[4] = (short)f2bf(v1.x); o[5] = (short)f2bf(v1.y);
  o[6] = (short)f2bf(v1.z); o[7] = (short)f2bf(v1.w);
  *((short8v*)out + i) = o;
}

// ---------------------------------------------------------------------------
// W (512 x C) f32 -> Wt (C x 512) bf16; z selects which of the 6 weights.
// ---------------------------------------------------------------------------
__global__ void wtrans_kernel(const float* __restrict__ w0, const float* __restrict__ w1,
                              const float* __restrict__ w2, const float* __restrict__ w3,
                              const float* __restrict__ w4, const float* __restrict__ w5,
                              unsigned short* __restrict__ o0, unsigned short* __restrict__ o1,
                              unsigned short* __restrict__ o2, unsigned short* __restrict__ o3,
                              unsigned short* __restrict__ o4, unsigned short* __restrict__ o5) {
  __shared__ float T[32][33];
  const int z = blockIdx.z;
  const float* in; unsigned short* out; int C;
  switch (z) {
    case 0: in = w0; out = o0; C = 512; break;
    case 1: in = w1; out = o1; C = 128; break;
    case 2: in = w2; out = o2; C = 128; break;
    case 3: in = w3; out = o3; C = 512; break;
    case 4: in = w4; out = o4; C = 128; break;
    default: in = w5; out = o5; C = 128; break;
  }
  const int c0 = blockIdx.x * 32, k0 = blockIdx.y * 32;
  if (c0 >= C) return;
  const int tx = threadIdx.x & 31, ty = threadIdx.x >> 5;
  #pragma unroll
  for (int i = 0; i < 4; i++)
    T[ty + i * 8][tx] = in[(size_t)(k0 + ty + i * 8) * C + c0 + tx];
  __syncthreads();
  #pragma unroll
  for (int i = 0; i < 4; i++)
    out[(size_t)(c0 + ty + i * 8) * 512 + k0 + tx] = f2bf(T[tx][ty + i * 8]);
}

// ---------------------------------------------------------------------------
// Merged MFMA projection. grid (128, 12, 2):
//   z: input (0=a pos 0..4095, 1=x pos 4096..8191)
//   y: 0-7 -> Q head y (norm+rope); 8-9 -> K head y-8 (norm+rope, +Kt perm);
//      10-11 -> V head y-10 (plain, Vt perm only)
// Kt/Vt are written with sigma-permuted token order within each aligned
// 32-token group: n' = lg*8 + h*4 + i for n = h*16 + lg*4 + i.
// ---------------------------------------------------------------------------
__global__ __launch_bounds__(256) void proj_all_kernel(
    const unsigned short* __restrict__ Xa, const unsigned short* __restrict__ Xx,
    const unsigned short* __restrict__ WtQa, const unsigned short* __restrict__ WtKa,
    const unsigned short* __restrict__ WtVa, const unsigned short* __restrict__ WtQx,
    const unsigned short* __restrict__ WtKx, const unsigned short* __restrict__ WtVx,
    const float* __restrict__ gq_a, const float* __restrict__ gk_a,
    const float* __restrict__ gq_x, const float* __restrict__ gk_x,
    unsigned short* __restrict__ Qb, unsigned short* __restrict__ Kb,
    unsigned short* __restrict__ Kt, unsigned short* __restrict__ Vt)
{
  __shared__ unsigned short Tsh[64][72];
  const int tid = threadIdx.x;
  const int w = tid >> 6, l = tid & 63, lc = l & 15, lg = l >> 4;
  const int z = blockIdx.z;
  const int y = blockIdx.y;
  const int row0 = blockIdx.x * 64;
  const int pos_offset = z ? 4096 : 0;

  const unsigned short* Xbf = z ? Xx : Xa;
  const unsigned short* Wt;
  const float* gamma = nullptr;
  unsigned short* OUT = nullptr;
  unsigned short* OUTT = nullptr;
  int h, Hout, doNR;
  if (y < 8) {
    h = y; Hout = NH; doNR = 1;
    Wt = z ? WtQx : WtQa; gamma = z ? gq_x : gq_a; OUT = Qb;
  } else if (y < 10) {
    h = y - 8; Hout = NKV; doNR = 1;
    Wt = z ? WtKx : WtKa; gamma = z ? gk_x : gk_a; OUT = Kb; OUTT = Kt;
  } else {
    h = y - 10; Hout = NKV; doNR = 0;
    Wt = z ? WtVx : WtVa; OUTT = Vt;
  }

  const unsigned short* ap = Xbf + (size_t)(row0 + w * 16 + lc) * 512 + lg * 8;
  const unsigned short* bp = Wt + (size_t)(h * 64 + lc) * 512 + lg * 8;

  f32x4 acc[4];
  #pragma unroll
  for (int ct = 0; ct < 4; ct++) { acc[ct][0]=0.f; acc[ct][1]=0.f; acc[ct][2]=0.f; acc[ct][3]=0.f; }

  #pragma unroll 4
  for (int kc = 0; kc < 16; kc++) {
    short8v av = *(const short8v*)(ap + kc * 32);
    #pragma unroll
    for (int ct = 0; ct < 4; ct++) {
      short8v bv = *(const short8v*)(bp + (size_t)(ct * 16 * 512) + kc * 32);
      acc[ct] = __builtin_amdgcn_mfma_f32_16x16x32_bf16(av, bv, acc[ct], 0, 0, 0);
    }
  }

  float o[4][4];
  if (doNR) {
    float srow[4];
    #pragma unroll
    for (int reg = 0; reg < 4; reg++) {
      float ss = acc[0][reg]*acc[0][reg] + acc[1][reg]*acc[1][reg]
               + acc[2][reg]*acc[2][reg] + acc[3][reg]*acc[3][reg];
      ss += __shfl_xor(ss, 1, 64);
      ss += __shfl_xor(ss, 2, 64);
      ss += __shfl_xor(ss, 4, 64);
      ss += __shfl_xor(ss, 8, 64);
      srow[reg] = 8.0f / fmaxf(sqrtf(ss), 1e-12f);
    }
    float gam[4];
    #pragma unroll
    for (int ct = 0; ct < 4; ct++) gam[ct] = gamma[h * 64 + ct * 16 + lc];
    const float LOG1E4 = 9.210340371976184f;
    float invf[2];
    invf[0] = __expf(-((float)lc / 32.f) * LOG1E4);
    invf[1] = __expf(-((float)(16 + lc) / 32.f) * LOG1E4);
    const int posb = pos_offset + (row0 & 4095) + w * 16 + lg * 4;
    #pragma unroll
    for (int reg = 0; reg < 4; reg++) {
      #pragma unroll
      for (int half = 0; half < 2; half++) {
        float ang = (float)(posb + reg) * invf[half];
        float sn, cs;
        sincosf(ang, &sn, &cs);
        float v1 = acc[half][reg] * srow[reg] * gam[half];
        float v2 = acc[half + 2][reg] * srow[reg] * gam[half + 2];
        o[half][reg]     = v1 * cs - v2 * sn;
        o[half + 2][reg] = v2 * cs + v1 * sn;
      }
    }
  } else {
    #pragma unroll
    for (int ct = 0; ct < 4; ct++)
      #pragma unroll
      for (int reg = 0; reg < 4; reg++) o[ct][reg] = acc[ct][reg];
  }

  #pragma unroll
  for (int ct = 0; ct < 4; ct++)
    #pragma unroll
    for (int reg = 0; reg < 4; reg++)
      Tsh[w * 16 + lg * 4 + reg][ct * 16 + lc] = f2bf(o[ct][reg]);
  __syncthreads();

  const int b = row0 >> 12;
  const int pos0 = pos_offset + (row0 & 4095);
  if (OUT) {
    const int r = tid >> 2, part = tid & 3;
    unsigned short* dst = OUT + (((size_t)b * Hout + h) * NTOK + pos0 + r) * 64 + part * 16;
    short8v u0 = *(const short8v*)&Tsh[r][part * 16];
    short8v u1 = *(const short8v*)&Tsh[r][part * 16 + 8];
    *(short8v*)dst = u0;
    *(short8v*)(dst + 8) = u1;
  }
  if (OUTT) {
    const int e = tid >> 2, part = tid & 3;
    short8v t0, t1;
    #pragma unroll
    for (int jj = 0; jj < 16; jj++) {
      const int LG = ((part & 1) << 1) | (jj >> 3);
      const int H  = (jj >> 2) & 1;
      const int I  = jj & 3;
      const int srcrow = (part >> 1) * 32 + H * 16 + LG * 4 + I;
      unsigned short v = Tsh[srcrow][e];
      if (jj < 8) t0[jj] = (short)v; else t1[jj - 8] = (short)v;
    }
    unsigned short* dstT = OUTT + (((size_t)b * NKV + h) * 64 + e) * NTOK + pos0 + part * 16;
    *(short8v*)dstT = t0;
    *(short8v*)(dstT + 8) = t1;
  }
}

// ---------------------------------------------------------------------------
// Per-segment partial summaries (8 n-chunks of 128 tokens) via MFMA from
// permuted Kt', Vt' (consistent k-slot pairing; sums order-invariant).
// grid 256 = (bkv*8+seg)*8+chunk.
// ---------------------------------------------------------------------------
__global__ __launch_bounds__(256) void seg_summary_kernel(
    const unsigned short* __restrict__ Kt, const unsigned short* __restrict__ Vt,
    float* __restrict__ Spart, float* __restrict__ Zpart)
{
  const int blk = blockIdx.x;
  const int chunk = blk & 7;
  const int seg = (blk >> 3) & 7;
  const int bkv = blk >> 6;
  const int tid = threadIdx.x;
  const int w = tid >> 6, l = tid & 63, lc = l & 15, lg = l >> 4;
  const unsigned short* KtB = Kt + ((size_t)bkv * 64) * NTOK + seg * SEGL + chunk * 128;
  const unsigned short* VtB = Vt + ((size_t)bkv * 64) * NTOK + seg * SEGL + chunk * 128;

  f32x4 acc[4];
  #pragma unroll
  for (int ct = 0; ct < 4; ct++) { acc[ct][0]=0.f; acc[ct][1]=0.f; acc[ct][2]=0.f; acc[ct][3]=0.f; }
  float zacc[4] = {0.f, 0.f, 0.f, 0.f};

  for (int n0 = 0; n0 < 128; n0 += 32) {
    short8v av = *(const short8v*)(VtB + (size_t)(w * 16 + lc) * NTOK + n0 + lg * 8);
    #pragma unroll
    for (int ct = 0; ct < 4; ct++) {
      short8v kv = *(const short8v*)(KtB + (size_t)(ct * 16 + lc) * NTOK + n0 + lg * 8);
      short8v skv;
      float zp = 0.f;
      #pragma unroll
      for (int i = 0; i < 8; i++) {
        float kf = bf2f((unsigned short)kv[i]);
        float sk = kf > 0.f ? kf + 1.f : __expf(kf);
        zp += sk;
        skv[i] = (short)f2bf(sk);
      }
      zacc[ct] += zp;
      acc[ct] = __builtin_amdgcn_mfma_f32_16x16x32_bf16(av, skv, acc[ct], 0, 0, 0);
    }
  }

  float* Sp = Spart + (size_t)blk * 4096;
  #pragma unroll
  for (int ct = 0; ct < 4; ct++)
    #pragma unroll
    for (int reg = 0; reg < 4; reg++)
      Sp[(size_t)(w * 16 + lg * 4 + reg) * 64 + ct * 16 + lc] = acc[ct][reg];

  if (w == 0) {
    #pragma unroll
    for (int ct = 0; ct < 4; ct++) {
      zacc[ct] += __shfl_xor(zacc[ct], 16, 64);
      zacc[ct] += __shfl_xor(zacc[ct], 32, 64);
    }
    if (lg == 0) {
      float* Zp = Zpart + (size_t)blk * 64;
      #pragma unroll
      for (int ct = 0; ct < 4; ct++) Zp[ct * 16 + lc] = zacc[ct];
    }
  }
}

// Chunk-reduce + exclusive prefix over segments -> bf16 PT + f32 PZ.
// grid (4, 16), block 256: one column per thread.
__global__ void prefix_kernel(const float* __restrict__ Spart, const float* __restrict__ Zpart,
                              unsigned short* __restrict__ PT, float* __restrict__ PZ)
{
  const int bkv = blockIdx.x;
  const int col = blockIdx.y * 256 + threadIdx.x;
  float run = 0.f;
  for (int s = 0; s < NSEG; s++) {
    float v = 0.f;
    #pragma unroll
    for (int c = 0; c < 8; c++)
      v += Spart[(((size_t)(bkv * 8 + s)) * 8 + c) * 4096 + col];
    PT[((size_t)bkv * 8 + s) * 4096 + col] = f2bf(run);
    run += v;
  }
  if (blockIdx.y == 0 && threadIdx.x < 64) {
    const int d = threadIdx.x;
    float rz = 0.f;
    for (int s = 0; s < NSEG; s++) {
      float v = 0.f;
      #pragma unroll
      for (int c = 0; c < 8; c++)
        v += Zpart[(((size_t)(bkv * 8 + s)) * 8 + c) * 64 + d];
      PZ[((size_t)bkv * 8 + s) * 64 + d] = rz;
      rz += v;
    }
  }
}

// ---------------------------------------------------------------------------
// MFMA flash attention v4: causal-balanced q-tile pair, global_load_lds
// staging (XOR-swizzled source granules, linear LDS), single barrier/step,
// b128 PV reads (V pre-permuted in global), setprio around MFMA.
// ---------------------------------------------------------------------------
__global__ __launch_bounds__(256, 4) void attn_mfma_kernel(
    const unsigned short* __restrict__ Qb, const unsigned short* __restrict__ Kb,
    const unsigned short* __restrict__ Vt, const unsigned short* __restrict__ PT,
    const float* __restrict__ PZ, const float* __restrict__ beta,
    float* __restrict__ OUT)
{
  __shared__ __attribute__((aligned(16))) unsigned short Ks[2][64][64];
  __shared__ __attribute__((aligned(16))) unsigned short Vs[2][64][64];
  const int tid = threadIdx.x;
  const int w = tid >> 6;
  const int l = tid & 63;
  const int lc = l & 15;
  const int lg = l >> 4;
  const int r7 = lc & 7;

  const int j   = blockIdx.x & 7;
  const int seg = (blockIdx.x >> 3) & 7;
  const int bh  = blockIdx.x >> 6;
  const int h = bh & (NH - 1), b = bh >> 3;
  const int bkv = b * NKV + (h & (NKV - 1));   // jnp.tile -> h % KVH
  const int qtA = 15 - j, qtB = j;
  const int segbase = seg * SEGL;

  const unsigned short* Kbase = Kb + ((size_t)bkv * NTOK + segbase) * 64;
  const unsigned short* Vbase = Vt + ((size_t)bkv * 64) * NTOK + segbase;

  // staging constants: row within 32-row pass, swizzled source granule
  const int srow = tid >> 3;                 // 0..31
  const int sg   = (tid & 7) ^ (srow & 7);   // involution granule swizzle

  // Q fragments for both tiles
  short8v aq0[2], aq1[2];
  {
    const unsigned short* qp =
        Qb + (((size_t)bh * NTOK) + segbase + qtA * 64 + w * 16 + lc) * 64 + lg * 8;
    aq0[0] = *(const short8v*)(qp);
    aq1[0] = *(const short8v*)(qp + 32);
  }
  {
    const unsigned short* qp =
        Qb + (((size_t)bh * NTOK) + segbase + qtB * 64 + w * 16 + lc) * 64 + lg * 8;
    aq0[1] = *(const short8v*)(qp);
    aq1[1] = *(const short8v*)(qp + 32);
  }

  f32x4 O[2][4];
  #pragma unroll
  for (int tt = 0; tt < 2; tt++)
    #pragma unroll
    for (int ce = 0; ce < 4; ce++) { O[tt][ce][0]=0.f; O[tt][ce][1]=0.f; O[tt][ce][2]=0.f; O[tt][ce][3]=0.f; }
  float rsumL[2] = {0.f, 0.f};

  // ---- prologue: stage tile 0 ----
  {
    unsigned short* kD = &Ks[0][0][0];
    unsigned short* vD = &Vs[0][0][0];
    #pragma unroll
    for (int p = 0; p < 2; p++) {
      const int row = p * 32 + srow;
      gload16(Kbase + (size_t)row * 64 + sg * 8, kD + p * 2048 + tid * 8);
      gload16(Vbase + (size_t)row * NTOK + sg * 8, vD + p * 2048 + tid * 8);
    }
  }
  __syncthreads();

  for (int kt = 0; kt <= qtA; ++kt) {
    const int buf = kt & 1;
    if (kt < qtA) {
      const int ktn = kt + 1;
      unsigned short* kD = &Ks[buf ^ 1][0][0];
      unsigned short* vD = &Vs[buf ^ 1][0][0];
      #pragma unroll
      for (int p = 0; p < 2; p++) {
        const int row = p * 32 + srow;
        gload16(Kbase + (size_t)(ktn * 64 + row) * 64 + sg * 8, kD + p * 2048 + tid * 8);
        gload16(Vbase + (size_t)row * NTOK + ktn * 64 + sg * 8, vD + p * 2048 + tid * 8);
      }
    }

    __builtin_amdgcn_s_setprio(1);
    #pragma unroll
    for (int tt = 0; tt < 2; tt++) {
      if (tt == 1 && kt > qtB) continue;
      const int qt_ = tt ? qtB : qtA;
      const bool diag = (kt == qt_);
      const int ctmax = diag ? w : 3;

      // ---- S^T = K Q^T, P = exp(s/8 - 8) with causal mask, packed in-lane ----
      short4v pa[4];
      #pragma unroll
      for (int ck = 0; ck < 4; ck++) {
        if (ck > ctmax) {
          pa[ck][0] = 0; pa[ck][1] = 0; pa[ck][2] = 0; pa[ck][3] = 0;
          continue;
        }
        f32x4 s;
        s[0]=0.f; s[1]=0.f; s[2]=0.f; s[3]=0.f;
        const int krow = ck * 16 + lc;
        short8v ak0 = *(const short8v*)&Ks[buf][krow][((lg ^ r7) & 7) * 8];
        short8v ak1 = *(const short8v*)&Ks[buf][krow][(((lg + 4) ^ r7) & 7) * 8];
        s = __builtin_amdgcn_mfma_f32_16x16x32_bf16(ak0, aq0[tt], s, 0, 0, 0);
        s = __builtin_amdgcn_mfma_f32_16x16x32_bf16(ak1, aq1[tt], s, 0, 0, 0);
        const bool needmask = diag && (ck == w);
        float p0 = __expf(s[0] * 0.125f - 8.0f);
        float p1 = __expf(s[1] * 0.125f - 8.0f);
        float p2 = __expf(s[2] * 0.125f - 8.0f);
        float p3 = __expf(s[3] * 0.125f - 8.0f);
        if (needmask) {
          if (lg * 4 + 0 > lc) p0 = 0.f;
          if (lg * 4 + 1 > lc) p1 = 0.f;
          if (lg * 4 + 2 > lc) p2 = 0.f;
          if (lg * 4 + 3 > lc) p3 = 0.f;
        }
        rsumL[tt] += p0 + p1 + p2 + p3;
        pa[ck][0] = (short)f2bf(p0);
        pa[ck][1] = (short)f2bf(p1);
        pa[ck][2] = (short)f2bf(p2);
        pa[ck][3] = (short)f2bf(p3);
      }

      // ---- O += P V via 16x16x32; B-frag = one b128 from permuted+swizzled Vs ----
      #pragma unroll
      for (int cp = 0; cp < 2; cp++) {
        if (cp * 2 > ctmax) continue;
        short8v a8;
        #pragma unroll
        for (int i = 0; i < 4; i++) { a8[i] = pa[cp * 2][i]; a8[4 + i] = pa[cp * 2 + 1][i]; }
        #pragma unroll
        for (int ce = 0; ce < 4; ce++) {
          short8v b8 = *(const short8v*)&Vs[buf][ce * 16 + lc][(((cp * 4 + lg) ^ r7) & 7) * 8];
          O[tt][ce] = __builtin_amdgcn_mfma_f32_16x16x32_bf16(a8, b8, O[tt][ce], 0, 0, 0);
        }
      }
    }
    __builtin_amdgcn_s_setprio(0);
    __syncthreads();
  }

  // ---- epilogue per tile: softmax sum + memory path + gated write ----
  const float g = 1.f / (1.f + __expf(-beta[h]));
  const float g1 = 1.f - g;
  const unsigned short* stp = PT + ((size_t)bkv * NSEG + seg) * 4096 + lc * 64 + lg * 8;
  const float* zp = PZ + ((size_t)bkv * NSEG + seg) * 64 + lg * 8;

  #pragma unroll
  for (int tt = 0; tt < 2; tt++) {
    float rsum = rsumL[tt];
    rsum += __shfl_xor(rsum, 16, 64);
    rsum += __shfl_xor(rsum, 32, 64);

    short8v asq0, asq1;
    float den = 1e-12f;
    #pragma unroll
    for (int i = 0; i < 8; i++) {
      float f0 = bf2f((unsigned short)aq0[tt][i]);
      float e0 = f0 > 0.f ? f0 + 1.f : __expf(f0);
      asq0[i] = (short)f2bf(e0);
      den += e0 * zp[i];
      float f1 = bf2f((unsigned short)aq1[tt][i]);
      float e1 = f1 > 0.f ? f1 + 1.f : __expf(f1);
      asq1[i] = (short)f2bf(e1);
      den += e1 * zp[32 + i];
    }
    f32x4 N[4];
    #pragma unroll
    for (int ct = 0; ct < 4; ct++) { N[ct][0]=0.f; N[ct][1]=0.f; N[ct][2]=0.f; N[ct][3]=0.f; }
    #pragma unroll
    for (int ct = 0; ct < 4; ct++) {
      short8v bs0 = *(const short8v*)(stp + ct * 16 * 64);
      short8v bs1 = *(const short8v*)(stp + ct * 16 * 64 + 32);
      N[ct] = __builtin_amdgcn_mfma_f32_16x16x32_bf16(asq0, bs0, N[ct], 0, 0, 0);
      N[ct] = __builtin_amdgcn_mfma_f32_16x16x32_bf16(asq1, bs1, N[ct], 0, 0, 0);
    }
    den += __shfl_xor(den, 16, 64);
    den += __shfl_xor(den, 32, 64);
    float denc[4], rs[4];
    #pragma unroll
    for (int reg = 0; reg < 4; reg++) {
      denc[reg] = __shfl(den, lg * 4 + reg, 64);
      rs[reg]   = __shfl(rsum, lg * 4 + reg, 64);
    }

    const int q0 = (tt ? qtB : qtA) * 64;
    const int nrow = segbase + q0 + w * 16 + lg * 4;
    #pragma unroll
    for (int reg = 0; reg < 4; reg++) {
      const int n = nrow + reg;
      const float invs = 1.f / rs[reg];
      const float invd = 1.f / denc[reg];
      size_t obase;
      if (n < 4096) obase = (size_t)BATCH * 4096 * 512 + (((size_t)b * 4096 + n) * NH + h) * 64;
      else          obase = (((size_t)b * 4096 + (n - 4096)) * NH + h) * 64;
      #pragma unroll
      for (int ce = 0; ce < 4; ce++) {
        OUT[obase + ce * 16 + lc] = g * N[ce][reg] * invd + g1 * O[tt][ce][reg] * invs;
      }
    }
  }
}

// ---------------------------------------------------------------------------
extern "C" void kernel_launch(void* const* d_in, const int* in_sizes, int n_in,
                              void* d_out, int out_size, void* d_ws, size_t ws_size,
                              hipStream_t stream) {
  const float* x    = (const float*)d_in[0];
  const float* a    = (const float*)d_in[1];
  const float* Wq_x = (const float*)d_in[2];
  const float* Wk_x = (const float*)d_in[3];
  const float* Wv_x = (const float*)d_in[4];
  const float* Wq_a = (const float*)d_in[5];
  const float* Wk_a = (const float*)d_in[6];
  const float* Wv_a = (const float*)d_in[7];
  const float* gq_x = (const float*)d_in[8];
  const float* gk_x = (const float*)d_in[9];
  const float* gq_a = (const float*)d_in[10];
  const float* gk_a = (const float*)d_in[11];
  const float* beta = (const float*)d_in[12];

  unsigned short* Qb = (unsigned short*)d_ws;          // 8388608
  unsigned short* Kb = Qb + (size_t)8388608;           // 2097152
  unsigned short* Kt = Kb + (size_t)2097152;           // 2097152 (permuted)
  unsigned short* Vt = Kt + (size_t)2097152;           // 2097152 (permuted)
  unsigned short* Xa = Vt + (size_t)2097152;           // 4194304
  unsigned short* Xx = Xa + (size_t)4194304;           // 4194304
  unsigned short* WtQa = Xx + (size_t)4194304;         // 262144
  unsigned short* WtKa = WtQa + (size_t)262144;        // 65536
  unsigned short* WtVa = WtKa + (size_t)65536;         // 65536
  unsigned short* WtQx = WtVa + (size_t)65536;         // 262144
  unsigned short* WtKx = WtQx + (size_t)262144;        // 65536
  unsigned short* WtVx = WtKx + (size_t)65536;         // 65536
  float* Spart = (float*)(WtVx + (size_t)65536);       // 1048576 f32 (4 MB)
  float* Zpart = Spart + (size_t)1048576;              // 16384
  float* PZ = Zpart + (size_t)16384;                   // 2048
  unsigned short* PT = (unsigned short*)(PZ + (size_t)2048); // 131072

  cast_bf16_kernel<<<dim3(2048, 2), 256, 0, stream>>>(a, x, Xa, Xx);
  wtrans_kernel<<<dim3(16, 16, 6), 256, 0, stream>>>(
      Wq_a, Wk_a, Wv_a, Wq_x, Wk_x, Wv_x, WtQa, WtKa, WtVa, WtQx, WtKx, WtVx);
  proj_all_kernel<<<dim3(128, 12, 2), 256, 0, stream>>>(
      Xa, Xx, WtQa, WtKa, WtVa, WtQx, WtKx, WtVx,
      gq_a, gk_a, gq_x, gk_x, Qb, Kb, Kt, Vt);
  seg_summary_kernel<<<256, 256, 0, stream>>>(Kt, Vt, Spart, Zpart);
  prefix_kernel<<<dim3(4, 16), 256, 0, stream>>>(Spart, Zpart, PT, PZ);
  attn_mfma_kernel<<<dim3(1024), 256, 0, stream>>>(Qb, Kb, Vt, PT, PZ, beta, (float*)d_out);
}

// Round 8
// 160.341 us; speedup vs baseline: 10.5596x; 1.3447x over previous
//
#include <hip/hip_runtime.h>
#include <math.h>

#define NH 8
#define NKV 2
#define SEGL 1024
#define NSEG 8
#define NTOK 8192
#define BATCH 2
#define DIMK 512

typedef short short8v __attribute__((ext_vector_type(8)));
typedef short short4v __attribute__((ext_vector_type(4)));
typedef float f32x4 __attribute__((ext_vector_type(4)));

__device__ __forceinline__ unsigned short f2bf(float f) {
  union { float f; unsigned u; } c; c.f = f;
  unsigned u = c.u;
  return (unsigned short)((u + 0x7FFFu + ((u >> 16) & 1u)) >> 16);
}
__device__ __forceinline__ float bf2f(unsigned short h) {
  union { unsigned u; float f; } c; c.u = ((unsigned)h) << 16;
  return c.f;
}

// async global->LDS, 16 bytes per lane. LDS dest must be wave-uniform + lane*16.
__device__ __forceinline__ void gload16(const unsigned short* g, unsigned short* l) {
  __builtin_amdgcn_global_load_lds(
      (const __attribute__((address_space(1))) unsigned int*)g,
      (__attribute__((address_space(3))) unsigned int*)l, 16, 0, 0);
}

// ---------------------------------------------------------------------------
// f32 -> bf16 cast; y selects input (0 = a, 1 = x).
// ---------------------------------------------------------------------------
__global__ void cast_bf16_kernel(const float* __restrict__ a, const float* __restrict__ x,
                                 unsigned short* __restrict__ outa,
                                 unsigned short* __restrict__ outx) {
  const float* in = blockIdx.y ? x : a;
  unsigned short* out = blockIdx.y ? outx : outa;
  int i = blockIdx.x * blockDim.x + threadIdx.x;
  const float4* p = (const float4*)in + (size_t)i * 2;
  float4 v0 = p[0], v1 = p[1];
  short8v o;
  o[0] = (short)f2bf(v0.x); o[1] = (short)f2bf(v0.y);
  o[2] = (short)f2bf(v0.z); o[3] = (short)f2bf(v0.w);
  o[4] = (short)f2bf(v1.x); o[5] = (short)f2bf(v1.y);
  o[6] = (short)f2bf(v1.z); o[7] = (short)f2bf(v1.w);
  *((short8v*)out + i) = o;
}

// ---------------------------------------------------------------------------
// W (512 x C) f32 -> Wt (C x 512) bf16; z selects which of the 6 weights.
// ---------------------------------------------------------------------------
__global__ void wtrans_kernel(const float* __restrict__ w0, const float* __restrict__ w1,
                              const float* __restrict__ w2, const float* __restrict__ w3,
                              const float* __restrict__ w4, const float* __restrict__ w5,
                              unsigned short* __restrict__ o0, unsigned short* __restrict__ o1,
                              unsigned short* __restrict__ o2, unsigned short* __restrict__ o3,
                              unsigned short* __restrict__ o4, unsigned short* __restrict__ o5) {
  __shared__ float T[32][33];
  const int z = blockIdx.z;
  const float* in; unsigned short* out; int C;
  switch (z) {
    case 0: in = w0; out = o0; C = 512; break;
    case 1: in = w1; out = o1; C = 128; break;
    case 2: in = w2; out = o2; C = 128; break;
    case 3: in = w3; out = o3; C = 512; break;
    case 4: in = w4; out = o4; C = 128; break;
    default: in = w5; out = o5; C = 128; break;
  }
  const int c0 = blockIdx.x * 32, k0 = blockIdx.y * 32;
  if (c0 >= C) return;
  const int tx = threadIdx.x & 31, ty = threadIdx.x >> 5;
  #pragma unroll
  for (int i = 0; i < 4; i++)
    T[ty + i * 8][tx] = in[(size_t)(k0 + ty + i * 8) * C + c0 + tx];
  __syncthreads();
  #pragma unroll
  for (int i = 0; i < 4; i++)
    out[(size_t)(c0 + ty + i * 8) * 512 + k0 + tx] = f2bf(T[tx][ty + i * 8]);
}

// ---------------------------------------------------------------------------
// Merged MFMA projection v2: 256-row x 64-col block, LDS-staged X/W chunks
// (global_load_lds + XOR-granule swizzle), BK=64, 8 k-steps.
// grid (32, 12, 2):
//   z: input (0=a pos 0..4095, 1=x pos 4096..8191)
//   y: 0-7 -> Q head y (norm+rope); 8-9 -> K head y-8 (norm+rope, +Kt perm);
//      10-11 -> V head y-10 (plain, Vt perm only)
// Kt/Vt written with sigma-permuted token order within aligned 32-token groups.
// ---------------------------------------------------------------------------
__global__ __launch_bounds__(256) void proj_all_kernel(
    const unsigned short* __restrict__ Xa, const unsigned short* __restrict__ Xx,
    const unsigned short* __restrict__ WtQa, const unsigned short* __restrict__ WtKa,
    const unsigned short* __restrict__ WtVa, const unsigned short* __restrict__ WtQx,
    const unsigned short* __restrict__ WtKx, const unsigned short* __restrict__ WtVx,
    const float* __restrict__ gq_a, const float* __restrict__ gk_a,
    const float* __restrict__ gq_x, const float* __restrict__ gk_x,
    unsigned short* __restrict__ Qb, unsigned short* __restrict__ Kb,
    unsigned short* __restrict__ Kt, unsigned short* __restrict__ Vt)
{
  __shared__ __attribute__((aligned(16))) unsigned short Xs[256][64];
  __shared__ __attribute__((aligned(16))) unsigned short Ws[64][64];
  __shared__ unsigned short Tsh[64][72];
  const int tid = threadIdx.x;
  const int w = tid >> 6, l = tid & 63, lc = l & 15, lg = l >> 4;
  const int r7 = lc & 7;
  const int z = blockIdx.z;
  const int y = blockIdx.y;
  const int row0 = blockIdx.x * 256;
  const int pos_offset = z ? 4096 : 0;

  const unsigned short* Xbf = z ? Xx : Xa;
  const unsigned short* Wt;
  const float* gamma = nullptr;
  unsigned short* OUT = nullptr;
  unsigned short* OUTT = nullptr;
  int h, Hout, doNR;
  if (y < 8) {
    h = y; Hout = NH; doNR = 1;
    Wt = z ? WtQx : WtQa; gamma = z ? gq_x : gq_a; OUT = Qb;
  } else if (y < 10) {
    h = y - 8; Hout = NKV; doNR = 1;
    Wt = z ? WtKx : WtKa; gamma = z ? gk_x : gk_a; OUT = Kb; OUTT = Kt;
  } else {
    h = y - 10; Hout = NKV; doNR = 0;
    Wt = z ? WtVx : WtVa; OUTT = Vt;
  }

  // staging constants: srow = row within 32-row pass, swizzled source granule
  const int srow = tid >> 3;                 // 0..31
  const int sg   = (tid & 7) ^ (srow & 7);   // involution granule swizzle
  const unsigned short* Xrow = Xbf + (size_t)(row0 + srow) * 512 + sg * 8;
  const unsigned short* Wrow = Wt + (size_t)(h * 64 + srow) * 512 + sg * 8;

  f32x4 acc[4][4];
  #pragma unroll
  for (int m = 0; m < 4; m++)
    #pragma unroll
    for (int ct = 0; ct < 4; ct++) { acc[m][ct][0]=0.f; acc[m][ct][1]=0.f; acc[m][ct][2]=0.f; acc[m][ct][3]=0.f; }

  for (int s = 0; s < 8; s++) {
    const int k0 = s * 64;
    // ---- stage X chunk [256][64] (8 passes of 32 rows) ----
    #pragma unroll
    for (int p = 0; p < 8; p++)
      gload16(Xrow + (size_t)p * 32 * 512 + k0, &Xs[0][0] + p * 2048 + tid * 8);
    // ---- stage W chunk [64][64] (2 passes of 32 rows) ----
    #pragma unroll
    for (int p = 0; p < 2; p++)
      gload16(Wrow + (size_t)p * 32 * 512 + k0, &Ws[0][0] + p * 2048 + tid * 8);
    __syncthreads();

    __builtin_amdgcn_s_setprio(1);
    #pragma unroll
    for (int kc = 0; kc < 2; kc++) {
      short8v a8[4], b8[4];
      #pragma unroll
      for (int m = 0; m < 4; m++)
        a8[m] = *(const short8v*)&Xs[m * 64 + w * 16 + lc][(((kc * 4 + lg) ^ r7) & 7) * 8];
      #pragma unroll
      for (int ct = 0; ct < 4; ct++)
        b8[ct] = *(const short8v*)&Ws[ct * 16 + lc][(((kc * 4 + lg) ^ r7) & 7) * 8];
      #pragma unroll
      for (int m = 0; m < 4; m++)
        #pragma unroll
        for (int ct = 0; ct < 4; ct++)
          acc[m][ct] = __builtin_amdgcn_mfma_f32_16x16x32_bf16(a8[m], b8[ct], acc[m][ct], 0, 0, 0);
    }
    __builtin_amdgcn_s_setprio(0);
    __syncthreads();
  }

  // ---- epilogue: per 64-row round m: norm+rope in-register, Tsh, copy out ----
  float gam[4];
  float invf[2];
  if (doNR) {
    #pragma unroll
    for (int ct = 0; ct < 4; ct++) gam[ct] = gamma[h * 64 + ct * 16 + lc];
    const float LOG1E4 = 9.210340371976184f;
    invf[0] = __expf(-((float)lc / 32.f) * LOG1E4);
    invf[1] = __expf(-((float)(16 + lc) / 32.f) * LOG1E4);
  }

  #pragma unroll
  for (int m = 0; m < 4; m++) {
    if (doNR) {
      float srw[4];
      #pragma unroll
      for (int reg = 0; reg < 4; reg++) {
        float ss = acc[m][0][reg]*acc[m][0][reg] + acc[m][1][reg]*acc[m][1][reg]
                 + acc[m][2][reg]*acc[m][2][reg] + acc[m][3][reg]*acc[m][3][reg];
        ss += __shfl_xor(ss, 1, 64);
        ss += __shfl_xor(ss, 2, 64);
        ss += __shfl_xor(ss, 4, 64);
        ss += __shfl_xor(ss, 8, 64);
        srw[reg] = 8.0f / fmaxf(sqrtf(ss), 1e-12f);
      }
      const int posb = pos_offset + ((row0 + m * 64) & 4095) + w * 16 + lg * 4;
      #pragma unroll
      for (int reg = 0; reg < 4; reg++) {
        #pragma unroll
        for (int half = 0; half < 2; half++) {
          float ang = (float)(posb + reg) * invf[half];
          float sn, cs;
          sincosf(ang, &sn, &cs);
          float v1 = acc[m][half][reg] * srw[reg] * gam[half];
          float v2 = acc[m][half + 2][reg] * srw[reg] * gam[half + 2];
          acc[m][half][reg]     = v1 * cs - v2 * sn;
          acc[m][half + 2][reg] = v2 * cs + v1 * sn;
        }
      }
    }

    #pragma unroll
    for (int ct = 0; ct < 4; ct++)
      #pragma unroll
      for (int reg = 0; reg < 4; reg++)
        Tsh[w * 16 + lg * 4 + reg][ct * 16 + lc] = f2bf(acc[m][ct][reg]);
    __syncthreads();

    const int growm = row0 + m * 64;
    const int b = growm >> 12;
    const int pos0 = pos_offset + (growm & 4095);
    if (OUT) {
      const int r = tid >> 2, part = tid & 3;
      unsigned short* dst = OUT + (((size_t)b * Hout + h) * NTOK + pos0 + r) * 64 + part * 16;
      short8v u0 = *(const short8v*)&Tsh[r][part * 16];
      short8v u1 = *(const short8v*)&Tsh[r][part * 16 + 8];
      *(short8v*)dst = u0;
      *(short8v*)(dst + 8) = u1;
    }
    if (OUTT) {
      const int e = tid >> 2, part = tid & 3;
      short8v t0, t1;
      #pragma unroll
      for (int jj = 0; jj < 16; jj++) {
        const int LG = ((part & 1) << 1) | (jj >> 3);
        const int H  = (jj >> 2) & 1;
        const int I  = jj & 3;
        const int srcrow = (part >> 1) * 32 + H * 16 + LG * 4 + I;
        unsigned short v = Tsh[srcrow][e];
        if (jj < 8) t0[jj] = (short)v; else t1[jj - 8] = (short)v;
      }
      unsigned short* dstT = OUTT + (((size_t)b * NKV + h) * 64 + e) * NTOK + pos0 + part * 16;
      *(short8v*)dstT = t0;
      *(short8v*)(dstT + 8) = t1;
    }
    __syncthreads();
  }
}

// ---------------------------------------------------------------------------
// Per-segment partial summaries (8 n-chunks of 128 tokens) via MFMA from
// permuted Kt', Vt' (consistent k-slot pairing; sums order-invariant).
// grid 256 = (bkv*8+seg)*8+chunk.
// ---------------------------------------------------------------------------
__global__ __launch_bounds__(256) void seg_summary_kernel(
    const unsigned short* __restrict__ Kt, const unsigned short* __restrict__ Vt,
    float* __restrict__ Spart, float* __restrict__ Zpart)
{
  const int blk = blockIdx.x;
  const int chunk = blk & 7;
  const int seg = (blk >> 3) & 7;
  const int bkv = blk >> 6;
  const int tid = threadIdx.x;
  const int w = tid >> 6, l = tid & 63, lc = l & 15, lg = l >> 4;
  const unsigned short* KtB = Kt + ((size_t)bkv * 64) * NTOK + seg * SEGL + chunk * 128;
  const unsigned short* VtB = Vt + ((size_t)bkv * 64) * NTOK + seg * SEGL + chunk * 128;

  f32x4 acc[4];
  #pragma unroll
  for (int ct = 0; ct < 4; ct++) { acc[ct][0]=0.f; acc[ct][1]=0.f; acc[ct][2]=0.f; acc[ct][3]=0.f; }
  float zacc[4] = {0.f, 0.f, 0.f, 0.f};

  for (int n0 = 0; n0 < 128; n0 += 32) {
    short8v av = *(const short8v*)(VtB + (size_t)(w * 16 + lc) * NTOK + n0 + lg * 8);
    #pragma unroll
    for (int ct = 0; ct < 4; ct++) {
      short8v kv = *(const short8v*)(KtB + (size_t)(ct * 16 + lc) * NTOK + n0 + lg * 8);
      short8v skv;
      float zp = 0.f;
      #pragma unroll
      for (int i = 0; i < 8; i++) {
        float kf = bf2f((unsigned short)kv[i]);
        float sk = kf > 0.f ? kf + 1.f : __expf(kf);
        zp += sk;
        skv[i] = (short)f2bf(sk);
      }
      zacc[ct] += zp;
      acc[ct] = __builtin_amdgcn_mfma_f32_16x16x32_bf16(av, skv, acc[ct], 0, 0, 0);
    }
  }

  float* Sp = Spart + (size_t)blk * 4096;
  #pragma unroll
  for (int ct = 0; ct < 4; ct++)
    #pragma unroll
    for (int reg = 0; reg < 4; reg++)
      Sp[(size_t)(w * 16 + lg * 4 + reg) * 64 + ct * 16 + lc] = acc[ct][reg];

  if (w == 0) {
    #pragma unroll
    for (int ct = 0; ct < 4; ct++) {
      zacc[ct] += __shfl_xor(zacc[ct], 16, 64);
      zacc[ct] += __shfl_xor(zacc[ct], 32, 64);
    }
    if (lg == 0) {
      float* Zp = Zpart + (size_t)blk * 64;
      #pragma unroll
      for (int ct = 0; ct < 4; ct++) Zp[ct * 16 + lc] = zacc[ct];
    }
  }
}

// Chunk-reduce + exclusive prefix over segments -> bf16 PT + f32 PZ.
// grid (4, 16), block 256: one column per thread.
__global__ void prefix_kernel(const float* __restrict__ Spart, const float* __restrict__ Zpart,
                              unsigned short* __restrict__ PT, float* __restrict__ PZ)
{
  const int bkv = blockIdx.x;
  const int col = blockIdx.y * 256 + threadIdx.x;
  float run = 0.f;
  for (int s = 0; s < NSEG; s++) {
    float v = 0.f;
    #pragma unroll
    for (int c = 0; c < 8; c++)
      v += Spart[(((size_t)(bkv * 8 + s)) * 8 + c) * 4096 + col];
    PT[((size_t)bkv * 8 + s) * 4096 + col] = f2bf(run);
    run += v;
  }
  if (blockIdx.y == 0 && threadIdx.x < 64) {
    const int d = threadIdx.x;
    float rz = 0.f;
    for (int s = 0; s < NSEG; s++) {
      float v = 0.f;
      #pragma unroll
      for (int c = 0; c < 8; c++)
        v += Zpart[(((size_t)(bkv * 8 + s)) * 8 + c) * 64 + d];
      PZ[((size_t)bkv * 8 + s) * 64 + d] = rz;
      rz += v;
    }
  }
}

// ---------------------------------------------------------------------------
// MFMA flash attention v4: causal-balanced q-tile pair, global_load_lds
// staging (XOR-swizzled source granules, linear LDS), single barrier/step,
// b128 PV reads (V pre-permuted in global), setprio around MFMA.
// ---------------------------------------------------------------------------
__global__ __launch_bounds__(256, 4) void attn_mfma_kernel(
    const unsigned short* __restrict__ Qb, const unsigned short* __restrict__ Kb,
    const unsigned short* __restrict__ Vt, const unsigned short* __restrict__ PT,
    const float* __restrict__ PZ, const float* __restrict__ beta,
    float* __restrict__ OUT)
{
  __shared__ __attribute__((aligned(16))) unsigned short Ks[2][64][64];
  __shared__ __attribute__((aligned(16))) unsigned short Vs[2][64][64];
  const int tid = threadIdx.x;
  const int w = tid >> 6;
  const int l = tid & 63;
  const int lc = l & 15;
  const int lg = l >> 4;
  const int r7 = lc & 7;

  const int j   = blockIdx.x & 7;
  const int seg = (blockIdx.x >> 3) & 7;
  const int bh  = blockIdx.x >> 6;
  const int h = bh & (NH - 1), b = bh >> 3;
  const int bkv = b * NKV + (h & (NKV - 1));   // jnp.tile -> h % KVH
  const int qtA = 15 - j, qtB = j;
  const int segbase = seg * SEGL;

  const unsigned short* Kbase = Kb + ((size_t)bkv * NTOK + segbase) * 64;
  const unsigned short* Vbase = Vt + ((size_t)bkv * 64) * NTOK + segbase;

  // staging constants: row within 32-row pass, swizzled source granule
  const int srow = tid >> 3;                 // 0..31
  const int sg   = (tid & 7) ^ (srow & 7);   // involution granule swizzle

  // Q fragments for both tiles
  short8v aq0[2], aq1[2];
  {
    const unsigned short* qp =
        Qb + (((size_t)bh * NTOK) + segbase + qtA * 64 + w * 16 + lc) * 64 + lg * 8;
    aq0[0] = *(const short8v*)(qp);
    aq1[0] = *(const short8v*)(qp + 32);
  }
  {
    const unsigned short* qp =
        Qb + (((size_t)bh * NTOK) + segbase + qtB * 64 + w * 16 + lc) * 64 + lg * 8;
    aq0[1] = *(const short8v*)(qp);
    aq1[1] = *(const short8v*)(qp + 32);
  }

  f32x4 O[2][4];
  #pragma unroll
  for (int tt = 0; tt < 2; tt++)
    #pragma unroll
    for (int ce = 0; ce < 4; ce++) { O[tt][ce][0]=0.f; O[tt][ce][1]=0.f; O[tt][ce][2]=0.f; O[tt][ce][3]=0.f; }
  float rsumL[2] = {0.f, 0.f};

  // ---- prologue: stage tile 0 ----
  {
    unsigned short* kD = &Ks[0][0][0];
    unsigned short* vD = &Vs[0][0][0];
    #pragma unroll
    for (int p = 0; p < 2; p++) {
      const int row = p * 32 + srow;
      gload16(Kbase + (size_t)row * 64 + sg * 8, kD + p * 2048 + tid * 8);
      gload16(Vbase + (size_t)row * NTOK + sg * 8, vD + p * 2048 + tid * 8);
    }
  }
  __syncthreads();

  for (int kt = 0; kt <= qtA; ++kt) {
    const int buf = kt & 1;
    if (kt < qtA) {
      const int ktn = kt + 1;
      unsigned short* kD = &Ks[buf ^ 1][0][0];
      unsigned short* vD = &Vs[buf ^ 1][0][0];
      #pragma unroll
      for (int p = 0; p < 2; p++) {
        const int row = p * 32 + srow;
        gload16(Kbase + (size_t)(ktn * 64 + row) * 64 + sg * 8, kD + p * 2048 + tid * 8);
        gload16(Vbase + (size_t)row * NTOK + ktn * 64 + sg * 8, vD + p * 2048 + tid * 8);
      }
    }

    __builtin_amdgcn_s_setprio(1);
    #pragma unroll
    for (int tt = 0; tt < 2; tt++) {
      if (tt == 1 && kt > qtB) continue;
      const int qt_ = tt ? qtB : qtA;
      const bool diag = (kt == qt_);
      const int ctmax = diag ? w : 3;

      // ---- S^T = K Q^T, P = exp(s/8 - 8) with causal mask, packed in-lane ----
      short4v pa[4];
      #pragma unroll
      for (int ck = 0; ck < 4; ck++) {
        if (ck > ctmax) {
          pa[ck][0] = 0; pa[ck][1] = 0; pa[ck][2] = 0; pa[ck][3] = 0;
          continue;
        }
        f32x4 s;
        s[0]=0.f; s[1]=0.f; s[2]=0.f; s[3]=0.f;
        const int krow = ck * 16 + lc;
        short8v ak0 = *(const short8v*)&Ks[buf][krow][((lg ^ r7) & 7) * 8];
        short8v ak1 = *(const short8v*)&Ks[buf][krow][(((lg + 4) ^ r7) & 7) * 8];
        s = __builtin_amdgcn_mfma_f32_16x16x32_bf16(ak0, aq0[tt], s, 0, 0, 0);
        s = __builtin_amdgcn_mfma_f32_16x16x32_bf16(ak1, aq1[tt], s, 0, 0, 0);
        const bool needmask = diag && (ck == w);
        float p0 = __expf(s[0] * 0.125f - 8.0f);
        float p1 = __expf(s[1] * 0.125f - 8.0f);
        float p2 = __expf(s[2] * 0.125f - 8.0f);
        float p3 = __expf(s[3] * 0.125f - 8.0f);
        if (needmask) {
          if (lg * 4 + 0 > lc) p0 = 0.f;
          if (lg * 4 + 1 > lc) p1 = 0.f;
          if (lg * 4 + 2 > lc) p2 = 0.f;
          if (lg * 4 + 3 > lc) p3 = 0.f;
        }
        rsumL[tt] += p0 + p1 + p2 + p3;
        pa[ck][0] = (short)f2bf(p0);
        pa[ck][1] = (short)f2bf(p1);
        pa[ck][2] = (short)f2bf(p2);
        pa[ck][3] = (short)f2bf(p3);
      }

      // ---- O += P V via 16x16x32; B-frag = one b128 from permuted+swizzled Vs ----
      #pragma unroll
      for (int cp = 0; cp < 2; cp++) {
        if (cp * 2 > ctmax) continue;
        short8v a8;
        #pragma unroll
        for (int i = 0; i < 4; i++) { a8[i] = pa[cp * 2][i]; a8[4 + i] = pa[cp * 2 + 1][i]; }
        #pragma unroll
        for (int ce = 0; ce < 4; ce++) {
          short8v b8 = *(const short8v*)&Vs[buf][ce * 16 + lc][(((cp * 4 + lg) ^ r7) & 7) * 8];
          O[tt][ce] = __builtin_amdgcn_mfma_f32_16x16x32_bf16(a8, b8, O[tt][ce], 0, 0, 0);
        }
      }
    }
    __builtin_amdgcn_s_setprio(0);
    __syncthreads();
  }

  // ---- epilogue per tile: softmax sum + memory path + gated write ----
  const float g = 1.f / (1.f + __expf(-beta[h]));
  const float g1 = 1.f - g;
  const unsigned short* stp = PT + ((size_t)bkv * NSEG + seg) * 4096 + lc * 64 + lg * 8;
  const float* zp = PZ + ((size_t)bkv * NSEG + seg) * 64 + lg * 8;

  #pragma unroll
  for (int tt = 0; tt < 2; tt++) {
    float rsum = rsumL[tt];
    rsum += __shfl_xor(rsum, 16, 64);
    rsum += __shfl_xor(rsum, 32, 64);

    short8v asq0, asq1;
    float den = 1e-12f;
    #pragma unroll
    for (int i = 0; i < 8; i++) {
      float f0 = bf2f((unsigned short)aq0[tt][i]);
      float e0 = f0 > 0.f ? f0 + 1.f : __expf(f0);
      asq0[i] = (short)f2bf(e0);
      den += e0 * zp[i];
      float f1 = bf2f((unsigned short)aq1[tt][i]);
      float e1 = f1 > 0.f ? f1 + 1.f : __expf(f1);
      asq1[i] = (short)f2bf(e1);
      den += e1 * zp[32 + i];
    }
    f32x4 N[4];
    #pragma unroll
    for (int ct = 0; ct < 4; ct++) { N[ct][0]=0.f; N[ct][1]=0.f; N[ct][2]=0.f; N[ct][3]=0.f; }
    #pragma unroll
    for (int ct = 0; ct < 4; ct++) {
      short8v bs0 = *(const short8v*)(stp + ct * 16 * 64);
      short8v bs1 = *(const short8v*)(stp + ct * 16 * 64 + 32);
      N[ct] = __builtin_amdgcn_mfma_f32_16x16x32_bf16(asq0, bs0, N[ct], 0, 0, 0);
      N[ct] = __builtin_amdgcn_mfma_f32_16x16x32_bf16(asq1, bs1, N[ct], 0, 0, 0);
    }
    den += __shfl_xor(den, 16, 64);
    den += __shfl_xor(den, 32, 64);
    float denc[4], rs[4];
    #pragma unroll
    for (int reg = 0; reg < 4; reg++) {
      denc[reg] = __shfl(den, lg * 4 + reg, 64);
      rs[reg]   = __shfl(rsum, lg * 4 + reg, 64);
    }

    const int q0 = (tt ? qtB : qtA) * 64;
    const int nrow = segbase + q0 + w * 16 + lg * 4;
    #pragma unroll
    for (int reg = 0; reg < 4; reg++) {
      const int n = nrow + reg;
      const float invs = 1.f / rs[reg];
      const float invd = 1.f / denc[reg];
      size_t obase;
      if (n < 4096) obase = (size_t)BATCH * 4096 * 512 + (((size_t)b * 4096 + n) * NH + h) * 64;
      else          obase = (((size_t)b * 4096 + (n - 4096)) * NH + h) * 64;
      #pragma unroll
      for (int ce = 0; ce < 4; ce++) {
        OUT[obase + ce * 16 + lc] = g * N[ce][reg] * invd + g1 * O[tt][ce][reg] * invs;
      }
    }
  }
}

// ---------------------------------------------------------------------------
extern "C" void kernel_launch(void* const* d_in, const int* in_sizes, int n_in,
                              void* d_out, int out_size, void* d_ws, size_t ws_size,
                              hipStream_t stream) {
  const float* x    = (const float*)d_in[0];
  const float* a    = (const float*)d_in[1];
  const float* Wq_x = (const float*)d_in[2];
  const float* Wk_x = (const float*)d_in[3];
  const float* Wv_x = (const float*)d_in[4];
  const float* Wq_a = (const float*)d_in[5];
  const float* Wk_a = (const float*)d_in[6];
  const float* Wv_a = (const float*)d_in[7];
  const float* gq_x = (const float*)d_in[8];
  const float* gk_x = (const float*)d_in[9];
  const float* gq_a = (const float*)d_in[10];
  const float* gk_a = (const float*)d_in[11];
  const float* beta = (const float*)d_in[12];

  unsigned short* Qb = (unsigned short*)d_ws;          // 8388608
  unsigned short* Kb = Qb + (size_t)8388608;           // 2097152
  unsigned short* Kt = Kb + (size_t)2097152;           // 2097152 (permuted)
  unsigned short* Vt = Kt + (size_t)2097152;           // 2097152 (permuted)
  unsigned short* Xa = Vt + (size_t)2097152;           // 4194304
  unsigned short* Xx = Xa + (size_t)4194304;           // 4194304
  unsigned short* WtQa = Xx + (size_t)4194304;         // 262144
  unsigned short* WtKa = WtQa + (size_t)262144;        // 65536
  unsigned short* WtVa = WtKa + (size_t)65536;         // 65536
  unsigned short* WtQx = WtVa + (size_t)65536;         // 262144
  unsigned short* WtKx = WtQx + (size_t)262144;        // 65536
  unsigned short* WtVx = WtKx + (size_t)65536;         // 65536
  float* Spart = (float*)(WtVx + (size_t)65536);       // 1048576 f32 (4 MB)
  float* Zpart = Spart + (size_t)1048576;              // 16384
  float* PZ = Zpart + (size_t)16384;                   // 2048
  unsigned short* PT = (unsigned short*)(PZ + (size_t)2048); // 131072

  cast_bf16_kernel<<<dim3(2048, 2), 256, 0, stream>>>(a, x, Xa, Xx);
  wtrans_kernel<<<dim3(16, 16, 6), 256, 0, stream>>>(
      Wq_a, Wk_a, Wv_a, Wq_x, Wk_x, Wv_x, WtQa, WtKa, WtVa, WtQx, WtKx, WtVx);
  proj_all_kernel<<<dim3(32, 12, 2), 256, 0, stream>>>(
      Xa, Xx, WtQa, WtKa, WtVa, WtQx, WtKx, WtVx,
      gq_a, gk_a, gq_x, gk_x, Qb, Kb, Kt, Vt);
  seg_summary_kernel<<<256, 256, 0, stream>>>(Kt, Vt, Spart, Zpart);
  prefix_kernel<<<dim3(4, 16), 256, 0, stream>>>(Spart, Zpart, PT, PZ);
  attn_mfma_kernel<<<dim3(1024), 256, 0, stream>>>(Qb, Kb, Vt, PT, PZ, beta, (float*)d_out);
}

// Round 9
// 130.637 us; speedup vs baseline: 12.9607x; 1.2274x over previous
//
#include <hip/hip_runtime.h>
#include <math.h>

#define NH 8
#define NKV 2
#define SEGL 1024
#define NSEG 8
#define NTOK 8192
#define BATCH 2
#define DIMK 512

typedef short short8v __attribute__((ext_vector_type(8)));
typedef short short4v __attribute__((ext_vector_type(4)));
typedef float f32x4 __attribute__((ext_vector_type(4)));

__device__ __forceinline__ unsigned short f2bf(float f) {
  union { float f; unsigned u; } c; c.f = f;
  unsigned u = c.u;
  return (unsigned short)((u + 0x7FFFu + ((u >> 16) & 1u)) >> 16);
}
__device__ __forceinline__ float bf2f(unsigned short h) {
  union { unsigned u; float f; } c; c.u = ((unsigned)h) << 16;
  return c.f;
}

// async global->LDS, 16 bytes per lane. LDS dest must be wave-uniform + lane*16.
__device__ __forceinline__ void gload16(const unsigned short* g, unsigned short* l) {
  __builtin_amdgcn_global_load_lds(
      (const __attribute__((address_space(1))) unsigned int*)g,
      (__attribute__((address_space(3))) unsigned int*)l, 16, 0, 0);
}

// ---------------------------------------------------------------------------
// f32 -> bf16 cast; y selects input (0 = a, 1 = x).
// ---------------------------------------------------------------------------
__global__ void cast_bf16_kernel(const float* __restrict__ a, const float* __restrict__ x,
                                 unsigned short* __restrict__ outa,
                                 unsigned short* __restrict__ outx) {
  const float* in = blockIdx.y ? x : a;
  unsigned short* out = blockIdx.y ? outx : outa;
  int i = blockIdx.x * blockDim.x + threadIdx.x;
  const float4* p = (const float4*)in + (size_t)i * 2;
  float4 v0 = p[0], v1 = p[1];
  short8v o;
  o[0] = (short)f2bf(v0.x); o[1] = (short)f2bf(v0.y);
  o[2] = (short)f2bf(v0.z); o[3] = (short)f2bf(v0.w);
  o[4] = (short)f2bf(v1.x); o[5] = (short)f2bf(v1.y);
  o[6] = (short)f2bf(v1.z); o[7] = (short)f2bf(v1.w);
  *((short8v*)out + i) = o;
}

// ---------------------------------------------------------------------------
// RoPE cos/sin table: tab[pos][j] = cos(pos*invf_j), tab[pos][32+j] = sin(...)
// Identical float expressions to the previous in-kernel computation.
// ---------------------------------------------------------------------------
__global__ void rope_tab_kernel(float* __restrict__ tab) {
  const int i = blockIdx.x * 256 + threadIdx.x;   // over 8192*32
  const int pos = i >> 5, j = i & 31;
  const float LOG1E4 = 9.210340371976184f;
  float inv = __expf(-((float)j / 32.f) * LOG1E4);
  float sn, cs;
  sincosf((float)pos * inv, &sn, &cs);
  tab[(size_t)pos * 64 + j] = cs;
  tab[(size_t)pos * 64 + 32 + j] = sn;
}

// ---------------------------------------------------------------------------
// W (512 x C) f32 -> Wt (C x 512) bf16; z selects which of the 6 weights.
// ---------------------------------------------------------------------------
__global__ void wtrans_kernel(const float* __restrict__ w0, const float* __restrict__ w1,
                              const float* __restrict__ w2, const float* __restrict__ w3,
                              const float* __restrict__ w4, const float* __restrict__ w5,
                              unsigned short* __restrict__ o0, unsigned short* __restrict__ o1,
                              unsigned short* __restrict__ o2, unsigned short* __restrict__ o3,
                              unsigned short* __restrict__ o4, unsigned short* __restrict__ o5) {
  __shared__ float T[32][33];
  const int z = blockIdx.z;
  const float* in; unsigned short* out; int C;
  switch (z) {
    case 0: in = w0; out = o0; C = 512; break;
    case 1: in = w1; out = o1; C = 128; break;
    case 2: in = w2; out = o2; C = 128; break;
    case 3: in = w3; out = o3; C = 512; break;
    case 4: in = w4; out = o4; C = 128; break;
    default: in = w5; out = o5; C = 128; break;
  }
  const int c0 = blockIdx.x * 32, k0 = blockIdx.y * 32;
  if (c0 >= C) return;
  const int tx = threadIdx.x & 31, ty = threadIdx.x >> 5;
  #pragma unroll
  for (int i = 0; i < 4; i++)
    T[ty + i * 8][tx] = in[(size_t)(k0 + ty + i * 8) * C + c0 + tx];
  __syncthreads();
  #pragma unroll
  for (int i = 0; i < 4; i++)
    out[(size_t)(c0 + ty + i * 8) * 512 + k0 + tx] = f2bf(T[tx][ty + i * 8]);
}

// ---------------------------------------------------------------------------
// Merged MFMA projection v3: 128-row x 64-col block, double-buffered
// global_load_lds staging (attn-proven schedule: issue next -> compute -> one
// barrier), XOR-granule swizzle, BK=64, 8 k-steps. Tsh aliases Xs[0].
// grid (64, 12, 2).
// ---------------------------------------------------------------------------
__global__ __launch_bounds__(256, 3) void proj_all_kernel(
    const unsigned short* __restrict__ Xa, const unsigned short* __restrict__ Xx,
    const unsigned short* __restrict__ WtQa, const unsigned short* __restrict__ WtKa,
    const unsigned short* __restrict__ WtVa, const unsigned short* __restrict__ WtQx,
    const unsigned short* __restrict__ WtKx, const unsigned short* __restrict__ WtVx,
    const float* __restrict__ gq_a, const float* __restrict__ gk_a,
    const float* __restrict__ gq_x, const float* __restrict__ gk_x,
    const float* __restrict__ Rtab,
    unsigned short* __restrict__ Qb, unsigned short* __restrict__ Kb,
    unsigned short* __restrict__ Kt, unsigned short* __restrict__ Vt)
{
  __shared__ __attribute__((aligned(16))) unsigned short Xs[2][128][64];  // 32 KB
  __shared__ __attribute__((aligned(16))) unsigned short Ws2[2][64][64];  // 16 KB
  unsigned short (*Tsh)[72] = (unsigned short (*)[72])&Xs[0][0][0];       // alias

  const int tid = threadIdx.x;
  const int w = tid >> 6, l = tid & 63, lc = l & 15, lg = l >> 4;
  const int r7 = lc & 7;
  const int z = blockIdx.z;
  const int y = blockIdx.y;
  const int row0 = blockIdx.x * 128;
  const int pos_offset = z ? 4096 : 0;

  const unsigned short* Xbf = z ? Xx : Xa;
  const unsigned short* Wt;
  const float* gamma = nullptr;
  unsigned short* OUT = nullptr;
  unsigned short* OUTT = nullptr;
  int h, Hout, doNR;
  if (y < 8) {
    h = y; Hout = NH; doNR = 1;
    Wt = z ? WtQx : WtQa; gamma = z ? gq_x : gq_a; OUT = Qb;
  } else if (y < 10) {
    h = y - 8; Hout = NKV; doNR = 1;
    Wt = z ? WtKx : WtKa; gamma = z ? gk_x : gk_a; OUT = Kb; OUTT = Kt;
  } else {
    h = y - 10; Hout = NKV; doNR = 0;
    Wt = z ? WtVx : WtVa; OUTT = Vt;
  }

  // staging constants: srow = row within 32-row pass, swizzled source granule
  const int srow = tid >> 3;                 // 0..31
  const int sg   = (tid & 7) ^ (srow & 7);   // involution granule swizzle
  const unsigned short* Xrow = Xbf + (size_t)(row0 + srow) * 512 + sg * 8;
  const unsigned short* Wrow = Wt + (size_t)(h * 64 + srow) * 512 + sg * 8;

  f32x4 acc[2][4];
  #pragma unroll
  for (int m = 0; m < 2; m++)
    #pragma unroll
    for (int ct = 0; ct < 4; ct++) { acc[m][ct][0]=0.f; acc[m][ct][1]=0.f; acc[m][ct][2]=0.f; acc[m][ct][3]=0.f; }

  // ---- prologue: stage k-step 0 into buf 0 ----
  #pragma unroll
  for (int p = 0; p < 4; p++)
    gload16(Xrow + (size_t)p * 32 * 512, &Xs[0][0][0] + p * 2048 + tid * 8);
  #pragma unroll
  for (int p = 0; p < 2; p++)
    gload16(Wrow + (size_t)p * 32 * 512, &Ws2[0][0][0] + p * 2048 + tid * 8);
  __syncthreads();

  for (int s = 0; s < 8; s++) {
    const int buf = s & 1;
    if (s < 7) {
      const int k0n = (s + 1) * 64;
      #pragma unroll
      for (int p = 0; p < 4; p++)
        gload16(Xrow + (size_t)p * 32 * 512 + k0n, &Xs[buf ^ 1][0][0] + p * 2048 + tid * 8);
      #pragma unroll
      for (int p = 0; p < 2; p++)
        gload16(Wrow + (size_t)p * 32 * 512 + k0n, &Ws2[buf ^ 1][0][0] + p * 2048 + tid * 8);
    }

    __builtin_amdgcn_s_setprio(1);
    #pragma unroll
    for (int kc = 0; kc < 2; kc++) {
      const int gsw = (((kc * 4 + lg) ^ r7) & 7) * 8;
      short8v a8[2], b8[4];
      #pragma unroll
      for (int m = 0; m < 2; m++)
        a8[m] = *(const short8v*)&Xs[buf][m * 64 + w * 16 + lc][gsw];
      #pragma unroll
      for (int ct = 0; ct < 4; ct++)
        b8[ct] = *(const short8v*)&Ws2[buf][ct * 16 + lc][gsw];
      #pragma unroll
      for (int m = 0; m < 2; m++)
        #pragma unroll
        for (int ct = 0; ct < 4; ct++)
          acc[m][ct] = __builtin_amdgcn_mfma_f32_16x16x32_bf16(a8[m], b8[ct], acc[m][ct], 0, 0, 0);
    }
    __builtin_amdgcn_s_setprio(0);
    __syncthreads();
  }

  // ---- epilogue: per 64-row round m (Tsh aliases Xs[0]; all staging done) ----
  float gam[4];
  if (doNR) {
    #pragma unroll
    for (int ct = 0; ct < 4; ct++) gam[ct] = gamma[h * 64 + ct * 16 + lc];
  }

  #pragma unroll
  for (int m = 0; m < 2; m++) {
    if (doNR) {
      float srw[4];
      #pragma unroll
      for (int reg = 0; reg < 4; reg++) {
        float ss = acc[m][0][reg]*acc[m][0][reg] + acc[m][1][reg]*acc[m][1][reg]
                 + acc[m][2][reg]*acc[m][2][reg] + acc[m][3][reg]*acc[m][3][reg];
        ss += __shfl_xor(ss, 1, 64);
        ss += __shfl_xor(ss, 2, 64);
        ss += __shfl_xor(ss, 4, 64);
        ss += __shfl_xor(ss, 8, 64);
        srw[reg] = 8.0f / fmaxf(sqrtf(ss), 1e-12f);
      }
      const int posb = pos_offset + ((row0 + m * 64) & 4095) + w * 16 + lg * 4;
      #pragma unroll
      for (int reg = 0; reg < 4; reg++) {
        const float* tabr = Rtab + (size_t)(posb + reg) * 64;
        #pragma unroll
        for (int half = 0; half < 2; half++) {
          float cs = tabr[half * 16 + lc];
          float sn = tabr[32 + half * 16 + lc];
          float v1 = acc[m][half][reg] * srw[reg] * gam[half];
          float v2 = acc[m][half + 2][reg] * srw[reg] * gam[half + 2];
          acc[m][half][reg]     = v1 * cs - v2 * sn;
          acc[m][half + 2][reg] = v2 * cs + v1 * sn;
        }
      }
    }

    #pragma unroll
    for (int ct = 0; ct < 4; ct++)
      #pragma unroll
      for (int reg = 0; reg < 4; reg++)
        Tsh[w * 16 + lg * 4 + reg][ct * 16 + lc] = f2bf(acc[m][ct][reg]);
    __syncthreads();

    const int growm = row0 + m * 64;
    const int b = growm >> 12;
    const int pos0 = pos_offset + (growm & 4095);
    if (OUT) {
      const int r = tid >> 2, part = tid & 3;
      unsigned short* dst = OUT + (((size_t)b * Hout + h) * NTOK + pos0 + r) * 64 + part * 16;
      short8v u0 = *(const short8v*)&Tsh[r][part * 16];
      short8v u1 = *(const short8v*)&Tsh[r][part * 16 + 8];
      *(short8v*)dst = u0;
      *(short8v*)(dst + 8) = u1;
    }
    if (OUTT) {
      const int e = tid >> 2, part = tid & 3;
      short8v t0, t1;
      #pragma unroll
      for (int jj = 0; jj < 16; jj++) {
        const int LG = ((part & 1) << 1) | (jj >> 3);
        const int H  = (jj >> 2) & 1;
        const int I  = jj & 3;
        const int srcrow = (part >> 1) * 32 + H * 16 + LG * 4 + I;
        unsigned short v = Tsh[srcrow][e];
        if (jj < 8) t0[jj] = (short)v; else t1[jj - 8] = (short)v;
      }
      unsigned short* dstT = OUTT + (((size_t)b * NKV + h) * 64 + e) * NTOK + pos0 + part * 16;
      *(short8v*)dstT = t0;
      *(short8v*)(dstT + 8) = t1;
    }
    __syncthreads();
  }
}

// ---------------------------------------------------------------------------
// Per-segment partial summaries (8 n-chunks of 128 tokens) via MFMA from
// permuted Kt', Vt' (consistent k-slot pairing; sums order-invariant).
// grid 256 = (bkv*8+seg)*8+chunk.
// ---------------------------------------------------------------------------
__global__ __launch_bounds__(256) void seg_summary_kernel(
    const unsigned short* __restrict__ Kt, const unsigned short* __restrict__ Vt,
    float* __restrict__ Spart, float* __restrict__ Zpart)
{
  const int blk = blockIdx.x;
  const int chunk = blk & 7;
  const int seg = (blk >> 3) & 7;
  const int bkv = blk >> 6;
  const int tid = threadIdx.x;
  const int w = tid >> 6, l = tid & 63, lc = l & 15, lg = l >> 4;
  const unsigned short* KtB = Kt + ((size_t)bkv * 64) * NTOK + seg * SEGL + chunk * 128;
  const unsigned short* VtB = Vt + ((size_t)bkv * 64) * NTOK + seg * SEGL + chunk * 128;

  f32x4 acc[4];
  #pragma unroll
  for (int ct = 0; ct < 4; ct++) { acc[ct][0]=0.f; acc[ct][1]=0.f; acc[ct][2]=0.f; acc[ct][3]=0.f; }
  float zacc[4] = {0.f, 0.f, 0.f, 0.f};

  for (int n0 = 0; n0 < 128; n0 += 32) {
    short8v av = *(const short8v*)(VtB + (size_t)(w * 16 + lc) * NTOK + n0 + lg * 8);
    #pragma unroll
    for (int ct = 0; ct < 4; ct++) {
      short8v kv = *(const short8v*)(KtB + (size_t)(ct * 16 + lc) * NTOK + n0 + lg * 8);
      short8v skv;
      float zp = 0.f;
      #pragma unroll
      for (int i = 0; i < 8; i++) {
        float kf = bf2f((unsigned short)kv[i]);
        float sk = kf > 0.f ? kf + 1.f : __expf(kf);
        zp += sk;
        skv[i] = (short)f2bf(sk);
      }
      zacc[ct] += zp;
      acc[ct] = __builtin_amdgcn_mfma_f32_16x16x32_bf16(av, skv, acc[ct], 0, 0, 0);
    }
  }

  float* Sp = Spart + (size_t)blk * 4096;
  #pragma unroll
  for (int ct = 0; ct < 4; ct++)
    #pragma unroll
    for (int reg = 0; reg < 4; reg++)
      Sp[(size_t)(w * 16 + lg * 4 + reg) * 64 + ct * 16 + lc] = acc[ct][reg];

  if (w == 0) {
    #pragma unroll
    for (int ct = 0; ct < 4; ct++) {
      zacc[ct] += __shfl_xor(zacc[ct], 16, 64);
      zacc[ct] += __shfl_xor(zacc[ct], 32, 64);
    }
    if (lg == 0) {
      float* Zp = Zpart + (size_t)blk * 64;
      #pragma unroll
      for (int ct = 0; ct < 4; ct++) Zp[ct * 16 + lc] = zacc[ct];
    }
  }
}

// Chunk-reduce + exclusive prefix over segments -> bf16 PT + f32 PZ.
// grid (4, 16), block 256: one column per thread.
__global__ void prefix_kernel(const float* __restrict__ Spart, const float* __restrict__ Zpart,
                              unsigned short* __restrict__ PT, float* __restrict__ PZ)
{
  const int bkv = blockIdx.x;
  const int col = blockIdx.y * 256 + threadIdx.x;
  float run = 0.f;
  for (int s = 0; s < NSEG; s++) {
    float v = 0.f;
    #pragma unroll
    for (int c = 0; c < 8; c++)
      v += Spart[(((size_t)(bkv * 8 + s)) * 8 + c) * 4096 + col];
    PT[((size_t)bkv * 8 + s) * 4096 + col] = f2bf(run);
    run += v;
  }
  if (blockIdx.y == 0 && threadIdx.x < 64) {
    const int d = threadIdx.x;
    float rz = 0.f;
    for (int s = 0; s < NSEG; s++) {
      float v = 0.f;
      #pragma unroll
      for (int c = 0; c < 8; c++)
        v += Zpart[(((size_t)(bkv * 8 + s)) * 8 + c) * 64 + d];
      PZ[((size_t)bkv * 8 + s) * 64 + d] = rz;
      rz += v;
    }
  }
}

// ---------------------------------------------------------------------------
// MFMA flash attention v4: causal-balanced q-tile pair, global_load_lds
// staging (XOR-swizzled source granules, linear LDS), single barrier/step,
// b128 PV reads (V pre-permuted in global), setprio around MFMA.
// ---------------------------------------------------------------------------
__global__ __launch_bounds__(256, 4) void attn_mfma_kernel(
    const unsigned short* __restrict__ Qb, const unsigned short* __restrict__ Kb,
    const unsigned short* __restrict__ Vt, const unsigned short* __restrict__ PT,
    const float* __restrict__ PZ, const float* __restrict__ beta,
    float* __restrict__ OUT)
{
  __shared__ __attribute__((aligned(16))) unsigned short Ks[2][64][64];
  __shared__ __attribute__((aligned(16))) unsigned short Vs[2][64][64];
  const int tid = threadIdx.x;
  const int w = tid >> 6;
  const int l = tid & 63;
  const int lc = l & 15;
  const int lg = l >> 4;
  const int r7 = lc & 7;

  const int j   = blockIdx.x & 7;
  const int seg = (blockIdx.x >> 3) & 7;
  const int bh  = blockIdx.x >> 6;
  const int h = bh & (NH - 1), b = bh >> 3;
  const int bkv = b * NKV + (h & (NKV - 1));   // jnp.tile -> h % KVH
  const int qtA = 15 - j, qtB = j;
  const int segbase = seg * SEGL;

  const unsigned short* Kbase = Kb + ((size_t)bkv * NTOK + segbase) * 64;
  const unsigned short* Vbase = Vt + ((size_t)bkv * 64) * NTOK + segbase;

  // staging constants: row within 32-row pass, swizzled source granule
  const int srow = tid >> 3;                 // 0..31
  const int sg   = (tid & 7) ^ (srow & 7);   // involution granule swizzle

  // Q fragments for both tiles
  short8v aq0[2], aq1[2];
  {
    const unsigned short* qp =
        Qb + (((size_t)bh * NTOK) + segbase + qtA * 64 + w * 16 + lc) * 64 + lg * 8;
    aq0[0] = *(const short8v*)(qp);
    aq1[0] = *(const short8v*)(qp + 32);
  }
  {
    const unsigned short* qp =
        Qb + (((size_t)bh * NTOK) + segbase + qtB * 64 + w * 16 + lc) * 64 + lg * 8;
    aq0[1] = *(const short8v*)(qp);
    aq1[1] = *(const short8v*)(qp + 32);
  }

  f32x4 O[2][4];
  #pragma unroll
  for (int tt = 0; tt < 2; tt++)
    #pragma unroll
    for (int ce = 0; ce < 4; ce++) { O[tt][ce][0]=0.f; O[tt][ce][1]=0.f; O[tt][ce][2]=0.f; O[tt][ce][3]=0.f; }
  float rsumL[2] = {0.f, 0.f};

  // ---- prologue: stage tile 0 ----
  {
    unsigned short* kD = &Ks[0][0][0];
    unsigned short* vD = &Vs[0][0][0];
    #pragma unroll
    for (int p = 0; p < 2; p++) {
      const int row = p * 32 + srow;
      gload16(Kbase + (size_t)row * 64 + sg * 8, kD + p * 2048 + tid * 8);
      gload16(Vbase + (size_t)row * NTOK + sg * 8, vD + p * 2048 + tid * 8);
    }
  }
  __syncthreads();

  for (int kt = 0; kt <= qtA; ++kt) {
    const int buf = kt & 1;
    if (kt < qtA) {
      const int ktn = kt + 1;
      unsigned short* kD = &Ks[buf ^ 1][0][0];
      unsigned short* vD = &Vs[buf ^ 1][0][0];
      #pragma unroll
      for (int p = 0; p < 2; p++) {
        const int row = p * 32 + srow;
        gload16(Kbase + (size_t)(ktn * 64 + row) * 64 + sg * 8, kD + p * 2048 + tid * 8);
        gload16(Vbase + (size_t)row * NTOK + ktn * 64 + sg * 8, vD + p * 2048 + tid * 8);
      }
    }

    __builtin_amdgcn_s_setprio(1);
    #pragma unroll
    for (int tt = 0; tt < 2; tt++) {
      if (tt == 1 && kt > qtB) continue;
      const int qt_ = tt ? qtB : qtA;
      const bool diag = (kt == qt_);
      const int ctmax = diag ? w : 3;

      // ---- S^T = K Q^T, P = exp(s/8 - 8) with causal mask, packed in-lane ----
      short4v pa[4];
      #pragma unroll
      for (int ck = 0; ck < 4; ck++) {
        if (ck > ctmax) {
          pa[ck][0] = 0; pa[ck][1] = 0; pa[ck][2] = 0; pa[ck][3] = 0;
          continue;
        }
        f32x4 s;
        s[0]=0.f; s[1]=0.f; s[2]=0.f; s[3]=0.f;
        const int krow = ck * 16 + lc;
        short8v ak0 = *(const short8v*)&Ks[buf][krow][((lg ^ r7) & 7) * 8];
        short8v ak1 = *(const short8v*)&Ks[buf][krow][(((lg + 4) ^ r7) & 7) * 8];
        s = __builtin_amdgcn_mfma_f32_16x16x32_bf16(ak0, aq0[tt], s, 0, 0, 0);
        s = __builtin_amdgcn_mfma_f32_16x16x32_bf16(ak1, aq1[tt], s, 0, 0, 0);
        const bool needmask = diag && (ck == w);
        float p0 = __expf(s[0] * 0.125f - 8.0f);
        float p1 = __expf(s[1] * 0.125f - 8.0f);
        float p2 = __expf(s[2] * 0.125f - 8.0f);
        float p3 = __expf(s[3] * 0.125f - 8.0f);
        if (needmask) {
          if (lg * 4 + 0 > lc) p0 = 0.f;
          if (lg * 4 + 1 > lc) p1 = 0.f;
          if (lg * 4 + 2 > lc) p2 = 0.f;
          if (lg * 4 + 3 > lc) p3 = 0.f;
        }
        rsumL[tt] += p0 + p1 + p2 + p3;
        pa[ck][0] = (short)f2bf(p0);
        pa[ck][1] = (short)f2bf(p1);
        pa[ck][2] = (short)f2bf(p2);
        pa[ck][3] = (short)f2bf(p3);
      }

      // ---- O += P V via 16x16x32; B-frag = one b128 from permuted+swizzled Vs ----
      #pragma unroll
      for (int cp = 0; cp < 2; cp++) {
        if (cp * 2 > ctmax) continue;
        short8v a8;
        #pragma unroll
        for (int i = 0; i < 4; i++) { a8[i] = pa[cp * 2][i]; a8[4 + i] = pa[cp * 2 + 1][i]; }
        #pragma unroll
        for (int ce = 0; ce < 4; ce++) {
          short8v b8 = *(const short8v*)&Vs[buf][ce * 16 + lc][(((cp * 4 + lg) ^ r7) & 7) * 8];
          O[tt][ce] = __builtin_amdgcn_mfma_f32_16x16x32_bf16(a8, b8, O[tt][ce], 0, 0, 0);
        }
      }
    }
    __builtin_amdgcn_s_setprio(0);
    __syncthreads();
  }

  // ---- epilogue per tile: softmax sum + memory path + gated write ----
  const float g = 1.f / (1.f + __expf(-beta[h]));
  const float g1 = 1.f - g;
  const unsigned short* stp = PT + ((size_t)bkv * NSEG + seg) * 4096 + lc * 64 + lg * 8;
  const float* zp = PZ + ((size_t)bkv * NSEG + seg) * 64 + lg * 8;

  #pragma unroll
  for (int tt = 0; tt < 2; tt++) {
    float rsum = rsumL[tt];
    rsum += __shfl_xor(rsum, 16, 64);
    rsum += __shfl_xor(rsum, 32, 64);

    short8v asq0, asq1;
    float den = 1e-12f;
    #pragma unroll
    for (int i = 0; i < 8; i++) {
      float f0 = bf2f((unsigned short)aq0[tt][i]);
      float e0 = f0 > 0.f ? f0 + 1.f : __expf(f0);
      asq0[i] = (short)f2bf(e0);
      den += e0 * zp[i];
      float f1 = bf2f((unsigned short)aq1[tt][i]);
      float e1 = f1 > 0.f ? f1 + 1.f : __expf(f1);
      asq1[i] = (short)f2bf(e1);
      den += e1 * zp[32 + i];
    }
    f32x4 N[4];
    #pragma unroll
    for (int ct = 0; ct < 4; ct++) { N[ct][0]=0.f; N[ct][1]=0.f; N[ct][2]=0.f; N[ct][3]=0.f; }
    #pragma unroll
    for (int ct = 0; ct < 4; ct++) {
      short8v bs0 = *(const short8v*)(stp + ct * 16 * 64);
      short8v bs1 = *(const short8v*)(stp + ct * 16 * 64 + 32);
      N[ct] = __builtin_amdgcn_mfma_f32_16x16x32_bf16(asq0, bs0, N[ct], 0, 0, 0);
      N[ct] = __builtin_amdgcn_mfma_f32_16x16x32_bf16(asq1, bs1, N[ct], 0, 0, 0);
    }
    den += __shfl_xor(den, 16, 64);
    den += __shfl_xor(den, 32, 64);
    float denc[4], rs[4];
    #pragma unroll
    for (int reg = 0; reg < 4; reg++) {
      denc[reg] = __shfl(den, lg * 4 + reg, 64);
      rs[reg]   = __shfl(rsum, lg * 4 + reg, 64);
    }

    const int q0 = (tt ? qtB : qtA) * 64;
    const int nrow = segbase + q0 + w * 16 + lg * 4;
    #pragma unroll
    for (int reg = 0; reg < 4; reg++) {
      const int n = nrow + reg;
      const float invs = 1.f / rs[reg];
      const float invd = 1.f / denc[reg];
      size_t obase;
      if (n < 4096) obase = (size_t)BATCH * 4096 * 512 + (((size_t)b * 4096 + n) * NH + h) * 64;
      else          obase = (((size_t)b * 4096 + (n - 4096)) * NH + h) * 64;
      #pragma unroll
      for (int ce = 0; ce < 4; ce++) {
        OUT[obase + ce * 16 + lc] = g * N[ce][reg] * invd + g1 * O[tt][ce][reg] * invs;
      }
    }
  }
}

// ---------------------------------------------------------------------------
extern "C" void kernel_launch(void* const* d_in, const int* in_sizes, int n_in,
                              void* d_out, int out_size, void* d_ws, size_t ws_size,
                              hipStream_t stream) {
  const float* x    = (const float*)d_in[0];
  const float* a    = (const float*)d_in[1];
  const float* Wq_x = (const float*)d_in[2];
  const float* Wk_x = (const float*)d_in[3];
  const float* Wv_x = (const float*)d_in[4];
  const float* Wq_a = (const float*)d_in[5];
  const float* Wk_a = (const float*)d_in[6];
  const float* Wv_a = (const float*)d_in[7];
  const float* gq_x = (const float*)d_in[8];
  const float* gk_x = (const float*)d_in[9];
  const float* gq_a = (const float*)d_in[10];
  const float* gk_a = (const float*)d_in[11];
  const float* beta = (const float*)d_in[12];

  unsigned short* Qb = (unsigned short*)d_ws;          // 8388608
  unsigned short* Kb = Qb + (size_t)8388608;           // 2097152
  unsigned short* Kt = Kb + (size_t)2097152;           // 2097152 (permuted)
  unsigned short* Vt = Kt + (size_t)2097152;           // 2097152 (permuted)
  unsigned short* Xa = Vt + (size_t)2097152;           // 4194304
  unsigned short* Xx = Xa + (size_t)4194304;           // 4194304
  unsigned short* WtQa = Xx + (size_t)4194304;         // 262144
  unsigned short* WtKa = WtQa + (size_t)262144;        // 65536
  unsigned short* WtVa = WtKa + (size_t)65536;         // 65536
  unsigned short* WtQx = WtVa + (size_t)65536;         // 262144
  unsigned short* WtKx = WtQx + (size_t)262144;        // 65536
  unsigned short* WtVx = WtKx + (size_t)65536;         // 65536
  float* Spart = (float*)(WtVx + (size_t)65536);       // 1048576 f32 (4 MB)
  float* Zpart = Spart + (size_t)1048576;              // 16384
  float* PZ = Zpart + (size_t)16384;                   // 2048
  unsigned short* PT = (unsigned short*)(PZ + (size_t)2048); // 131072 bf16
  float* Rtab = (float*)(PT + (size_t)131072);         // 524288 f32 (2 MB)

  cast_bf16_kernel<<<dim3(2048, 2), 256, 0, stream>>>(a, x, Xa, Xx);
  rope_tab_kernel<<<1024, 256, 0, stream>>>(Rtab);
  wtrans_kernel<<<dim3(16, 16, 6), 256, 0, stream>>>(
      Wq_a, Wk_a, Wv_a, Wq_x, Wk_x, Wv_x, WtQa, WtKa, WtVa, WtQx, WtKx, WtVx);
  proj_all_kernel<<<dim3(64, 12, 2), 256, 0, stream>>>(
      Xa, Xx, WtQa, WtKa, WtVa, WtQx, WtKx, WtVx,
      gq_a, gk_a, gq_x, gk_x, Rtab, Qb, Kb, Kt, Vt);
  seg_summary_kernel<<<256, 256, 0, stream>>>(Kt, Vt, Spart, Zpart);
  prefix_kernel<<<dim3(4, 16), 256, 0, stream>>>(Spart, Zpart, PT, PZ);
  attn_mfma_kernel<<<dim3(1024), 256, 0, stream>>>(Qb, Kb, Vt, PT, PZ, beta, (float*)d_out);
}

// Round 11
// 103.331 us; speedup vs baseline: 16.3856x; 1.2643x over previous
//
#include <hip/hip_runtime.h>
#include <math.h>

#define NH 8
#define NKV 2
#define SEGL 1024
#define NSEG 8
#define NTOK 8192
#define BATCH 2
#define DIMK 512

typedef short short8v __attribute__((ext_vector_type(8)));
typedef short short4v __attribute__((ext_vector_type(4)));
typedef float f32x4 __attribute__((ext_vector_type(4)));

__device__ __forceinline__ unsigned short f2bf(float f) {
  union { float f; unsigned u; } c; c.f = f;
  unsigned u = c.u;
  return (unsigned short)((u + 0x7FFFu + ((u >> 16) & 1u)) >> 16);
}
__device__ __forceinline__ float bf2f(unsigned short h) {
  union { unsigned u; float f; } c; c.u = ((unsigned)h) << 16;
  return c.f;
}

// async global->LDS, 16 bytes per lane. LDS dest must be wave-uniform + lane*16.
__device__ __forceinline__ void gload16(const unsigned short* g, unsigned short* l) {
  __builtin_amdgcn_global_load_lds(
      (const __attribute__((address_space(1))) unsigned int*)g,
      (__attribute__((address_space(3))) unsigned int*)l, 16, 0, 0);
}

// ---------------------------------------------------------------------------
// f32 -> bf16 cast; y selects input (0 = a, 1 = x).
// ---------------------------------------------------------------------------
__global__ void cast_bf16_kernel(const float* __restrict__ a, const float* __restrict__ x,
                                 unsigned short* __restrict__ outa,
                                 unsigned short* __restrict__ outx) {
  const float* in = blockIdx.y ? x : a;
  unsigned short* out = blockIdx.y ? outx : outa;
  int i = blockIdx.x * blockDim.x + threadIdx.x;
  const float4* p = (const float4*)in + (size_t)i * 2;
  float4 v0 = p[0], v1 = p[1];
  short8v o;
  o[0] = (short)f2bf(v0.x); o[1] = (short)f2bf(v0.y);
  o[2] = (short)f2bf(v0.z); o[3] = (short)f2bf(v0.w);
  o[4] = (short)f2bf(v1.x); o[5] = (short)f2bf(v1.y);
  o[6] = (short)f2bf(v1.z); o[7] = (short)f2bf(v1.w);
  *((short8v*)out + i) = o;
}

// ---------------------------------------------------------------------------
// RoPE cos/sin table: tab[pos][j] = cos(pos*invf_j), tab[pos][32+j] = sin(...)
// ---------------------------------------------------------------------------
__global__ void rope_tab_kernel(float* __restrict__ tab) {
  const int i = blockIdx.x * 256 + threadIdx.x;   // over 8192*32
  const int pos = i >> 5, j = i & 31;
  const float LOG1E4 = 9.210340371976184f;
  float inv = __expf(-((float)j / 32.f) * LOG1E4);
  float sn, cs;
  sincosf((float)pos * inv, &sn, &cs);
  tab[(size_t)pos * 64 + j] = cs;
  tab[(size_t)pos * 64 + 32 + j] = sn;
}

// ---------------------------------------------------------------------------
// W (512 x C) f32 -> Wt (C x 512) bf16; z selects which of the 6 weights.
// ---------------------------------------------------------------------------
__global__ void wtrans_kernel(const float* __restrict__ w0, const float* __restrict__ w1,
                              const float* __restrict__ w2, const float* __restrict__ w3,
                              const float* __restrict__ w4, const float* __restrict__ w5,
                              unsigned short* __restrict__ o0, unsigned short* __restrict__ o1,
                              unsigned short* __restrict__ o2, unsigned short* __restrict__ o3,
                              unsigned short* __restrict__ o4, unsigned short* __restrict__ o5) {
  __shared__ float T[32][33];
  const int z = blockIdx.z;
  const float* in; unsigned short* out; int C;
  switch (z) {
    case 0: in = w0; out = o0; C = 512; break;
    case 1: in = w1; out = o1; C = 128; break;
    case 2: in = w2; out = o2; C = 128; break;
    case 3: in = w3; out = o3; C = 512; break;
    case 4: in = w4; out = o4; C = 128; break;
    default: in = w5; out = o5; C = 128; break;
  }
  const int c0 = blockIdx.x * 32, k0 = blockIdx.y * 32;
  if (c0 >= C) return;
  const int tx = threadIdx.x & 31, ty = threadIdx.x >> 5;
  #pragma unroll
  for (int i = 0; i < 4; i++)
    T[ty + i * 8][tx] = in[(size_t)(k0 + ty + i * 8) * C + c0 + tx];
  __syncthreads();
  #pragma unroll
  for (int i = 0; i < 4; i++)
    out[(size_t)(c0 + ty + i * 8) * 512 + k0 + tx] = f2bf(T[tx][ty + i * 8]);
}

// ---------------------------------------------------------------------------
// Merged MFMA projection v3: 128-row x 64-col block, double-buffered
// global_load_lds staging, XOR-granule swizzle, BK=64, 8 k-steps.
// grid (64, 12, 2).
// ---------------------------------------------------------------------------
__global__ __launch_bounds__(256, 3) void proj_all_kernel(
    const unsigned short* __restrict__ Xa, const unsigned short* __restrict__ Xx,
    const unsigned short* __restrict__ WtQa, const unsigned short* __restrict__ WtKa,
    const unsigned short* __restrict__ WtVa, const unsigned short* __restrict__ WtQx,
    const unsigned short* __restrict__ WtKx, const unsigned short* __restrict__ WtVx,
    const float* __restrict__ gq_a, const float* __restrict__ gk_a,
    const float* __restrict__ gq_x, const float* __restrict__ gk_x,
    const float* __restrict__ Rtab,
    unsigned short* __restrict__ Qb, unsigned short* __restrict__ Kb,
    unsigned short* __restrict__ Kt, unsigned short* __restrict__ Vt)
{
  __shared__ __attribute__((aligned(16))) unsigned short Xs[2][128][64];  // 32 KB
  __shared__ __attribute__((aligned(16))) unsigned short Ws2[2][64][64];  // 16 KB
  unsigned short (*Tsh)[72] = (unsigned short (*)[72])&Xs[0][0][0];       // alias

  const int tid = threadIdx.x;
  const int w = tid >> 6, l = tid & 63, lc = l & 15, lg = l >> 4;
  const int r7 = lc & 7;
  const int z = blockIdx.z;
  const int y = blockIdx.y;
  const int row0 = blockIdx.x * 128;
  const int pos_offset = z ? 4096 : 0;

  const unsigned short* Xbf = z ? Xx : Xa;
  const unsigned short* Wt;
  const float* gamma = nullptr;
  unsigned short* OUT = nullptr;
  unsigned short* OUTT = nullptr;
  int h, Hout, doNR;
  if (y < 8) {
    h = y; Hout = NH; doNR = 1;
    Wt = z ? WtQx : WtQa; gamma = z ? gq_x : gq_a; OUT = Qb;
  } else if (y < 10) {
    h = y - 8; Hout = NKV; doNR = 1;
    Wt = z ? WtKx : WtKa; gamma = z ? gk_x : gk_a; OUT = Kb; OUTT = Kt;
  } else {
    h = y - 10; Hout = NKV; doNR = 0;
    Wt = z ? WtVx : WtVa; OUTT = Vt;
  }

  const int srow = tid >> 3;
  const int sg   = (tid & 7) ^ (srow & 7);
  const unsigned short* Xrow = Xbf + (size_t)(row0 + srow) * 512 + sg * 8;
  const unsigned short* Wrow = Wt + (size_t)(h * 64 + srow) * 512 + sg * 8;

  f32x4 acc[2][4];
  #pragma unroll
  for (int m = 0; m < 2; m++)
    #pragma unroll
    for (int ct = 0; ct < 4; ct++) { acc[m][ct][0]=0.f; acc[m][ct][1]=0.f; acc[m][ct][2]=0.f; acc[m][ct][3]=0.f; }

  // ---- prologue: stage k-step 0 into buf 0 ----
  #pragma unroll
  for (int p = 0; p < 4; p++)
    gload16(Xrow + (size_t)p * 32 * 512, &Xs[0][0][0] + p * 2048 + tid * 8);
  #pragma unroll
  for (int p = 0; p < 2; p++)
    gload16(Wrow + (size_t)p * 32 * 512, &Ws2[0][0][0] + p * 2048 + tid * 8);
  __syncthreads();

  for (int s = 0; s < 8; s++) {
    const int buf = s & 1;
    if (s < 7) {
      const int k0n = (s + 1) * 64;
      #pragma unroll
      for (int p = 0; p < 4; p++)
        gload16(Xrow + (size_t)p * 32 * 512 + k0n, &Xs[buf ^ 1][0][0] + p * 2048 + tid * 8);
      #pragma unroll
      for (int p = 0; p < 2; p++)
        gload16(Wrow + (size_t)p * 32 * 512 + k0n, &Ws2[buf ^ 1][0][0] + p * 2048 + tid * 8);
    }

    __builtin_amdgcn_s_setprio(1);
    #pragma unroll
    for (int kc = 0; kc < 2; kc++) {
      const int gsw = (((kc * 4 + lg) ^ r7) & 7) * 8;
      short8v a8[2], b8[4];
      #pragma unroll
      for (int m = 0; m < 2; m++)
        a8[m] = *(const short8v*)&Xs[buf][m * 64 + w * 16 + lc][gsw];
      #pragma unroll
      for (int ct = 0; ct < 4; ct++)
        b8[ct] = *(const short8v*)&Ws2[buf][ct * 16 + lc][gsw];
      #pragma unroll
      for (int m = 0; m < 2; m++)
        #pragma unroll
        for (int ct = 0; ct < 4; ct++)
          acc[m][ct] = __builtin_amdgcn_mfma_f32_16x16x32_bf16(a8[m], b8[ct], acc[m][ct], 0, 0, 0);
    }
    __builtin_amdgcn_s_setprio(0);
    __syncthreads();
  }

  // ---- epilogue ----
  float gam[4];
  if (doNR) {
    #pragma unroll
    for (int ct = 0; ct < 4; ct++) gam[ct] = gamma[h * 64 + ct * 16 + lc];
  }

  #pragma unroll
  for (int m = 0; m < 2; m++) {
    if (doNR) {
      float srw[4];
      #pragma unroll
      for (int reg = 0; reg < 4; reg++) {
        float ss = acc[m][0][reg]*acc[m][0][reg] + acc[m][1][reg]*acc[m][1][reg]
                 + acc[m][2][reg]*acc[m][2][reg] + acc[m][3][reg]*acc[m][3][reg];
        ss += __shfl_xor(ss, 1, 64);
        ss += __shfl_xor(ss, 2, 64);
        ss += __shfl_xor(ss, 4, 64);
        ss += __shfl_xor(ss, 8, 64);
        srw[reg] = 8.0f / fmaxf(sqrtf(ss), 1e-12f);
      }
      const int posb = pos_offset + ((row0 + m * 64) & 4095) + w * 16 + lg * 4;
      #pragma unroll
      for (int reg = 0; reg < 4; reg++) {
        const float* tabr = Rtab + (size_t)(posb + reg) * 64;
        #pragma unroll
        for (int half = 0; half < 2; half++) {
          float cs = tabr[half * 16 + lc];
          float sn = tabr[32 + half * 16 + lc];
          float v1 = acc[m][half][reg] * srw[reg] * gam[half];
          float v2 = acc[m][half + 2][reg] * srw[reg] * gam[half + 2];
          acc[m][half][reg]     = v1 * cs - v2 * sn;
          acc[m][half + 2][reg] = v2 * cs + v1 * sn;
        }
      }
    }

    #pragma unroll
    for (int ct = 0; ct < 4; ct++)
      #pragma unroll
      for (int reg = 0; reg < 4; reg++)
        Tsh[w * 16 + lg * 4 + reg][ct * 16 + lc] = f2bf(acc[m][ct][reg]);
    __syncthreads();

    const int growm = row0 + m * 64;
    const int b = growm >> 12;
    const int pos0 = pos_offset + (growm & 4095);
    if (OUT) {
      const int r = tid >> 2, part = tid & 3;
      unsigned short* dst = OUT + (((size_t)b * Hout + h) * NTOK + pos0 + r) * 64 + part * 16;
      short8v u0 = *(const short8v*)&Tsh[r][part * 16];
      short8v u1 = *(const short8v*)&Tsh[r][part * 16 + 8];
      *(short8v*)dst = u0;
      *(short8v*)(dst + 8) = u1;
    }
    if (OUTT) {
      const int e = tid >> 2, part = tid & 3;
      short8v t0, t1;
      #pragma unroll
      for (int jj = 0; jj < 16; jj++) {
        const int LG = ((part & 1) << 1) | (jj >> 3);
        const int H  = (jj >> 2) & 1;
        const int I  = jj & 3;
        const int srcrow = (part >> 1) * 32 + H * 16 + LG * 4 + I;
        unsigned short v = Tsh[srcrow][e];
        if (jj < 8) t0[jj] = (short)v; else t1[jj - 8] = (short)v;
      }
      unsigned short* dstT = OUTT + (((size_t)b * NKV + h) * 64 + e) * NTOK + pos0 + part * 16;
      *(short8v*)dstT = t0;
      *(short8v*)(dstT + 8) = t1;
    }
    __syncthreads();
  }
}

// ---------------------------------------------------------------------------
// Per-segment partial summaries (8 n-chunks of 128 tokens) via MFMA.
// grid 256 = (bkv*8+seg)*8+chunk.
// ---------------------------------------------------------------------------
__global__ __launch_bounds__(256) void seg_summary_kernel(
    const unsigned short* __restrict__ Kt, const unsigned short* __restrict__ Vt,
    float* __restrict__ Spart, float* __restrict__ Zpart)
{
  const int blk = blockIdx.x;
  const int chunk = blk & 7;
  const int seg = (blk >> 3) & 7;
  const int bkv = blk >> 6;
  const int tid = threadIdx.x;
  const int w = tid >> 6, l = tid & 63, lc = l & 15, lg = l >> 4;
  const unsigned short* KtB = Kt + ((size_t)bkv * 64) * NTOK + seg * SEGL + chunk * 128;
  const unsigned short* VtB = Vt + ((size_t)bkv * 64) * NTOK + seg * SEGL + chunk * 128;

  f32x4 acc[4];
  #pragma unroll
  for (int ct = 0; ct < 4; ct++) { acc[ct][0]=0.f; acc[ct][1]=0.f; acc[ct][2]=0.f; acc[ct][3]=0.f; }
  float zacc[4] = {0.f, 0.f, 0.f, 0.f};

  for (int n0 = 0; n0 < 128; n0 += 32) {
    short8v av = *(const short8v*)(VtB + (size_t)(w * 16 + lc) * NTOK + n0 + lg * 8);
    #pragma unroll
    for (int ct = 0; ct < 4; ct++) {
      short8v kv = *(const short8v*)(KtB + (size_t)(ct * 16 + lc) * NTOK + n0 + lg * 8);
      short8v skv;
      float zp = 0.f;
      #pragma unroll
      for (int i = 0; i < 8; i++) {
        float kf = bf2f((unsigned short)kv[i]);
        float sk = kf > 0.f ? kf + 1.f : __expf(kf);
        zp += sk;
        skv[i] = (short)f2bf(sk);
      }
      zacc[ct] += zp;
      acc[ct] = __builtin_amdgcn_mfma_f32_16x16x32_bf16(av, skv, acc[ct], 0, 0, 0);
    }
  }

  float* Sp = Spart + (size_t)blk * 4096;
  #pragma unroll
  for (int ct = 0; ct < 4; ct++)
    #pragma unroll
    for (int reg = 0; reg < 4; reg++)
      Sp[(size_t)(w * 16 + lg * 4 + reg) * 64 + ct * 16 + lc] = acc[ct][reg];

  if (w == 0) {
    #pragma unroll
    for (int ct = 0; ct < 4; ct++) {
      zacc[ct] += __shfl_xor(zacc[ct], 16, 64);
      zacc[ct] += __shfl_xor(zacc[ct], 32, 64);
    }
    if (lg == 0) {
      float* Zp = Zpart + (size_t)blk * 64;
      #pragma unroll
      for (int ct = 0; ct < 4; ct++) Zp[ct * 16 + lc] = zacc[ct];
    }
  }
}

// Chunk-reduce + exclusive prefix over segments -> bf16 PT + f32 PZ.
__global__ void prefix_kernel(const float* __restrict__ Spart, const float* __restrict__ Zpart,
                              unsigned short* __restrict__ PT, float* __restrict__ PZ)
{
  const int bkv = blockIdx.x;
  const int col = blockIdx.y * 256 + threadIdx.x;
  float run = 0.f;
  for (int s = 0; s < NSEG; s++) {
    float v = 0.f;
    #pragma unroll
    for (int c = 0; c < 8; c++)
      v += Spart[(((size_t)(bkv * 8 + s)) * 8 + c) * 4096 + col];
    PT[((size_t)bkv * 8 + s) * 4096 + col] = f2bf(run);
    run += v;
  }
  if (blockIdx.y == 0 && threadIdx.x < 64) {
    const int d = threadIdx.x;
    float rz = 0.f;
    for (int s = 0; s < NSEG; s++) {
      float v = 0.f;
      #pragma unroll
      for (int c = 0; c < 8; c++)
        v += Zpart[(((size_t)(bkv * 8 + s)) * 8 + c) * 64 + d];
      PZ[((size_t)bkv * 8 + s) * 64 + d] = rz;
      rz += v;
    }
  }
}

// ---------------------------------------------------------------------------
// MFMA flash attention v6: R9-proven 256-thread staging schedule, but each
// wave computes TWO heads (h = kv+4p, kv+4p+2) against the shared staged K/V.
// Grid 512 = (b,kv,p,seg,j), XCD-bijective swizzle. One barrier per step.
// ---------------------------------------------------------------------------
__global__ __launch_bounds__(256, 2) void attn_mfma_kernel(
    const unsigned short* __restrict__ Qb, const unsigned short* __restrict__ Kb,
    const unsigned short* __restrict__ Vt, const unsigned short* __restrict__ PT,
    const float* __restrict__ PZ, const float* __restrict__ beta,
    float* __restrict__ OUT)
{
  __shared__ __attribute__((aligned(16))) unsigned short Ks[2][64][64];
  __shared__ __attribute__((aligned(16))) unsigned short Vs[2][64][64];
  const int tid = threadIdx.x;
  const int w = tid >> 6;
  const int l = tid & 63;
  const int lc = l & 15;
  const int lg = l >> 4;
  const int r7 = lc & 7;

  // XCD-aware bijective swizzle (512 blocks, 512 % 8 == 0)
  const int bid = (blockIdx.x & 7) * 64 + (blockIdx.x >> 3);
  const int j   = bid & 7;
  const int seg = (bid >> 3) & 7;
  const int pp  = (bid >> 6) & 1;
  const int kv  = (bid >> 7) & 1;
  const int b   = bid >> 8;
  const int bkv = b * NKV + kv;          // jnp.tile -> h % KVH, h below keeps h&1==kv
  const int qtA = 15 - j, qtB = j;
  const int segbase = seg * SEGL;

  const unsigned short* Kbase = Kb + ((size_t)bkv * NTOK + segbase) * 64;
  const unsigned short* Vbase = Vt + ((size_t)bkv * 64) * NTOK + segbase;

  // staging constants: identical to proven R9 schedule
  const int srow = tid >> 3;                 // 0..31
  const int sg   = (tid & 7) ^ (srow & 7);   // involution granule swizzle

  // Q fragments: [hh][tt]
  short8v aq0[2][2], aq1[2][2];
  #pragma unroll
  for (int hh = 0; hh < 2; hh++) {
    const int h = kv + 4 * pp + 2 * hh;
    const int bh = b * NH + h;
    {
      const unsigned short* qp =
          Qb + (((size_t)bh * NTOK) + segbase + qtA * 64 + w * 16 + lc) * 64 + lg * 8;
      aq0[hh][0] = *(const short8v*)(qp);
      aq1[hh][0] = *(const short8v*)(qp + 32);
    }
    {
      const unsigned short* qp =
          Qb + (((size_t)bh * NTOK) + segbase + qtB * 64 + w * 16 + lc) * 64 + lg * 8;
      aq0[hh][1] = *(const short8v*)(qp);
      aq1[hh][1] = *(const short8v*)(qp + 32);
    }
  }

  f32x4 O[2][2][4];
  #pragma unroll
  for (int hh = 0; hh < 2; hh++)
    #pragma unroll
    for (int tt = 0; tt < 2; tt++)
      #pragma unroll
      for (int ce = 0; ce < 4; ce++) { O[hh][tt][ce][0]=0.f; O[hh][tt][ce][1]=0.f; O[hh][tt][ce][2]=0.f; O[hh][tt][ce][3]=0.f; }
  float rsumL[2][2] = {{0.f, 0.f}, {0.f, 0.f}};

  // exp(s*0.125 - 8) == exp2(s*c1 - c2)
  const float c1 = 0.125f * 1.44269504089f;
  const float c2 = 8.0f * 1.44269504089f;

  // ---- prologue: stage tile 0 (R9-exact) ----
  {
    unsigned short* kD = &Ks[0][0][0];
    unsigned short* vD = &Vs[0][0][0];
    #pragma unroll
    for (int p = 0; p < 2; p++) {
      const int row = p * 32 + srow;
      gload16(Kbase + (size_t)row * 64 + sg * 8, kD + p * 2048 + tid * 8);
      gload16(Vbase + (size_t)row * NTOK + sg * 8, vD + p * 2048 + tid * 8);
    }
  }
  __syncthreads();

  for (int kt = 0; kt <= qtA; ++kt) {
    const int buf = kt & 1;
    if (kt < qtA) {
      const int ktn = kt + 1;
      unsigned short* kD = &Ks[buf ^ 1][0][0];
      unsigned short* vD = &Vs[buf ^ 1][0][0];
      #pragma unroll
      for (int p = 0; p < 2; p++) {
        const int row = p * 32 + srow;
        gload16(Kbase + (size_t)(ktn * 64 + row) * 64 + sg * 8, kD + p * 2048 + tid * 8);
        gload16(Vbase + (size_t)row * NTOK + ktn * 64 + sg * 8, vD + p * 2048 + tid * 8);
      }
    }

    __builtin_amdgcn_s_setprio(1);
    #pragma unroll
    for (int hh = 0; hh < 2; hh++) {
      #pragma unroll
      for (int tt = 0; tt < 2; tt++) {
        if (tt == 1 && kt > qtB) continue;
        const int qt_ = tt ? qtB : qtA;
        const bool diag = (kt == qt_);
        const int ctmax = diag ? w : 3;

        // ---- S^T = K Q^T, P = exp2(s*c1 - c2) with causal mask ----
        short4v pa[4];
        #pragma unroll
        for (int ck = 0; ck < 4; ck++) {
          if (ck > ctmax) {
            pa[ck][0] = 0; pa[ck][1] = 0; pa[ck][2] = 0; pa[ck][3] = 0;
            continue;
          }
          f32x4 s;
          s[0]=0.f; s[1]=0.f; s[2]=0.f; s[3]=0.f;
          const int krow = ck * 16 + lc;
          short8v ak0 = *(const short8v*)&Ks[buf][krow][((lg ^ r7) & 7) * 8];
          short8v ak1 = *(const short8v*)&Ks[buf][krow][(((lg + 4) ^ r7) & 7) * 8];
          s = __builtin_amdgcn_mfma_f32_16x16x32_bf16(ak0, aq0[hh][tt], s, 0, 0, 0);
          s = __builtin_amdgcn_mfma_f32_16x16x32_bf16(ak1, aq1[hh][tt], s, 0, 0, 0);
          const bool needmask = diag && (ck == w);
          float p0 = exp2f(s[0] * c1 - c2);
          float p1 = exp2f(s[1] * c1 - c2);
          float p2 = exp2f(s[2] * c1 - c2);
          float p3 = exp2f(s[3] * c1 - c2);
          if (needmask) {
            if (lg * 4 + 0 > lc) p0 = 0.f;
            if (lg * 4 + 1 > lc) p1 = 0.f;
            if (lg * 4 + 2 > lc) p2 = 0.f;
            if (lg * 4 + 3 > lc) p3 = 0.f;
          }
          rsumL[hh][tt] += p0 + p1 + p2 + p3;
          pa[ck][0] = (short)f2bf(p0);
          pa[ck][1] = (short)f2bf(p1);
          pa[ck][2] = (short)f2bf(p2);
          pa[ck][3] = (short)f2bf(p3);
        }

        // ---- O += P V via 16x16x32; B-frag = one b128 from permuted+swizzled Vs ----
        #pragma unroll
        for (int cp = 0; cp < 2; cp++) {
          if (cp * 2 > ctmax) continue;
          short8v a8;
          #pragma unroll
          for (int i = 0; i < 4; i++) { a8[i] = pa[cp * 2][i]; a8[4 + i] = pa[cp * 2 + 1][i]; }
          #pragma unroll
          for (int ce = 0; ce < 4; ce++) {
            short8v b8 = *(const short8v*)&Vs[buf][ce * 16 + lc][(((cp * 4 + lg) ^ r7) & 7) * 8];
            O[hh][tt][ce] = __builtin_amdgcn_mfma_f32_16x16x32_bf16(a8, b8, O[hh][tt][ce], 0, 0, 0);
          }
        }
      }
    }
    __builtin_amdgcn_s_setprio(0);
    __syncthreads();
  }

  // ---- epilogue per (head, tile): softmax sum + memory path + gated write ----
  const unsigned short* stp = PT + ((size_t)bkv * NSEG + seg) * 4096 + lc * 64 + lg * 8;
  const float* zp = PZ + ((size_t)bkv * NSEG + seg) * 64 + lg * 8;

  #pragma unroll
  for (int hh = 0; hh < 2; hh++) {
    const int h = kv + 4 * pp + 2 * hh;
    const float g = 1.f / (1.f + __expf(-beta[h]));
    const float g1 = 1.f - g;

    #pragma unroll
    for (int tt = 0; tt < 2; tt++) {
      float rsum = rsumL[hh][tt];
      rsum += __shfl_xor(rsum, 16, 64);
      rsum += __shfl_xor(rsum, 32, 64);

      short8v asq0, asq1;
      float den = 1e-12f;
      #pragma unroll
      for (int i = 0; i < 8; i++) {
        float f0 = bf2f((unsigned short)aq0[hh][tt][i]);
        float e0 = f0 > 0.f ? f0 + 1.f : __expf(f0);
        asq0[i] = (short)f2bf(e0);
        den += e0 * zp[i];
        float f1 = bf2f((unsigned short)aq1[hh][tt][i]);
        float e1 = f1 > 0.f ? f1 + 1.f : __expf(f1);
        asq1[i] = (short)f2bf(e1);
        den += e1 * zp[32 + i];
      }
      f32x4 N[4];
      #pragma unroll
      for (int ct = 0; ct < 4; ct++) { N[ct][0]=0.f; N[ct][1]=0.f; N[ct][2]=0.f; N[ct][3]=0.f; }
      #pragma unroll
      for (int ct = 0; ct < 4; ct++) {
        short8v bs0 = *(const short8v*)(stp + ct * 16 * 64);
        short8v bs1 = *(const short8v*)(stp + ct * 16 * 64 + 32);
        N[ct] = __builtin_amdgcn_mfma_f32_16x16x32_bf16(asq0, bs0, N[ct], 0, 0, 0);
        N[ct] = __builtin_amdgcn_mfma_f32_16x16x32_bf16(asq1, bs1, N[ct], 0, 0, 0);
      }
      den += __shfl_xor(den, 16, 64);
      den += __shfl_xor(den, 32, 64);
      float denc[4], rs[4];
      #pragma unroll
      for (int reg = 0; reg < 4; reg++) {
        denc[reg] = __shfl(den, lg * 4 + reg, 64);
        rs[reg]   = __shfl(rsum, lg * 4 + reg, 64);
      }

      const int q0 = (tt ? qtB : qtA) * 64;
      const int nrow = segbase + q0 + w * 16 + lg * 4;
      #pragma unroll
      for (int reg = 0; reg < 4; reg++) {
        const int n = nrow + reg;
        const float invs = 1.f / rs[reg];
        const float invd = 1.f / denc[reg];
        size_t obase;
        if (n < 4096) obase = (size_t)BATCH * 4096 * 512 + (((size_t)b * 4096 + n) * NH + h) * 64;
        else          obase = (((size_t)b * 4096 + (n - 4096)) * NH + h) * 64;
        #pragma unroll
        for (int ce = 0; ce < 4; ce++) {
          OUT[obase + ce * 16 + lc] = g * N[ce][reg] * invd + g1 * O[hh][tt][ce][reg] * invs;
        }
      }
    }
  }
}

// ---------------------------------------------------------------------------
extern "C" void kernel_launch(void* const* d_in, const int* in_sizes, int n_in,
                              void* d_out, int out_size, void* d_ws, size_t ws_size,
                              hipStream_t stream) {
  const float* x    = (const float*)d_in[0];
  const float* a    = (const float*)d_in[1];
  const float* Wq_x = (const float*)d_in[2];
  const float* Wk_x = (const float*)d_in[3];
  const float* Wv_x = (const float*)d_in[4];
  const float* Wq_a = (const float*)d_in[5];
  const float* Wk_a = (const float*)d_in[6];
  const float* Wv_a = (const float*)d_in[7];
  const float* gq_x = (const float*)d_in[8];
  const float* gk_x = (const float*)d_in[9];
  const float* gq_a = (const float*)d_in[10];
  const float* gk_a = (const float*)d_in[11];
  const float* beta = (const float*)d_in[12];

  unsigned short* Qb = (unsigned short*)d_ws;          // 8388608
  unsigned short* Kb = Qb + (size_t)8388608;           // 2097152
  unsigned short* Kt = Kb + (size_t)2097152;           // 2097152 (permuted)
  unsigned short* Vt = Kt + (size_t)2097152;           // 2097152 (permuted)
  unsigned short* Xa = Vt + (size_t)2097152;           // 4194304
  unsigned short* Xx = Xa + (size_t)4194304;           // 4194304
  unsigned short* WtQa = Xx + (size_t)4194304;         // 262144
  unsigned short* WtKa = WtQa + (size_t)262144;        // 65536
  unsigned short* WtVa = WtKa + (size_t)65536;         // 65536
  unsigned short* WtQx = WtVa + (size_t)65536;         // 262144
  unsigned short* WtKx = WtQx + (size_t)262144;        // 65536
  unsigned short* WtVx = WtKx + (size_t)65536;         // 65536
  float* Spart = (float*)(WtVx + (size_t)65536);       // 1048576 f32 (4 MB)
  float* Zpart = Spart + (size_t)1048576;              // 16384
  float* PZ = Zpart + (size_t)16384;                   // 2048
  unsigned short* PT = (unsigned short*)(PZ + (size_t)2048); // 131072 bf16
  float* Rtab = (float*)(PT + (size_t)131072);         // 524288 f32 (2 MB)

  cast_bf16_kernel<<<dim3(2048, 2), 256, 0, stream>>>(a, x, Xa, Xx);
  rope_tab_kernel<<<1024, 256, 0, stream>>>(Rtab);
  wtrans_kernel<<<dim3(16, 16, 6), 256, 0, stream>>>(
      Wq_a, Wk_a, Wv_a, Wq_x, Wk_x, Wv_x, WtQa, WtKa, WtVa, WtQx, WtKx, WtVx);
  proj_all_kernel<<<dim3(64, 12, 2), 256, 0, stream>>>(
      Xa, Xx, WtQa, WtKa, WtVa, WtQx, WtKx, WtVx,
      gq_a, gk_a, gq_x, gk_x, Rtab, Qb, Kb, Kt, Vt);
  seg_summary_kernel<<<256, 256, 0, stream>>>(Kt, Vt, Spart, Zpart);
  prefix_kernel<<<dim3(4, 16), 256, 0, stream>>>(Spart, Zpart, PT, PZ);
  attn_mfma_kernel<<<dim3(512), 256, 0, stream>>>(Qb, Kb, Vt, PT, PZ, beta, (float*)d_out);
}

// Round 12
// 93.801 us; speedup vs baseline: 18.0504x; 1.1016x over previous
//
#include <hip/hip_runtime.h>
#include <math.h>

#define NH 8
#define NKV 2
#define SEGL 1024
#define NSEG 8
#define NTOK 8192
#define BATCH 2
#define DIMK 512

typedef short short8v __attribute__((ext_vector_type(8)));
typedef short short4v __attribute__((ext_vector_type(4)));
typedef float f32x4 __attribute__((ext_vector_type(4)));
typedef int int4v __attribute__((ext_vector_type(4)));

__device__ __forceinline__ unsigned short f2bf(float f) {
  union { float f; unsigned u; } c; c.f = f;
  unsigned u = c.u;
  return (unsigned short)((u + 0x7FFFu + ((u >> 16) & 1u)) >> 16);
}
__device__ __forceinline__ float bf2f(unsigned short h) {
  union { unsigned u; float f; } c; c.u = ((unsigned)h) << 16;
  return c.f;
}
// HW packed f32->bf16 (RNE, identical to f2bf emulation). T12 primitive.
__device__ __forceinline__ unsigned cvtpk(float lo, float hi) {
  unsigned r;
  asm("v_cvt_pk_bf16_f32 %0, %1, %2" : "=v"(r) : "v"(lo), "v"(hi));
  return r;
}

// async global->LDS, 16 bytes per lane. LDS dest must be wave-uniform + lane*16.
__device__ __forceinline__ void gload16(const unsigned short* g, unsigned short* l) {
  __builtin_amdgcn_global_load_lds(
      (const __attribute__((address_space(1))) unsigned int*)g,
      (__attribute__((address_space(3))) unsigned int*)l, 16, 0, 0);
}

// ---------------------------------------------------------------------------
// f32 -> bf16 cast; y selects input (0 = a, 1 = x).
// ---------------------------------------------------------------------------
__global__ void cast_bf16_kernel(const float* __restrict__ a, const float* __restrict__ x,
                                 unsigned short* __restrict__ outa,
                                 unsigned short* __restrict__ outx) {
  const float* in = blockIdx.y ? x : a;
  unsigned short* out = blockIdx.y ? outx : outa;
  int i = blockIdx.x * blockDim.x + threadIdx.x;
  const float4* p = (const float4*)in + (size_t)i * 2;
  float4 v0 = p[0], v1 = p[1];
  short8v o;
  o[0] = (short)f2bf(v0.x); o[1] = (short)f2bf(v0.y);
  o[2] = (short)f2bf(v0.z); o[3] = (short)f2bf(v0.w);
  o[4] = (short)f2bf(v1.x); o[5] = (short)f2bf(v1.y);
  o[6] = (short)f2bf(v1.z); o[7] = (short)f2bf(v1.w);
  *((short8v*)out + i) = o;
}

// ---------------------------------------------------------------------------
// RoPE cos/sin table: tab[pos][j] = cos(pos*invf_j), tab[pos][32+j] = sin(...)
// ---------------------------------------------------------------------------
__global__ void rope_tab_kernel(float* __restrict__ tab) {
  const int i = blockIdx.x * 256 + threadIdx.x;   // over 8192*32
  const int pos = i >> 5, j = i & 31;
  const float LOG1E4 = 9.210340371976184f;
  float inv = __expf(-((float)j / 32.f) * LOG1E4);
  float sn, cs;
  sincosf((float)pos * inv, &sn, &cs);
  tab[(size_t)pos * 64 + j] = cs;
  tab[(size_t)pos * 64 + 32 + j] = sn;
}

// ---------------------------------------------------------------------------
// W (512 x C) f32 -> Wt (C x 512) bf16; z selects which of the 6 weights.
// ---------------------------------------------------------------------------
__global__ void wtrans_kernel(const float* __restrict__ w0, const float* __restrict__ w1,
                              const float* __restrict__ w2, const float* __restrict__ w3,
                              const float* __restrict__ w4, const float* __restrict__ w5,
                              unsigned short* __restrict__ o0, unsigned short* __restrict__ o1,
                              unsigned short* __restrict__ o2, unsigned short* __restrict__ o3,
                              unsigned short* __restrict__ o4, unsigned short* __restrict__ o5) {
  __shared__ float T[32][33];
  const int z = blockIdx.z;
  const float* in; unsigned short* out; int C;
  switch (z) {
    case 0: in = w0; out = o0; C = 512; break;
    case 1: in = w1; out = o1; C = 128; break;
    case 2: in = w2; out = o2; C = 128; break;
    case 3: in = w3; out = o3; C = 512; break;
    case 4: in = w4; out = o4; C = 128; break;
    default: in = w5; out = o5; C = 128; break;
  }
  const int c0 = blockIdx.x * 32, k0 = blockIdx.y * 32;
  if (c0 >= C) return;
  const int tx = threadIdx.x & 31, ty = threadIdx.x >> 5;
  #pragma unroll
  for (int i = 0; i < 4; i++)
    T[ty + i * 8][tx] = in[(size_t)(k0 + ty + i * 8) * C + c0 + tx];
  __syncthreads();
  #pragma unroll
  for (int i = 0; i < 4; i++)
    out[(size_t)(c0 + ty + i * 8) * 512 + k0 + tx] = f2bf(T[tx][ty + i * 8]);
}

// ---------------------------------------------------------------------------
// Merged MFMA projection v3: 128-row x 64-col block, double-buffered
// global_load_lds staging, XOR-granule swizzle, BK=64, 8 k-steps.
// grid (64, 12, 2).
// ---------------------------------------------------------------------------
__global__ __launch_bounds__(256, 3) void proj_all_kernel(
    const unsigned short* __restrict__ Xa, const unsigned short* __restrict__ Xx,
    const unsigned short* __restrict__ WtQa, const unsigned short* __restrict__ WtKa,
    const unsigned short* __restrict__ WtVa, const unsigned short* __restrict__ WtQx,
    const unsigned short* __restrict__ WtKx, const unsigned short* __restrict__ WtVx,
    const float* __restrict__ gq_a, const float* __restrict__ gk_a,
    const float* __restrict__ gq_x, const float* __restrict__ gk_x,
    const float* __restrict__ Rtab,
    unsigned short* __restrict__ Qb, unsigned short* __restrict__ Kb,
    unsigned short* __restrict__ Kt, unsigned short* __restrict__ Vt)
{
  __shared__ __attribute__((aligned(16))) unsigned short Xs[2][128][64];  // 32 KB
  __shared__ __attribute__((aligned(16))) unsigned short Ws2[2][64][64];  // 16 KB
  unsigned short (*Tsh)[72] = (unsigned short (*)[72])&Xs[0][0][0];       // alias

  const int tid = threadIdx.x;
  const int w = tid >> 6, l = tid & 63, lc = l & 15, lg = l >> 4;
  const int r7 = lc & 7;
  const int z = blockIdx.z;
  const int y = blockIdx.y;
  const int row0 = blockIdx.x * 128;
  const int pos_offset = z ? 4096 : 0;

  const unsigned short* Xbf = z ? Xx : Xa;
  const unsigned short* Wt;
  const float* gamma = nullptr;
  unsigned short* OUT = nullptr;
  unsigned short* OUTT = nullptr;
  int h, Hout, doNR;
  if (y < 8) {
    h = y; Hout = NH; doNR = 1;
    Wt = z ? WtQx : WtQa; gamma = z ? gq_x : gq_a; OUT = Qb;
  } else if (y < 10) {
    h = y - 8; Hout = NKV; doNR = 1;
    Wt = z ? WtKx : WtKa; gamma = z ? gk_x : gk_a; OUT = Kb; OUTT = Kt;
  } else {
    h = y - 10; Hout = NKV; doNR = 0;
    Wt = z ? WtVx : WtVa; OUTT = Vt;
  }

  const int srow = tid >> 3;
  const int sg   = (tid & 7) ^ (srow & 7);
  const unsigned short* Xrow = Xbf + (size_t)(row0 + srow) * 512 + sg * 8;
  const unsigned short* Wrow = Wt + (size_t)(h * 64 + srow) * 512 + sg * 8;

  f32x4 acc[2][4];
  #pragma unroll
  for (int m = 0; m < 2; m++)
    #pragma unroll
    for (int ct = 0; ct < 4; ct++) { acc[m][ct][0]=0.f; acc[m][ct][1]=0.f; acc[m][ct][2]=0.f; acc[m][ct][3]=0.f; }

  // ---- prologue: stage k-step 0 into buf 0 ----
  #pragma unroll
  for (int p = 0; p < 4; p++)
    gload16(Xrow + (size_t)p * 32 * 512, &Xs[0][0][0] + p * 2048 + tid * 8);
  #pragma unroll
  for (int p = 0; p < 2; p++)
    gload16(Wrow + (size_t)p * 32 * 512, &Ws2[0][0][0] + p * 2048 + tid * 8);
  __syncthreads();

  for (int s = 0; s < 8; s++) {
    const int buf = s & 1;
    if (s < 7) {
      const int k0n = (s + 1) * 64;
      #pragma unroll
      for (int p = 0; p < 4; p++)
        gload16(Xrow + (size_t)p * 32 * 512 + k0n, &Xs[buf ^ 1][0][0] + p * 2048 + tid * 8);
      #pragma unroll
      for (int p = 0; p < 2; p++)
        gload16(Wrow + (size_t)p * 32 * 512 + k0n, &Ws2[buf ^ 1][0][0] + p * 2048 + tid * 8);
    }

    __builtin_amdgcn_s_setprio(1);
    #pragma unroll
    for (int kc = 0; kc < 2; kc++) {
      const int gsw = (((kc * 4 + lg) ^ r7) & 7) * 8;
      short8v a8[2], b8[4];
      #pragma unroll
      for (int m = 0; m < 2; m++)
        a8[m] = *(const short8v*)&Xs[buf][m * 64 + w * 16 + lc][gsw];
      #pragma unroll
      for (int ct = 0; ct < 4; ct++)
        b8[ct] = *(const short8v*)&Ws2[buf][ct * 16 + lc][gsw];
      #pragma unroll
      for (int m = 0; m < 2; m++)
        #pragma unroll
        for (int ct = 0; ct < 4; ct++)
          acc[m][ct] = __builtin_amdgcn_mfma_f32_16x16x32_bf16(a8[m], b8[ct], acc[m][ct], 0, 0, 0);
    }
    __builtin_amdgcn_s_setprio(0);
    __syncthreads();
  }

  // ---- epilogue ----
  float gam[4];
  if (doNR) {
    #pragma unroll
    for (int ct = 0; ct < 4; ct++) gam[ct] = gamma[h * 64 + ct * 16 + lc];
  }

  #pragma unroll
  for (int m = 0; m < 2; m++) {
    if (doNR) {
      float srw[4];
      #pragma unroll
      for (int reg = 0; reg < 4; reg++) {
        float ss = acc[m][0][reg]*acc[m][0][reg] + acc[m][1][reg]*acc[m][1][reg]
                 + acc[m][2][reg]*acc[m][2][reg] + acc[m][3][reg]*acc[m][3][reg];
        ss += __shfl_xor(ss, 1, 64);
        ss += __shfl_xor(ss, 2, 64);
        ss += __shfl_xor(ss, 4, 64);
        ss += __shfl_xor(ss, 8, 64);
        srw[reg] = 8.0f / fmaxf(sqrtf(ss), 1e-12f);
      }
      const int posb = pos_offset + ((row0 + m * 64) & 4095) + w * 16 + lg * 4;
      #pragma unroll
      for (int reg = 0; reg < 4; reg++) {
        const float* tabr = Rtab + (size_t)(posb + reg) * 64;
        #pragma unroll
        for (int half = 0; half < 2; half++) {
          float cs = tabr[half * 16 + lc];
          float sn = tabr[32 + half * 16 + lc];
          float v1 = acc[m][half][reg] * srw[reg] * gam[half];
          float v2 = acc[m][half + 2][reg] * srw[reg] * gam[half + 2];
          acc[m][half][reg]     = v1 * cs - v2 * sn;
          acc[m][half + 2][reg] = v2 * cs + v1 * sn;
        }
      }
    }

    #pragma unroll
    for (int ct = 0; ct < 4; ct++)
      #pragma unroll
      for (int reg = 0; reg < 4; reg++)
        Tsh[w * 16 + lg * 4 + reg][ct * 16 + lc] = f2bf(acc[m][ct][reg]);
    __syncthreads();

    const int growm = row0 + m * 64;
    const int b = growm >> 12;
    const int pos0 = pos_offset + (growm & 4095);
    if (OUT) {
      const int r = tid >> 2, part = tid & 3;
      unsigned short* dst = OUT + (((size_t)b * Hout + h) * NTOK + pos0 + r) * 64 + part * 16;
      short8v u0 = *(const short8v*)&Tsh[r][part * 16];
      short8v u1 = *(const short8v*)&Tsh[r][part * 16 + 8];
      *(short8v*)dst = u0;
      *(short8v*)(dst + 8) = u1;
    }
    if (OUTT) {
      const int e = tid >> 2, part = tid & 3;
      short8v t0, t1;
      #pragma unroll
      for (int jj = 0; jj < 16; jj++) {
        const int LG = ((part & 1) << 1) | (jj >> 3);
        const int H  = (jj >> 2) & 1;
        const int I  = jj & 3;
        const int srcrow = (part >> 1) * 32 + H * 16 + LG * 4 + I;
        unsigned short v = Tsh[srcrow][e];
        if (jj < 8) t0[jj] = (short)v; else t1[jj - 8] = (short)v;
      }
      unsigned short* dstT = OUTT + (((size_t)b * NKV + h) * 64 + e) * NTOK + pos0 + part * 16;
      *(short8v*)dstT = t0;
      *(short8v*)(dstT + 8) = t1;
    }
    __syncthreads();
  }
}

// ---------------------------------------------------------------------------
// Per-segment partial summaries (8 n-chunks of 128 tokens) via MFMA.
// grid 256 = (bkv*8+seg)*8+chunk.
// ---------------------------------------------------------------------------
__global__ __launch_bounds__(256) void seg_summary_kernel(
    const unsigned short* __restrict__ Kt, const unsigned short* __restrict__ Vt,
    float* __restrict__ Spart, float* __restrict__ Zpart)
{
  const int blk = blockIdx.x;
  const int chunk = blk & 7;
  const int seg = (blk >> 3) & 7;
  const int bkv = blk >> 6;
  const int tid = threadIdx.x;
  const int w = tid >> 6, l = tid & 63, lc = l & 15, lg = l >> 4;
  const unsigned short* KtB = Kt + ((size_t)bkv * 64) * NTOK + seg * SEGL + chunk * 128;
  const unsigned short* VtB = Vt + ((size_t)bkv * 64) * NTOK + seg * SEGL + chunk * 128;

  f32x4 acc[4];
  #pragma unroll
  for (int ct = 0; ct < 4; ct++) { acc[ct][0]=0.f; acc[ct][1]=0.f; acc[ct][2]=0.f; acc[ct][3]=0.f; }
  float zacc[4] = {0.f, 0.f, 0.f, 0.f};

  for (int n0 = 0; n0 < 128; n0 += 32) {
    short8v av = *(const short8v*)(VtB + (size_t)(w * 16 + lc) * NTOK + n0 + lg * 8);
    #pragma unroll
    for (int ct = 0; ct < 4; ct++) {
      short8v kv = *(const short8v*)(KtB + (size_t)(ct * 16 + lc) * NTOK + n0 + lg * 8);
      short8v skv;
      float zp = 0.f;
      #pragma unroll
      for (int i = 0; i < 8; i++) {
        float kf = bf2f((unsigned short)kv[i]);
        float sk = kf > 0.f ? kf + 1.f : __expf(kf);
        zp += sk;
        skv[i] = (short)f2bf(sk);
      }
      zacc[ct] += zp;
      acc[ct] = __builtin_amdgcn_mfma_f32_16x16x32_bf16(av, skv, acc[ct], 0, 0, 0);
    }
  }

  float* Sp = Spart + (size_t)blk * 4096;
  #pragma unroll
  for (int ct = 0; ct < 4; ct++)
    #pragma unroll
    for (int reg = 0; reg < 4; reg++)
      Sp[(size_t)(w * 16 + lg * 4 + reg) * 64 + ct * 16 + lc] = acc[ct][reg];

  if (w == 0) {
    #pragma unroll
    for (int ct = 0; ct < 4; ct++) {
      zacc[ct] += __shfl_xor(zacc[ct], 16, 64);
      zacc[ct] += __shfl_xor(zacc[ct], 32, 64);
    }
    if (lg == 0) {
      float* Zp = Zpart + (size_t)blk * 64;
      #pragma unroll
      for (int ct = 0; ct < 4; ct++) Zp[ct * 16 + lc] = zacc[ct];
    }
  }
}

// Chunk-reduce + exclusive prefix over segments -> bf16 PT + f32 PZ.
__global__ void prefix_kernel(const float* __restrict__ Spart, const float* __restrict__ Zpart,
                              unsigned short* __restrict__ PT, float* __restrict__ PZ)
{
  const int bkv = blockIdx.x;
  const int col = blockIdx.y * 256 + threadIdx.x;
  float run = 0.f;
  for (int s = 0; s < NSEG; s++) {
    float v = 0.f;
    #pragma unroll
    for (int c = 0; c < 8; c++)
      v += Spart[(((size_t)(bkv * 8 + s)) * 8 + c) * 4096 + col];
    PT[((size_t)bkv * 8 + s) * 4096 + col] = f2bf(run);
    run += v;
  }
  if (blockIdx.y == 0 && threadIdx.x < 64) {
    const int d = threadIdx.x;
    float rz = 0.f;
    for (int s = 0; s < NSEG; s++) {
      float v = 0.f;
      #pragma unroll
      for (int c = 0; c < 8; c++)
        v += Zpart[(((size_t)(bkv * 8 + s)) * 8 + c) * 64 + d];
      PZ[((size_t)bkv * 8 + s) * 64 + d] = rz;
      rz += v;
    }
  }
}

// ---------------------------------------------------------------------------
// MFMA flash attention v7: v6 structure (2 heads/block share staged K/V,
// R9-proven staging schedule) + hoisted per-step K/V fragment reads and
// v_cvt_pk_bf16_f32 packing (T12) to cut the VALU hot path.
// ---------------------------------------------------------------------------
__global__ __launch_bounds__(256, 2) void attn_mfma_kernel(
    const unsigned short* __restrict__ Qb, const unsigned short* __restrict__ Kb,
    const unsigned short* __restrict__ Vt, const unsigned short* __restrict__ PT,
    const float* __restrict__ PZ, const float* __restrict__ beta,
    float* __restrict__ OUT)
{
  __shared__ __attribute__((aligned(16))) unsigned short Ks[2][64][64];
  __shared__ __attribute__((aligned(16))) unsigned short Vs[2][64][64];
  const int tid = threadIdx.x;
  const int w = tid >> 6;
  const int l = tid & 63;
  const int lc = l & 15;
  const int lg = l >> 4;
  const int r7 = lc & 7;

  // XCD-aware bijective swizzle (512 blocks, 512 % 8 == 0)
  const int bid = (blockIdx.x & 7) * 64 + (blockIdx.x >> 3);
  const int j   = bid & 7;
  const int seg = (bid >> 3) & 7;
  const int pp  = (bid >> 6) & 1;
  const int kv  = (bid >> 7) & 1;
  const int b   = bid >> 8;
  const int bkv = b * NKV + kv;          // jnp.tile -> h % KVH
  const int qtA = 15 - j, qtB = j;
  const int segbase = seg * SEGL;

  const unsigned short* Kbase = Kb + ((size_t)bkv * NTOK + segbase) * 64;
  const unsigned short* Vbase = Vt + ((size_t)bkv * 64) * NTOK + segbase;

  // staging constants: identical to proven R9 schedule
  const int srow = tid >> 3;                 // 0..31
  const int sg   = (tid & 7) ^ (srow & 7);   // involution granule swizzle

  // Q fragments: [hh][tt]
  short8v aq0[2][2], aq1[2][2];
  #pragma unroll
  for (int hh = 0; hh < 2; hh++) {
    const int h = kv + 4 * pp + 2 * hh;
    const int bh = b * NH + h;
    {
      const unsigned short* qp =
          Qb + (((size_t)bh * NTOK) + segbase + qtA * 64 + w * 16 + lc) * 64 + lg * 8;
      aq0[hh][0] = *(const short8v*)(qp);
      aq1[hh][0] = *(const short8v*)(qp + 32);
    }
    {
      const unsigned short* qp =
          Qb + (((size_t)bh * NTOK) + segbase + qtB * 64 + w * 16 + lc) * 64 + lg * 8;
      aq0[hh][1] = *(const short8v*)(qp);
      aq1[hh][1] = *(const short8v*)(qp + 32);
    }
  }

  f32x4 O[2][2][4];
  #pragma unroll
  for (int hh = 0; hh < 2; hh++)
    #pragma unroll
    for (int tt = 0; tt < 2; tt++)
      #pragma unroll
      for (int ce = 0; ce < 4; ce++) { O[hh][tt][ce][0]=0.f; O[hh][tt][ce][1]=0.f; O[hh][tt][ce][2]=0.f; O[hh][tt][ce][3]=0.f; }
  float rsumL[2][2] = {{0.f, 0.f}, {0.f, 0.f}};

  // exp(s*0.125 - 8) == exp2(s*c1 - c2)
  const float c1 = 0.125f * 1.44269504089f;
  const float c2 = 8.0f * 1.44269504089f;

  // ---- prologue: stage tile 0 (R9-exact) ----
  {
    unsigned short* kD = &Ks[0][0][0];
    unsigned short* vD = &Vs[0][0][0];
    #pragma unroll
    for (int p = 0; p < 2; p++) {
      const int row = p * 32 + srow;
      gload16(Kbase + (size_t)row * 64 + sg * 8, kD + p * 2048 + tid * 8);
      gload16(Vbase + (size_t)row * NTOK + sg * 8, vD + p * 2048 + tid * 8);
    }
  }
  __syncthreads();

  for (int kt = 0; kt <= qtA; ++kt) {
    const int buf = kt & 1;
    if (kt < qtA) {
      const int ktn = kt + 1;
      unsigned short* kD = &Ks[buf ^ 1][0][0];
      unsigned short* vD = &Vs[buf ^ 1][0][0];
      #pragma unroll
      for (int p = 0; p < 2; p++) {
        const int row = p * 32 + srow;
        gload16(Kbase + (size_t)(ktn * 64 + row) * 64 + sg * 8, kD + p * 2048 + tid * 8);
        gload16(Vbase + (size_t)row * NTOK + ktn * 64 + sg * 8, vD + p * 2048 + tid * 8);
      }
    }

    __builtin_amdgcn_s_setprio(1);

    // ---- hoisted per-step K/V fragment reads (shared by both heads/tiles) ----
    short8v ak0r[4], ak1r[4];
    #pragma unroll
    for (int ck = 0; ck < 4; ck++) {
      const int krow = ck * 16 + lc;
      ak0r[ck] = *(const short8v*)&Ks[buf][krow][((lg ^ r7) & 7) * 8];
      ak1r[ck] = *(const short8v*)&Ks[buf][krow][(((lg + 4) ^ r7) & 7) * 8];
    }
    short8v bvr[2][4];
    #pragma unroll
    for (int cp = 0; cp < 2; cp++)
      #pragma unroll
      for (int ce = 0; ce < 4; ce++)
        bvr[cp][ce] = *(const short8v*)&Vs[buf][ce * 16 + lc][(((cp * 4 + lg) ^ r7) & 7) * 8];

    #pragma unroll
    for (int hh = 0; hh < 2; hh++) {
      #pragma unroll
      for (int tt = 0; tt < 2; tt++) {
        if (tt == 1 && kt > qtB) continue;
        const int qt_ = tt ? qtB : qtA;
        const bool diag = (kt == qt_);
        const int ctmax = diag ? w : 3;

        // ---- S^T = K Q^T, P = exp2(s*c1 - c2) with causal mask ----
        unsigned paw[4][2];
        #pragma unroll
        for (int ck = 0; ck < 4; ck++) {
          if (ck > ctmax) { paw[ck][0] = 0u; paw[ck][1] = 0u; continue; }
          f32x4 s;
          s[0]=0.f; s[1]=0.f; s[2]=0.f; s[3]=0.f;
          s = __builtin_amdgcn_mfma_f32_16x16x32_bf16(ak0r[ck], aq0[hh][tt], s, 0, 0, 0);
          s = __builtin_amdgcn_mfma_f32_16x16x32_bf16(ak1r[ck], aq1[hh][tt], s, 0, 0, 0);
          const bool needmask = diag && (ck == w);
          float p0 = exp2f(s[0] * c1 - c2);
          float p1 = exp2f(s[1] * c1 - c2);
          float p2 = exp2f(s[2] * c1 - c2);
          float p3 = exp2f(s[3] * c1 - c2);
          if (needmask) {
            if (lg * 4 + 0 > lc) p0 = 0.f;
            if (lg * 4 + 1 > lc) p1 = 0.f;
            if (lg * 4 + 2 > lc) p2 = 0.f;
            if (lg * 4 + 3 > lc) p3 = 0.f;
          }
          rsumL[hh][tt] += p0 + p1 + p2 + p3;
          paw[ck][0] = cvtpk(p0, p1);
          paw[ck][1] = cvtpk(p2, p3);
        }

        // ---- O += P V via 16x16x32; A from packed words, B from registers ----
        #pragma unroll
        for (int cp = 0; cp < 2; cp++) {
          if (cp * 2 > ctmax) continue;
          int4v a8i;
          a8i[0] = (int)paw[cp * 2][0];
          a8i[1] = (int)paw[cp * 2][1];
          a8i[2] = (int)paw[cp * 2 + 1][0];
          a8i[3] = (int)paw[cp * 2 + 1][1];
          short8v a8;
          __builtin_memcpy(&a8, &a8i, 16);
          #pragma unroll
          for (int ce = 0; ce < 4; ce++)
            O[hh][tt][ce] = __builtin_amdgcn_mfma_f32_16x16x32_bf16(a8, bvr[cp][ce], O[hh][tt][ce], 0, 0, 0);
        }
      }
    }
    __builtin_amdgcn_s_setprio(0);
    __syncthreads();
  }

  // ---- epilogue per (head, tile): softmax sum + memory path + gated write ----
  const unsigned short* stp = PT + ((size_t)bkv * NSEG + seg) * 4096 + lc * 64 + lg * 8;
  const float* zp = PZ + ((size_t)bkv * NSEG + seg) * 64 + lg * 8;

  #pragma unroll
  for (int hh = 0; hh < 2; hh++) {
    const int h = kv + 4 * pp + 2 * hh;
    const float g = 1.f / (1.f + __expf(-beta[h]));
    const float g1 = 1.f - g;

    #pragma unroll
    for (int tt = 0; tt < 2; tt++) {
      float rsum = rsumL[hh][tt];
      rsum += __shfl_xor(rsum, 16, 64);
      rsum += __shfl_xor(rsum, 32, 64);

      float sq0[8], sq1[8];
      float den = 1e-12f;
      #pragma unroll
      for (int i = 0; i < 8; i++) {
        float f0 = bf2f((unsigned short)aq0[hh][tt][i]);
        sq0[i] = f0 > 0.f ? f0 + 1.f : __expf(f0);
        den += sq0[i] * zp[i];
        float f1 = bf2f((unsigned short)aq1[hh][tt][i]);
        sq1[i] = f1 > 0.f ? f1 + 1.f : __expf(f1);
        den += sq1[i] * zp[32 + i];
      }
      int4v q0i, q1i;
      q0i[0] = (int)cvtpk(sq0[0], sq0[1]);
      q0i[1] = (int)cvtpk(sq0[2], sq0[3]);
      q0i[2] = (int)cvtpk(sq0[4], sq0[5]);
      q0i[3] = (int)cvtpk(sq0[6], sq0[7]);
      q1i[0] = (int)cvtpk(sq1[0], sq1[1]);
      q1i[1] = (int)cvtpk(sq1[2], sq1[3]);
      q1i[2] = (int)cvtpk(sq1[4], sq1[5]);
      q1i[3] = (int)cvtpk(sq1[6], sq1[7]);
      short8v asq0, asq1;
      __builtin_memcpy(&asq0, &q0i, 16);
      __builtin_memcpy(&asq1, &q1i, 16);

      f32x4 N[4];
      #pragma unroll
      for (int ct = 0; ct < 4; ct++) { N[ct][0]=0.f; N[ct][1]=0.f; N[ct][2]=0.f; N[ct][3]=0.f; }
      #pragma unroll
      for (int ct = 0; ct < 4; ct++) {
        short8v bs0 = *(const short8v*)(stp + ct * 16 * 64);
        short8v bs1 = *(const short8v*)(stp + ct * 16 * 64 + 32);
        N[ct] = __builtin_amdgcn_mfma_f32_16x16x32_bf16(asq0, bs0, N[ct], 0, 0, 0);
        N[ct] = __builtin_amdgcn_mfma_f32_16x16x32_bf16(asq1, bs1, N[ct], 0, 0, 0);
      }
      den += __shfl_xor(den, 16, 64);
      den += __shfl_xor(den, 32, 64);
      float denc[4], rs[4];
      #pragma unroll
      for (int reg = 0; reg < 4; reg++) {
        denc[reg] = __shfl(den, lg * 4 + reg, 64);
        rs[reg]   = __shfl(rsum, lg * 4 + reg, 64);
      }

      const int q0 = (tt ? qtB : qtA) * 64;
      const int nrow = segbase + q0 + w * 16 + lg * 4;
      #pragma unroll
      for (int reg = 0; reg < 4; reg++) {
        const int n = nrow + reg;
        const float invs = 1.f / rs[reg];
        const float invd = 1.f / denc[reg];
        size_t obase;
        if (n < 4096) obase = (size_t)BATCH * 4096 * 512 + (((size_t)b * 4096 + n) * NH + h) * 64;
        else          obase = (((size_t)b * 4096 + (n - 4096)) * NH + h) * 64;
        #pragma unroll
        for (int ce = 0; ce < 4; ce++) {
          OUT[obase + ce * 16 + lc] = g * N[ce][reg] * invd + g1 * O[hh][tt][ce][reg] * invs;
        }
      }
    }
  }
}

// ---------------------------------------------------------------------------
extern "C" void kernel_launch(void* const* d_in, const int* in_sizes, int n_in,
                              void* d_out, int out_size, void* d_ws, size_t ws_size,
                              hipStream_t stream) {
  const float* x    = (const float*)d_in[0];
  const float* a    = (const float*)d_in[1];
  const float* Wq_x = (const float*)d_in[2];
  const float* Wk_x = (const float*)d_in[3];
  const float* Wv_x = (const float*)d_in[4];
  const float* Wq_a = (const float*)d_in[5];
  const float* Wk_a = (const float*)d_in[6];
  const float* Wv_a = (const float*)d_in[7];
  const float* gq_x = (const float*)d_in[8];
  const float* gk_x = (const float*)d_in[9];
  const float* gq_a = (const float*)d_in[10];
  const float* gk_a = (const float*)d_in[11];
  const float* beta = (const float*)d_in[12];

  unsigned short* Qb = (unsigned short*)d_ws;          // 8388608
  unsigned short* Kb = Qb + (size_t)8388608;           // 2097152
  unsigned short* Kt = Kb + (size_t)2097152;           // 2097152 (permuted)
  unsigned short* Vt = Kt + (size_t)2097152;           // 2097152 (permuted)
  unsigned short* Xa = Vt + (size_t)2097152;           // 4194304
  unsigned short* Xx = Xa + (size_t)4194304;           // 4194304
  unsigned short* WtQa = Xx + (size_t)4194304;         // 262144
  unsigned short* WtKa = WtQa + (size_t)262144;        // 65536
  unsigned short* WtVa = WtKa + (size_t)65536;         // 65536
  unsigned short* WtQx = WtVa + (size_t)65536;         // 262144
  unsigned short* WtKx = WtQx + (size_t)262144;        // 65536
  unsigned short* WtVx = WtKx + (size_t)65536;         // 65536
  float* Spart = (float*)(WtVx + (size_t)65536);       // 1048576 f32 (4 MB)
  float* Zpart = Spart + (size_t)1048576;              // 16384
  float* PZ = Zpart + (size_t)16384;                   // 2048
  unsigned short* PT = (unsigned short*)(PZ + (size_t)2048); // 131072 bf16
  float* Rtab = (float*)(PT + (size_t)131072);         // 524288 f32 (2 MB)

  cast_bf16_kernel<<<dim3(2048, 2), 256, 0, stream>>>(a, x, Xa, Xx);
  rope_tab_kernel<<<1024, 256, 0, stream>>>(Rtab);
  wtrans_kernel<<<dim3(16, 16, 6), 256, 0, stream>>>(
      Wq_a, Wk_a, Wv_a, Wq_x, Wk_x, Wv_x, WtQa, WtKa, WtVa, WtQx, WtKx, WtVx);
  proj_all_kernel<<<dim3(64, 12, 2), 256, 0, stream>>>(
      Xa, Xx, WtQa, WtKa, WtVa, WtQx, WtKx, WtVx,
      gq_a, gk_a, gq_x, gk_x, Rtab, Qb, Kb, Kt, Vt);
  seg_summary_kernel<<<256, 256, 0, stream>>>(Kt, Vt, Spart, Zpart);
  prefix_kernel<<<dim3(4, 16), 256, 0, stream>>>(Spart, Zpart, PT, PZ);
  attn_mfma_kernel<<<dim3(512), 256, 0, stream>>>(Qb, Kb, Vt, PT, PZ, beta, (float*)d_out);
}